// Round 4
// baseline (7033.924 us; speedup 1.0000x reference)
//
#include <hip/hip_runtime.h>
#include <math.h>

#define DIMN 20
#define DD 21
#define NN 2048
#define MCN 32
#define UNITS 128
#define SIGC 0.2f
#define MUC 0.05f
#define RC 0.05f
#define DELTAC 0.01f

#define TM 32
#define NTH 512
#define PTOT (NN + MCN*NN + NN)
#define NBLK (PTOT/TM)

// ws layout (floats)
#define OFF_L 0
#define OFF_WT 512
#define OFF_U4 (OFF_WT + 4*16384)        // 66048 : packed [Uz|Ug|Ur|Uh] 21x512
#define OFF_W3 (OFF_U4 + DD*512)         // 76800 : packed [Wz|Wg|Wr] 128x384
#define OFF_FP1 (OFF_W3 + UNITS*384)     // 125952
#define OFF_VAL1 (OFF_FP1 + NN*DD)
#define OFF_VAL2 (OFF_VAL1 + NN)
#define OFF_T12  (OFF_VAL2 + NN)
#define OFF_GATES (OFF_T12 + NN)         // layer-2 gate stash: NBLK * 16384 floats
#define GB_STRIDE 16384

// LDS layout (floats): S0|S1|S2|Db|xT|Vb = 17728 floats = 70,912 B -> 2 blocks/CU
#define L_S0 0
#define L_S1 4096
#define L_S2 8192
#define L_D  12288
#define L_XT 16384
#define L_VB (16384 + 672)
#define L_TOT (16384 + 672 + 672)

#define ELT24(...) _Pragma("unroll") for (int p = 0; p < 2; p++){ _Pragma("unroll") for (int jj = 0; jj < 4; jj++){ __VA_ARGS__; } }

// element (row, p) of a [128-row][32-p] swizzled buffer
__device__ __forceinline__ int offs(int row, int p){
    return row*32 + (((p & 28) + 4*(row&7)) & 31) + (p & 3);
}

#define FMA8(acc, s2, w4) \
  acc[0][0]=fmaf(s2.x,w4.x,acc[0][0]); acc[0][1]=fmaf(s2.x,w4.y,acc[0][1]); \
  acc[0][2]=fmaf(s2.x,w4.z,acc[0][2]); acc[0][3]=fmaf(s2.x,w4.w,acc[0][3]); \
  acc[1][0]=fmaf(s2.y,w4.x,acc[1][0]); acc[1][1]=fmaf(s2.y,w4.y,acc[1][1]); \
  acc[1][2]=fmaf(s2.y,w4.z,acc[1][2]); acc[1][3]=fmaf(s2.y,w4.w,acc[1][3]);

// acc[2][4] += vec[k][p0..p0+1] * W[k][4jg..4jg+3]; W direct from global; 2-row lookahead
__device__ __forceinline__ void mm_g(const float* __restrict__ gW, int K,
    const float* __restrict__ vec, float acc[2][4], int jg, int p0)
{
    const float* wp = gW + 4*jg;
    int kp = K & ~1;
    float4 wa0 = *(const float4*)(wp);
    float2 sa0 = *(const float2*)(vec + offs(0, p0));
    float4 wa1 = *(const float4*)(wp + UNITS);
    float2 sa1 = *(const float2*)(vec + offs(1, p0));
    for (int c = 0; c < kp; c += 2){
        float4 wb0, wb1; float2 sb0, sb1;
        bool more = (c + 2) < kp;
        if (more){
            wb0 = *(const float4*)(wp + (c+2)*UNITS);
            sb0 = *(const float2*)(vec + offs(c+2, p0));
            wb1 = *(const float4*)(wp + (c+3)*UNITS);
            sb1 = *(const float2*)(vec + offs(c+3, p0));
        }
        FMA8(acc, sa0, wa0)
        FMA8(acc, sa1, wa1)
        if (more){ wa0=wb0; wa1=wb1; sa0=sb0; sa1=sb1; }
    }
    if (K & 1){
        float4 w4 = *(const float4*)(wp + kp*UNITS);
        float2 s2 = *(const float2*)(vec + offs(kp, p0));
        FMA8(acc, s2, w4)
    }
}

// fused z,g,r: W3 rows of 384; 2-row lookahead (K even)
__device__ __forceinline__ void mm3_g(const float* __restrict__ gW, int K,
    const float* __restrict__ vec, float a0[2][4], float a1[2][4], float a2[2][4],
    int jg, int p0)
{
    const float* wp = gW + 4*jg;
    int kp = K & ~1;
    float4 u0 = *(const float4*)(wp);
    float4 u1 = *(const float4*)(wp + 128);
    float4 u2 = *(const float4*)(wp + 256);
    float4 x0 = *(const float4*)(wp + 384);
    float4 x1 = *(const float4*)(wp + 384 + 128);
    float4 x2 = *(const float4*)(wp + 384 + 256);
    float2 s0 = *(const float2*)(vec + offs(0, p0));
    float2 s1 = *(const float2*)(vec + offs(1, p0));
    for (int c = 0; c < kp; c += 2){
        float4 nu0,nu1,nu2,nx0,nx1,nx2; float2 ns0,ns1;
        bool more = (c + 2) < kp;
        if (more){
            const float* r0 = wp + (c+2)*384;
            const float* r1 = wp + (c+3)*384;
            nu0 = *(const float4*)(r0); nu1 = *(const float4*)(r0+128); nu2 = *(const float4*)(r0+256);
            nx0 = *(const float4*)(r1); nx1 = *(const float4*)(r1+128); nx2 = *(const float4*)(r1+256);
            ns0 = *(const float2*)(vec + offs(c+2, p0));
            ns1 = *(const float2*)(vec + offs(c+3, p0));
        }
        FMA8(a0, s0, u0) FMA8(a1, s0, u1) FMA8(a2, s0, u2)
        FMA8(a0, s1, x0) FMA8(a1, s1, x1) FMA8(a2, s1, x2)
        if (more){ u0=nu0;u1=nu1;u2=nu2;x0=nx0;x1=nx1;x2=nx2;s0=ns0;s1=ns1; }
    }
    if (K & 1){
        const float* r = wp + kp*384;
        float2 s2 = *(const float2*)(vec + offs(kp, p0));
        float4 w0 = *(const float4*)(r);
        float4 w1v = *(const float4*)(r + 128);
        float4 w2 = *(const float4*)(r + 256);
        FMA8(a0, s2, w0) FMA8(a1, s2, w1v) FMA8(a2, s2, w2)
    }
}

// fused U-pass for all 4 gates: U4 rows of 512; 1-row lookahead (K=21 small)
__device__ __forceinline__ void mm4_g(const float* __restrict__ gW, int K,
    const float* __restrict__ vec, float a0[2][4], float a1[2][4], float a2[2][4], float a3[2][4],
    int jg, int p0)
{
    const float* wp = gW + 4*jg;
    float4 w0 = *(const float4*)(wp);
    float4 w1v = *(const float4*)(wp + 128);
    float4 w2 = *(const float4*)(wp + 256);
    float4 w3 = *(const float4*)(wp + 384);
    float2 s2 = *(const float2*)(vec + offs(0, p0));
    for (int k = 0; k < K; k++){
        float4 n0,n1,n2,n3; float2 ns;
        bool more = (k + 1) < K;
        if (more){
            const float* r = wp + (k+1)*512;
            n0 = *(const float4*)(r);
            n1 = *(const float4*)(r + 128);
            n2 = *(const float4*)(r + 256);
            n3 = *(const float4*)(r + 384);
            ns = *(const float2*)(vec + offs(k+1, p0));
        }
        FMA8(a0, s2, w0) FMA8(a1, s2, w1v) FMA8(a2, s2, w2) FMA8(a3, s2, w3)
        if (more){ w0=n0; w1v=n1; w2=n2; w3=n3; s2=ns; }
    }
}

__device__ __forceinline__ void write_own(float* buf, const float v[2][4], int j0, int p0){
    #pragma unroll
    for (int jj = 0; jj < 4; jj++){
        *(float2*)(buf + offs(j0 + jj, p0)) = make_float2(v[0][jj], v[1][jj]);
    }
}
__device__ __forceinline__ void read_own(const float* buf, float v[2][4], int j0, int p0){
    #pragma unroll
    for (int jj = 0; jj < 4; jj++){
        float2 q = *(const float2*)(buf + offs(j0 + jj, p0));
        v[0][jj]=q.x; v[1][jj]=q.y;
    }
}

__global__ void chol_kernel(float* __restrict__ Lout)
{
    if (threadIdx.x == 0 && blockIdx.x == 0) {
        double Lc[DIMN][DIMN];
        for (int i = 0; i < DIMN; i++)
            for (int j = 0; j <= i; j++) {
                double s = 0.01 * (0.5 + (i == j ? 0.5 : 0.0));
                for (int t2 = 0; t2 < j; t2++) s -= Lc[i][t2] * Lc[j][t2];
                Lc[i][j] = (i == j) ? sqrt(s) : s / Lc[j][j];
            }
        for (int i = 0; i < DIMN; i++)
            for (int j = 0; j < DIMN; j++)
                Lout[i*DIMN + j] = (j <= i) ? (float)Lc[i][j] : 0.0f;
    }
}

__global__ void transpose_k(const float* __restrict__ wz, const float* __restrict__ wg,
                            const float* __restrict__ wr, const float* __restrict__ wh,
                            float* __restrict__ WT)
{
    int idx = blockIdx.x*256 + threadIdx.x;           // 0..65535
    int q = idx >> 14, r2 = idx & 16383, k = r2 >> 7, j = r2 & 127;
    const float* src = (q==0)? wz : (q==1)? wg : (q==2)? wr : wh;
    WT[(q<<14) + j*UNITS + k] = src[k*UNITS + j];
}

// pack U4 = [uz|ug|ur|uh] 21x512 and W3 = [wz|wg|wr] 128x384
__global__ void pack_u4w3(const float* __restrict__ uz, const float* __restrict__ ug,
                          const float* __restrict__ ur, const float* __restrict__ uh,
                          const float* __restrict__ wz, const float* __restrict__ wg,
                          const float* __restrict__ wr,
                          float* __restrict__ U4, float* __restrict__ W3)
{
    int idx = blockIdx.x*256 + threadIdx.x;
    if (idx < 128*384){
        int k = idx/384, c = idx - k*384, g = c >> 7, j = c & 127;
        const float* s = (g==0)? wz : (g==1)? wg : wr;
        W3[idx] = s[k*UNITS + j];
        return;
    }
    int i2 = idx - 128*384;
    if (i2 < 21*512){
        int k = i2/512, c = i2 - k*512, g = c >> 7, j = c & 127;
        const float* s = (g==0)? uz : (g==1)? ug : (g==2)? ur : uh;
        U4[i2] = s[k*UNITS + j];
    }
}

#define DGM_PARAMS \
    const float* __restrict__ inputs, const float* __restrict__ eps, \
    const float* __restrict__ w1, const float* __restrict__ b1, \
    const float* __restrict__ uz, const float* __restrict__ bz, \
    const float* __restrict__ ug, const float* __restrict__ bg, \
    const float* __restrict__ ur, const float* __restrict__ br, \
    const float* __restrict__ uh, const float* __restrict__ wh, const float* __restrict__ bh, \
    const float* __restrict__ wv, const float* __restrict__ bv, \
    const float* __restrict__ Lm, const float* __restrict__ WT, \
    const float* __restrict__ U4, const float* __restrict__ W3, \
    float* __restrict__ gws, \
    float* __restrict__ fp1, float* __restrict__ val1, float* __restrict__ val2, \
    float* __restrict__ t12acc

#define DGM_ARGS inputs, eps, w1, b1, uz, bz, ug, bg, ur, br, uh, wh, bh, wv, bv, \
    Lm, WT, U4, W3, gws, fp1, val1, val2, t12acc

template<int SG>
__device__ __forceinline__ void dgm_body(float* lds, DGM_PARAMS)
{
    float* S0 = lds + L_S0;
    float* S1 = lds + L_S1;
    float* S2 = lds + L_S2;
    float* Db = lds + L_D;
    float* xT = lds + L_XT;
    float* Vb = lds + L_VB;

    const int t  = threadIdx.x;
    const int jg = t & 31;
    const int pg = t >> 5;          // 0..15
    const int p0 = pg * 2;
    const int j0 = jg * 4;
    const int P0 = blockIdx.x * TM;
    const int type = (P0 < NN) ? 0 : (P0 < NN + MCN*NN) ? 1 : 2;
    int base_n = 0, mrow = 0;
    if (type == 1){ int q = P0 - NN; mrow = q >> 11; base_n = q & (NN-1); }

    float* gb = gws + (size_t)blockIdx.x * GB_STRIDE;

    // ---- build x tile (and violation V for type 1) ----
    {
        int p = t & 31, kq = t >> 5;            // kq 0..15
        #pragma unroll
        for (int ki = 0; ki < 2; ki++){
            int k = kq + 16*ki;
            if (k > DIMN) break;
            float xv;
            if (type == 0){
                xv = inputs[(P0 + p)*DD + k];
            } else if (type == 2){
                xv = inputs[(NN + (P0 - NN - MCN*NN) + p)*DD + k];
            } else {
                int n = base_n + p;
                float x1v = inputs[n*DD + k];
                if (k == DIMN) xv = x1v;
                else {
                    const float* ep = eps + (size_t)(mrow*NN + n)*DIMN;
                    float a = x1v;
                    for (int d = 0; d < DIMN; d++) a = fmaf(ep[d], Lm[k*DIMN + d], a);
                    float viol = a * (SIGC * x1v);
                    Vb[offs(k, p)] = viol;
                    xv = x1v + viol;
                }
            }
            xT[offs(k, p)] = xv;
        }
    }
    __syncthreads();

    // ---- forward ----
    float s_own[2][4];
    {
        float acc[2][4];
        float4 b = *(const float4*)(b1 + j0);
        #pragma unroll
        for (int p = 0; p < 2; p++){ acc[p][0]=b.x; acc[p][1]=b.y; acc[p][2]=b.z; acc[p][3]=b.w; }
        mm_g(w1, DD, xT, acc, jg, p0);
        ELT24(s_own[p][jj] = tanhf(acc[p][jj]))
        write_own(S0, s_own, j0, p0);
        __syncthreads();
    }

    float zt[2][4], gt[2][4], rt[2][4], ht[2][4];

#define GATES(SIN, SMUL) \
    { \
    float4 q0 = *(const float4*)(bz + j0), q1 = *(const float4*)(bg + j0); \
    float4 q2 = *(const float4*)(br + j0), q3 = *(const float4*)(bh + j0); \
    float az[2][4], ag[2][4], ar[2][4], ah[2][4]; \
    _Pragma("unroll") for (int p = 0; p < 2; p++){ \
        az[p][0]=q0.x; az[p][1]=q0.y; az[p][2]=q0.z; az[p][3]=q0.w; \
        ag[p][0]=q1.x; ag[p][1]=q1.y; ag[p][2]=q1.z; ag[p][3]=q1.w; \
        ar[p][0]=q2.x; ar[p][1]=q2.y; ar[p][2]=q2.z; ar[p][3]=q2.w; \
        ah[p][0]=q3.x; ah[p][1]=q3.y; ah[p][2]=q3.z; ah[p][3]=q3.w; } \
    mm4_g(U4, DD, xT, az, ag, ar, ah, jg, p0); \
    mm3_g(W3, UNITS, SIN, az, ag, ar, jg, p0); \
    ELT24(zt[p][jj]=tanhf(az[p][jj]); gt[p][jj]=tanhf(ag[p][jj]); rt[p][jj]=tanhf(ar[p][jj])) \
    { float tt[2][4]; ELT24(tt[p][jj] = SMUL[p][jj]*rt[p][jj]) \
      __syncthreads(); write_own(Db, tt, j0, p0); __syncthreads(); } \
    mm_g(wh, UNITS, Db, ah, jg, p0); \
    ELT24(ht[p][jj] = tanhf(ah[p][jj])) \
    }

#define FWD_LAYER(SIN) \
    GATES(SIN, s_own) \
    ELT24(s_own[p][jj] = (1.f - gt[p][jj])*ht[p][jj] + zt[p][jj]*s_own[p][jj])

    FWD_LAYER(S0)                      // layer 1
    write_own(S1, s_own, j0, p0);
    __syncthreads();
    FWD_LAYER(S1)                      // layer 2 -- stash gates for backward
    if (SG && type != 2){
        write_own(gb,         zt, j0, p0);
        write_own(gb + 4096,  gt, j0, p0);
        write_own(gb + 8192,  rt, j0, p0);
        write_own(gb + 12288, ht, j0, p0);
    }
    write_own(S2, s_own, j0, p0);
    __syncthreads();
    FWD_LAYER(S2)                      // layer 3 -- zt/gt/rt/ht live into backward

    // ---- value head ----
    {
        float4 wv4 = *(const float4*)(wv + j0);
        float vs0 = s_own[0][0]*wv4.x + s_own[0][1]*wv4.y + s_own[0][2]*wv4.z + s_own[0][3]*wv4.w;
        float vs1 = s_own[1][0]*wv4.x + s_own[1][1]*wv4.y + s_own[1][2]*wv4.z + s_own[1][3]*wv4.w;
        __syncthreads();   // layer-3 mm_g(wh) readers of Db done
        *(float2*)(Db + jg*32 + p0) = make_float2(vs0, vs1);
        __syncthreads();
        if (t < TM){
            float v = bv[0];
            for (int j2 = 0; j2 < 32; j2++) v += Db[j2*32 + t];
            if (type == 0) val1[P0 + t] = v;
            else if (type == 2) val2[P0 + t - NN - MCN*NN] = v;
        }
        __syncthreads();
    }
    if (type == 2) return;

    // ---- backward ----
    float ds[2][4];
    {
        float4 wv4 = *(const float4*)(wv + j0);
        #pragma unroll
        for (int p = 0; p < 2; p++){ ds[p][0]=wv4.x; ds[p][1]=wv4.y; ds[p][2]=wv4.z; ds[p][3]=wv4.w; }
    }
    float proj[2] = {0.f, 0.f};
    float dxp[2] = {0.f, 0.f};
    const int pi = t >> 4, il = t & 15;   // pi 0..31, il 0..15

    const float* WTz = WT;
    const float* WTg = WT + 16384;
    const float* WTr = WT + 2*16384;
    const float* WTh = WT + 3*16384;

#define DX_DOT(UMAT) \
    { _Pragma("unroll") for (int ii = 0; ii < 2; ii++){ \
        int i = il + 16*ii; \
        if (i < DD){ \
            const float* Urow = UMAT + i*UNITS; \
            float a = 0.f; \
            for (int j2 = 0; j2 < UNITS; j2++) a = fmaf(Db[offs(j2, pi)], Urow[j2], a); \
            dxp[ii] += a; \
        } } }

#define PROJ_FOLD(UMAT, SEL) \
    { float uv[2][4]; \
      ELT24(uv[p][jj] = 0.f) \
      mm_g(UMAT, DIMN, Vb, uv, jg, p0); \
      ELT24(proj[p] += uv[p][jj]*SEL[p][jj]) }

// MODE 0: gates live in zt/gt/rt/ht; MODE 1: recompute; MODE 2: load from global stash
#define BWD_LAYER(SLP, SINP, MODE) \
    { \
    float sl[2][4]; \
    read_own(SLP, sl, j0, p0); \
    if (MODE == 1){ GATES(SINP, sl) } \
    else if (MODE == 2){ \
        read_own(gb,         zt, j0, p0); \
        read_own(gb + 4096,  gt, j0, p0); \
        read_own(gb + 8192,  rt, j0, p0); \
        read_own(gb + 12288, ht, j0, p0); \
    } \
    float dhp[2][4], dzp[2][4], dgp[2][4], dsn[2][4]; \
    ELT24(float d=ds[p][jj]; float g=gt[p][jj]; float h=ht[p][jj]; float z=zt[p][jj]; float s=sl[p][jj]; \
        dhp[p][jj] = d*(1.f - g)*(1.f - h*h); \
        dgp[p][jj] = -d*h*(1.f - g*g); \
        dzp[p][jj] = d*s*(1.f - z*z); \
        dsn[p][jj] = d*z) \
    if (type == 1){ \
        PROJ_FOLD(uh, dhp) \
        PROJ_FOLD(uz, dzp) \
        PROJ_FOLD(ug, dgp) \
    } \
    __syncthreads(); write_own(Db, dhp, j0, p0); __syncthreads(); \
    if (type == 0){ DX_DOT(uh) } \
    float dsr[2][4]; \
    ELT24(dsr[p][jj] = 0.f) \
    mm_g(WTh, UNITS, Db, dsr, jg, p0); \
    float drp[2][4]; \
    ELT24(float dr=dsr[p][jj]; float r=rt[p][jj]; float s=sl[p][jj]; \
        drp[p][jj] = dr*s*(1.f - r*r); \
        dsn[p][jj] += dr*r) \
    if (type == 1){ PROJ_FOLD(ur, drp) } \
    __syncthreads(); write_own(Db, dzp, j0, p0); __syncthreads(); \
    if (type == 0){ DX_DOT(uz) } \
    mm_g(WTz, UNITS, Db, dsn, jg, p0); \
    __syncthreads(); write_own(Db, dgp, j0, p0); __syncthreads(); \
    if (type == 0){ DX_DOT(ug) } \
    mm_g(WTg, UNITS, Db, dsn, jg, p0); \
    __syncthreads(); write_own(Db, drp, j0, p0); __syncthreads(); \
    if (type == 0){ DX_DOT(ur) } \
    mm_g(WTr, UNITS, Db, dsn, jg, p0); \
    ELT24(ds[p][jj] = dsn[p][jj]) \
    }

    BWD_LAYER(S2, S2, 0)               // layer 3: gates live from FWD_LAYER(S2)
    BWD_LAYER(S1, S1, (SG ? 2 : 1))    // layer 2: stashed gates (or recompute)
    BWD_LAYER(S0, S0, 1)               // layer 1: recompute

    // first layer backward + epilogue
    {
        float s0l[2][4];
        read_own(S0, s0l, j0, p0);
        float v0[2][4];
        ELT24(v0[p][jj] = ds[p][jj]*(1.f - s0l[p][jj]*s0l[p][jj]))

        if (type == 1){
            PROJ_FOLD(w1, v0)
            __syncthreads();   // mm_g(WTr) readers of Db done
            *(float2*)(Db + jg*32 + p0) = make_float2(proj[0], proj[1]);
            __syncthreads();
            if (t < TM){
                float s = 0.f;
                for (int j2 = 0; j2 < 32; j2++) s += Db[j2*32 + t];
                atomicAdd(t12acc + base_n + t, s);
            }
        } else {
            __syncthreads(); write_own(Db, v0, j0, p0); __syncthreads();
            DX_DOT(w1)
            #pragma unroll
            for (int ii = 0; ii < 2; ii++){
                int i = il + 16*ii;
                if (i < DD) fp1[(P0 + pi)*DD + i] = dxp[ii];
            }
        }
    }
}

__global__ __launch_bounds__(NTH, 4) void dgm_sg(DGM_PARAMS){
    __shared__ float lds[L_TOT];
    dgm_body<1>(lds, DGM_ARGS);
}
__global__ __launch_bounds__(NTH, 4) void dgm_rc(DGM_PARAMS){
    __shared__ float lds[L_TOT];
    dgm_body<0>(lds, DGM_ARGS);
}

__global__ void finalize_k(const float* __restrict__ inputs, const float* __restrict__ eps,
    const float* __restrict__ Lm, const float* __restrict__ fp1, const float* __restrict__ val1,
    const float* __restrict__ val2, const float* __restrict__ t12acc, float* __restrict__ out)
{
    int n = blockIdx.x*256 + threadIdx.x;
    if (n >= NN) return;
    float fp[DD];
    #pragma unroll
    for (int k = 0; k < DD; k++) fp[k] = fp1[n*DD + k];
    float t11 = fp[DIMN];
    #pragma unroll
    for (int k = 0; k < DIMN; k++) t11 = fmaf(MUC*inputs[n*DD + k], fp[k], t11);
    float esum[DIMN];
    #pragma unroll
    for (int d = 0; d < DIMN; d++){
        float a = 0.f;
        for (int m = 0; m < MCN; m++) a += eps[(size_t)(m*NN + n)*DIMN + d];
        esum[d] = a;
    }
    float t12b = 0.f;
    #pragma unroll
    for (int k = 0; k < DIMN; k++){
        float loc = inputs[n*DD + k];
        float ssum = (float)MCN * loc;
        #pragma unroll
        for (int d = 0; d < DIMN; d++) ssum = fmaf(esum[d], Lm[k*DIMN + d], ssum);
        float vsum = ssum * (SIGC*loc);
        t12b = fmaf(fp[k], vsum, t12b);
    }
    float term12 = (t12acc[n] - t12b) * (1.0f/(DELTAC*(float)MCN));
    out[n] = t11 + 0.5f*term12 - RC*val1[n];

    float prod = 1.f;
    #pragma unroll
    for (int k = 0; k < DIMN; k++) prod *= inputs[(NN + n)*DD + k];
    float payoff = powf(prod, 1.0f/(float)DIMN);
    if (!(payoff > 0.f)) payoff = 0.f;
    out[NN + n] = val2[n] - payoff;
}

extern "C" void kernel_launch(void* const* d_in, const int* in_sizes, int n_in,
                              void* d_out, int out_size, void* d_ws, size_t ws_size,
                              hipStream_t stream)
{
    const float* inputs = (const float*)d_in[0];
    const float* eps    = (const float*)d_in[1];
    const float* w1     = (const float*)d_in[2];
    const float* b1     = (const float*)d_in[3];
    const float* uz     = (const float*)d_in[4];
    const float* wz     = (const float*)d_in[5];
    const float* bz     = (const float*)d_in[6];
    const float* ug     = (const float*)d_in[7];
    const float* wg     = (const float*)d_in[8];
    const float* bg     = (const float*)d_in[9];
    const float* urr    = (const float*)d_in[10];
    const float* wr     = (const float*)d_in[11];
    const float* br     = (const float*)d_in[12];
    const float* uh     = (const float*)d_in[13];
    const float* wh     = (const float*)d_in[14];
    const float* bh     = (const float*)d_in[15];
    const float* wv     = (const float*)d_in[16];
    const float* bv     = (const float*)d_in[17];

    float* ws    = (float*)d_ws;
    float* Lm    = ws + OFF_L;
    float* WT    = ws + OFF_WT;
    float* U4    = ws + OFF_U4;
    float* W3    = ws + OFF_W3;
    float* fp1   = ws + OFF_FP1;
    float* val1  = ws + OFF_VAL1;
    float* val2  = ws + OFF_VAL2;
    float* t12   = ws + OFF_T12;
    float* gates = ws + OFF_GATES;
    float* out   = (float*)d_out;

    hipMemsetAsync(t12, 0, NN*sizeof(float), stream);
    hipLaunchKernelGGL(chol_kernel, dim3(1), dim3(64), 0, stream, Lm);
    hipLaunchKernelGGL(transpose_k, dim3(256), dim3(256), 0, stream, wz, wg, wr, wh, WT);
    hipLaunchKernelGGL(pack_u4w3, dim3(234), dim3(256), 0, stream, uz, ug, urr, uh, wz, wg, wr, U4, W3);

    size_t need_bytes = ((size_t)OFF_GATES + (size_t)NBLK * (size_t)GB_STRIDE) * sizeof(float);
    if (ws_size >= need_bytes){
        hipLaunchKernelGGL(dgm_sg, dim3(NBLK), dim3(NTH), 0, stream,
            inputs, eps, w1, b1, uz, bz, ug, bg, urr, br, uh, wh, bh, wv, bv,
            Lm, WT, U4, W3, gates, fp1, val1, val2, t12);
    } else {
        hipLaunchKernelGGL(dgm_rc, dim3(NBLK), dim3(NTH), 0, stream,
            inputs, eps, w1, b1, uz, bz, ug, bg, urr, br, uh, wh, bh, wv, bv,
            Lm, WT, U4, W3, gates, fp1, val1, val2, t12);
    }
    hipLaunchKernelGGL(finalize_k, dim3(8), dim3(256), 0, stream,
        inputs, eps, Lm, fp1, val1, val2, t12, out);
}

// Round 5
// 2850.704 us; speedup vs baseline: 2.4674x; 2.4674x over previous
//
#include <hip/hip_runtime.h>
#include <math.h>

#define DIMN 20
#define DD 21
#define NN 2048
#define MCN 32
#define UNITS 128
#define SIGC 0.2f
#define MUC 0.05f
#define RC 0.05f
#define DELTAC 0.01f

#define TM 32
#define KCH 8
#define KC3 4
#define PTOT (NN + MCN*NN + NN)
#define NBLK (PTOT/TM)

// ws layout (floats)
#define OFF_L 0
#define OFF_WT 512
#define OFF_UZGR (OFF_WT + 4*16384)      // 66048 : packed [Uz|Ug|Ur] 21x384 (pad to 8192)
#define OFF_WZGR (OFF_UZGR + 8192)       // 74240 : packed [Wz|Wg|Wr] 128x384
#define OFF_FP1  (OFF_WZGR + 49152)      // 123392
#define OFF_VAL1 (OFF_FP1 + NN*DD)       // 166400
#define OFF_VAL2 (OFF_VAL1 + NN)         // 168448
#define OFF_T12  (OFF_VAL2 + NN)         // 170496
#define OFF_GATES (OFF_T12 + NN)         // 172544 : per-block stash

// per-block stash (floats), per-thread-linear layout
#define ST_S1 0
#define ST_Z  4096
#define ST_G  8192
#define ST_R  12288
#define ST_H  16384
#define GB_STRIDE 20480

// LDS layouts (floats)
// SG: S0 0 | Db 4096 | Wc 8192 | xT 11264 | Vb 11936 | tot 12608 (50.4KB -> 3 blk/CU)
// RC: S0 0 | S1 4096 | Db 8192 | Wc 12288 | xT 15360 | Vb 16032 | tot 16704 (66.8KB -> 2)
#define L_TOT_SG 12608
#define L_TOT_RC 16704

#define ELT44(...) _Pragma("unroll") for (int p = 0; p < 4; p++){ _Pragma("unroll") for (int jj = 0; jj < 4; jj++){ __VA_ARGS__; } }

__device__ __forceinline__ int offq(int row, int p0){
    return row*32 + ((p0 + 4*(row&7)) & 31);
}
__device__ __forceinline__ int offs(int row, int p){
    return row*32 + (((p & 28) + 4*(row&7)) & 31) + (p & 3);
}

// stage `units` 16B-units from global g into contiguous LDS wc
__device__ __forceinline__ void stageW(const float* __restrict__ g, float* wc, int units){
#if defined(__has_builtin) && __has_builtin(__builtin_amdgcn_global_load_lds)
    int lane = threadIdx.x & 63, wid = threadIdx.x >> 6;
    for (int base = wid*64; base < units; base += 256){
        int u = base + lane;
        if (u < units)
            __builtin_amdgcn_global_load_lds(
                (const __attribute__((address_space(1))) unsigned int*)(g) + (size_t)u*4,
                (__attribute__((address_space(3))) unsigned int*)(wc) + (size_t)base*4,
                16, 0, 0);
    }
#else
    int t = threadIdx.x;
    for (int u = t; u < units; u += 256){
        float4 v = *(const float4*)(g + u*4);
        *(float4*)(wc + u*4) = v;
    }
#endif
}

#define FMA16(acc, s4, w4) \
  acc[0][0]=fmaf(s4.x,w4.x,acc[0][0]); acc[0][1]=fmaf(s4.x,w4.y,acc[0][1]); \
  acc[0][2]=fmaf(s4.x,w4.z,acc[0][2]); acc[0][3]=fmaf(s4.x,w4.w,acc[0][3]); \
  acc[1][0]=fmaf(s4.y,w4.x,acc[1][0]); acc[1][1]=fmaf(s4.y,w4.y,acc[1][1]); \
  acc[1][2]=fmaf(s4.y,w4.z,acc[1][2]); acc[1][3]=fmaf(s4.y,w4.w,acc[1][3]); \
  acc[2][0]=fmaf(s4.z,w4.x,acc[2][0]); acc[2][1]=fmaf(s4.z,w4.y,acc[2][1]); \
  acc[2][2]=fmaf(s4.z,w4.z,acc[2][2]); acc[2][3]=fmaf(s4.z,w4.w,acc[2][3]); \
  acc[3][0]=fmaf(s4.w,w4.x,acc[3][0]); acc[3][1]=fmaf(s4.w,w4.y,acc[3][1]); \
  acc[3][2]=fmaf(s4.w,w4.z,acc[3][2]); acc[3][3]=fmaf(s4.w,w4.w,acc[3][3]);

// acc[p][jj] += sum_k vec[k][p0+p] * W[k][4jg+jj]; staged LDS double-buffer (R1-proven)
__device__ __forceinline__ void mm_acc(const float* __restrict__ gW, int K,
    const float* __restrict__ vec, float acc[4][4], float* __restrict__ Wc,
    int jg, int p0)
{
    int nch = (K + KCH - 1) / KCH;
    {
        int r0 = (K < KCH) ? K : KCH;
        stageW(gW, Wc, r0*32);
    }
    for (int c = 0; c < nch; c++){
        __syncthreads();
        if (c + 1 < nch){
            int c0n = (c+1)*KCH;
            int rn = K - c0n; if (rn > KCH) rn = KCH;
            stageW(gW + c0n*UNITS, Wc + ((c+1)&1)*KCH*UNITS, rn*32);
        }
        int c0 = c*KCH;
        int rows = K - c0; if (rows > KCH) rows = KCH;
        const float* wb = Wc + (c&1)*KCH*UNITS;
        if (rows == KCH){
            #pragma unroll
            for (int kk = 0; kk < KCH; kk++){
                int k = c0 + kk;
                float4 w4 = *(const float4*)(wb + kk*UNITS + 4*jg);
                float4 s4 = *(const float4*)(vec + offq(k, p0));
                FMA16(acc, s4, w4)
            }
        } else {
            for (int kk = 0; kk < rows; kk++){
                int k = c0 + kk;
                float4 w4 = *(const float4*)(wb + kk*UNITS + 4*jg);
                float4 s4 = *(const float4*)(vec + offq(k, p0));
                FMA16(acc, s4, w4)
            }
        }
    }
    __syncthreads();
}

// fused z,g,r: W packed rows of 384 ([z|g|r]); staged (R1-proven)
__device__ __forceinline__ void mm3_acc(const float* __restrict__ gW, int K,
    const float* __restrict__ vec, float az[4][4], float ag[4][4], float ar[4][4],
    float* __restrict__ Wc, int jg, int p0)
{
    int nch = (K + KC3 - 1) / KC3;
    {
        int r0 = (K < KC3) ? K : KC3;
        stageW(gW, Wc, r0*96);
    }
    for (int c = 0; c < nch; c++){
        __syncthreads();
        if (c + 1 < nch){
            int c0n = (c+1)*KC3;
            int rn = K - c0n; if (rn > KC3) rn = KC3;
            stageW(gW + c0n*384, Wc + ((c+1)&1)*(KC3*384), rn*96);
        }
        int c0 = c*KC3;
        int rows = K - c0; if (rows > KC3) rows = KC3;
        const float* wb = Wc + (c&1)*(KC3*384);
        if (rows == KC3){
            #pragma unroll
            for (int kk = 0; kk < KC3; kk++){
                int k = c0 + kk;
                const float* wrow = wb + kk*384 + 4*jg;
                float4 s4  = *(const float4*)(vec + offq(k, p0));
                float4 wz4 = *(const float4*)(wrow);
                float4 wg4 = *(const float4*)(wrow + 128);
                float4 wr4 = *(const float4*)(wrow + 256);
                FMA16(az, s4, wz4)
                FMA16(ag, s4, wg4)
                FMA16(ar, s4, wr4)
            }
        } else {
            for (int kk = 0; kk < rows; kk++){
                int k = c0 + kk;
                const float* wrow = wb + kk*384 + 4*jg;
                float4 s4  = *(const float4*)(vec + offq(k, p0));
                float4 wz4 = *(const float4*)(wrow);
                float4 wg4 = *(const float4*)(wrow + 128);
                float4 wr4 = *(const float4*)(wrow + 256);
                FMA16(az, s4, wz4)
                FMA16(ag, s4, wg4)
                FMA16(ar, s4, wr4)
            }
        }
    }
    __syncthreads();
}

__device__ __forceinline__ void write_own(float* buf, const float v[4][4], int j0, int p0){
    #pragma unroll
    for (int jj = 0; jj < 4; jj++){
        int j = j0 + jj;
        float4 q = make_float4(v[0][jj], v[1][jj], v[2][jj], v[3][jj]);
        *(float4*)(buf + offq(j, p0)) = q;
    }
}
__device__ __forceinline__ void read_own(const float* buf, float v[4][4], int j0, int p0){
    #pragma unroll
    for (int jj = 0; jj < 4; jj++){
        int j = j0 + jj;
        float4 q = *(const float4*)(buf + offq(j, p0));
        v[0][jj]=q.x; v[1][jj]=q.y; v[2][jj]=q.z; v[3][jj]=q.w;
    }
}
// per-thread-linear global stash (coalesced; only same thread reads back)
__device__ __forceinline__ void stash_w(float* buf, const float v[4][4], int t){
    #pragma unroll
    for (int jj = 0; jj < 4; jj++)
        *(float4*)(buf + (jj*256 + t)*4) = make_float4(v[0][jj], v[1][jj], v[2][jj], v[3][jj]);
}
__device__ __forceinline__ void stash_r(const float* buf, float v[4][4], int t){
    #pragma unroll
    for (int jj = 0; jj < 4; jj++){
        float4 q = *(const float4*)(buf + (jj*256 + t)*4);
        v[0][jj]=q.x; v[1][jj]=q.y; v[2][jj]=q.z; v[3][jj]=q.w;
    }
}

// out = tanh(bias + x@U + vec@W)   (h gate)
__device__ __forceinline__ void gate_f(const float* __restrict__ U, const float* __restrict__ W,
    const float* __restrict__ bias, const float* __restrict__ xT, const float* __restrict__ Sin,
    float* __restrict__ Wc, float out[4][4], int jg, int p0, int j0)
{
    float acc[4][4];
    float4 b = *(const float4*)(bias + j0);
    #pragma unroll
    for (int p = 0; p < 4; p++){ acc[p][0]=b.x; acc[p][1]=b.y; acc[p][2]=b.z; acc[p][3]=b.w; }
    mm_acc(U, DD, xT, acc, Wc, jg, p0);
    mm_acc(W, UNITS, Sin, acc, Wc, jg, p0);
    #pragma unroll
    for (int p = 0; p < 4; p++)
        #pragma unroll
        for (int jj = 0; jj < 4; jj++) out[p][jj] = tanhf(acc[p][jj]);
}

// fused z,g,r gates
__device__ __forceinline__ void gate3_f(const float* __restrict__ Uzgr, const float* __restrict__ Wzgr,
    const float* __restrict__ bz, const float* __restrict__ bg, const float* __restrict__ br,
    const float* __restrict__ xT, const float* __restrict__ Sin,
    float* __restrict__ Wc, float zt[4][4], float gt[4][4], float rt[4][4],
    int jg, int p0, int j0)
{
    float4 b0 = *(const float4*)(bz + j0);
    float4 b1 = *(const float4*)(bg + j0);
    float4 b2 = *(const float4*)(br + j0);
    #pragma unroll
    for (int p = 0; p < 4; p++){
        zt[p][0]=b0.x; zt[p][1]=b0.y; zt[p][2]=b0.z; zt[p][3]=b0.w;
        gt[p][0]=b1.x; gt[p][1]=b1.y; gt[p][2]=b1.z; gt[p][3]=b1.w;
        rt[p][0]=b2.x; rt[p][1]=b2.y; rt[p][2]=b2.z; rt[p][3]=b2.w;
    }
    mm3_acc(Uzgr, DD, xT, zt, gt, rt, Wc, jg, p0);
    mm3_acc(Wzgr, UNITS, Sin, zt, gt, rt, Wc, jg, p0);
    ELT44(zt[p][jj]=tanhf(zt[p][jj]); gt[p][jj]=tanhf(gt[p][jj]); rt[p][jj]=tanhf(rt[p][jj]))
}

__global__ void chol_kernel(float* __restrict__ Lout)
{
    if (threadIdx.x == 0 && blockIdx.x == 0) {
        double Lc[DIMN][DIMN];
        for (int i = 0; i < DIMN; i++)
            for (int j = 0; j <= i; j++) {
                double s = 0.01 * (0.5 + (i == j ? 0.5 : 0.0));
                for (int t2 = 0; t2 < j; t2++) s -= Lc[i][t2] * Lc[j][t2];
                Lc[i][j] = (i == j) ? sqrt(s) : s / Lc[j][j];
            }
        for (int i = 0; i < DIMN; i++)
            for (int j = 0; j < DIMN; j++)
                Lout[i*DIMN + j] = (j <= i) ? (float)Lc[i][j] : 0.0f;
    }
}

__global__ void transpose_k(const float* __restrict__ wz, const float* __restrict__ wg,
                            const float* __restrict__ wr, const float* __restrict__ wh,
                            float* __restrict__ WT)
{
    int idx = blockIdx.x*256 + threadIdx.x;           // 0..65535
    int q = idx >> 14, r2 = idx & 16383, k = r2 >> 7, j = r2 & 127;
    const float* src = (q==0)? wz : (q==1)? wg : (q==2)? wr : wh;
    WT[(q<<14) + j*UNITS + k] = src[k*UNITS + j];
}

// pack [Uz|Ug|Ur] 21x384 and [Wz|Wg|Wr] 128x384
__global__ void pack_zgr(const float* __restrict__ uz, const float* __restrict__ ug,
                         const float* __restrict__ ur,
                         const float* __restrict__ wz, const float* __restrict__ wg,
                         const float* __restrict__ wr,
                         float* __restrict__ Uzgr, float* __restrict__ Wzgr)
{
    int idx = blockIdx.x*256 + threadIdx.x;
    if (idx < 128*384){
        int k = idx/384, c = idx - k*384, g = c >> 7, j = c & 127;
        const float* s = (g==0)? wz : (g==1)? wg : wr;
        Wzgr[idx] = s[k*UNITS + j];
        return;
    }
    int i2 = idx - 128*384;
    if (i2 < 21*384){
        int k = i2/384, c = i2 - k*384, g = c >> 7, j = c & 127;
        const float* s = (g==0)? uz : (g==1)? ug : ur;
        Uzgr[i2] = s[k*UNITS + j];
    }
}

#define DGM_PARAMS \
    const float* __restrict__ inputs, const float* __restrict__ eps, \
    const float* __restrict__ w1, const float* __restrict__ b1, \
    const float* __restrict__ uz, const float* __restrict__ bz, \
    const float* __restrict__ ug, const float* __restrict__ bg, \
    const float* __restrict__ ur, const float* __restrict__ br, \
    const float* __restrict__ uh, const float* __restrict__ wh, const float* __restrict__ bh, \
    const float* __restrict__ wv, const float* __restrict__ bv, \
    const float* __restrict__ Lm, const float* __restrict__ WT, \
    const float* __restrict__ Uzgr, const float* __restrict__ Wzgr, \
    float* __restrict__ gws, \
    float* __restrict__ fp1, float* __restrict__ val1, float* __restrict__ val2, \
    float* __restrict__ t12acc

#define DGM_ARGS inputs, eps, w1, b1, uz, bz, ug, bg, ur, br, uh, wh, bh, wv, bv, \
    Lm, WT, Uzgr, Wzgr, gws, fp1, val1, val2, t12acc

template<int SG>
__device__ __forceinline__ void dgm_body(float* lds, DGM_PARAMS)
{
    float* S0 = lds;
    float* S1 = SG ? lds : lds + 4096;          // RC only
    float* Db = lds + (SG ? 4096 : 8192);
    float* Wc = lds + (SG ? 8192 : 12288);
    float* xT = lds + (SG ? 11264 : 15360);
    float* Vb = lds + (SG ? 11936 : 16032);

    const int t  = threadIdx.x;
    const int jg = t & 31;
    const int pg = t >> 5;
    const int p0 = pg * 4;
    const int j0 = jg * 4;
    const int P0 = blockIdx.x * TM;
    const int type = (P0 < NN) ? 0 : (P0 < NN + MCN*NN) ? 1 : 2;
    int base_n = 0, mrow = 0;
    if (type == 1){ int q = P0 - NN; mrow = q >> 11; base_n = q & (NN-1); }

    float* gb = gws + (size_t)blockIdx.x * GB_STRIDE;

    // ---- build x tile (and violation V for type 1) ----
    {
        int p = t & 31, kq = t >> 5;
        for (int ki = 0; ki < 3; ki++){
            int k = kq + 8*ki;
            if (k > DIMN) break;
            float xv;
            if (type == 0){
                xv = inputs[(P0 + p)*DD + k];
            } else if (type == 2){
                xv = inputs[(NN + (P0 - NN - MCN*NN) + p)*DD + k];
            } else {
                int n = base_n + p;
                float x1v = inputs[n*DD + k];
                if (k == DIMN) xv = x1v;
                else {
                    const float* ep = eps + (size_t)(mrow*NN + n)*DIMN;
                    float a = x1v;
                    for (int d = 0; d < DIMN; d++) a = fmaf(ep[d], Lm[k*DIMN + d], a);
                    float viol = a * (SIGC * x1v);
                    Vb[offs(k, p)] = viol;
                    xv = x1v + viol;
                }
            }
            xT[offs(k, p)] = xv;
        }
    }
    __syncthreads();

    // ---- forward ----
    float s_own[4][4];
    {
        float acc[4][4];
        float4 b = *(const float4*)(b1 + j0);
        #pragma unroll
        for (int p = 0; p < 4; p++){ acc[p][0]=b.x; acc[p][1]=b.y; acc[p][2]=b.z; acc[p][3]=b.w; }
        mm_acc(w1, DD, xT, acc, Wc, jg, p0);
        ELT44(s_own[p][jj] = tanhf(acc[p][jj]))
        write_own(S0, s_own, j0, p0);
        __syncthreads();
    }

    float zt[4][4], gt[4][4], rt[4][4], ht[4][4];

#define GATES(SIN, SMUL) \
    gate3_f(Uzgr, Wzgr, bz, bg, br, xT, SIN, Wc, zt, gt, rt, jg, p0, j0); \
    { float tt[4][4]; ELT44(tt[p][jj] = SMUL[p][jj]*rt[p][jj]) write_own(Db, tt, j0, p0); } \
    gate_f(uh, wh, bh, xT, Db, Wc, ht, jg, p0, j0);

#define FWD_LAYER(SIN) \
    GATES(SIN, s_own) \
    ELT44(s_own[p][jj] = (1.f - gt[p][jj])*ht[p][jj] + zt[p][jj]*s_own[p][jj])

    FWD_LAYER(S0)                      // layer 1
    if (SG){ if (type != 2) stash_w(gb + ST_S1, s_own, t); }
    else   { write_own(S1, s_own, j0, p0); }
    write_own(Db, s_own, j0, p0);      // Sin for layer 2 (safe: wh-pass sync'd)

    FWD_LAYER(Db)                      // layer 2
    if (SG && type != 2){
        stash_w(gb + ST_Z, zt, t); stash_w(gb + ST_G, gt, t);
        stash_w(gb + ST_R, rt, t); stash_w(gb + ST_H, ht, t);
    }
    float s2r[4][4];
    ELT44(s2r[p][jj] = s_own[p][jj])
    write_own(Db, s_own, j0, p0);      // Sin for layer 3

    FWD_LAYER(Db)                      // layer 3 -- zt/gt/rt/ht stay live

    // ---- value head ----
    {
        float4 wv4 = *(const float4*)(wv + j0);
        float vs[4];
        #pragma unroll
        for (int p = 0; p < 4; p++)
            vs[p] = s_own[p][0]*wv4.x + s_own[p][1]*wv4.y + s_own[p][2]*wv4.z + s_own[p][3]*wv4.w;
        __syncthreads();
        *(float4*)(Db + jg*32 + p0) = make_float4(vs[0], vs[1], vs[2], vs[3]);
        __syncthreads();
        if (t < TM){
            float v = bv[0];
            for (int j2 = 0; j2 < 32; j2++) v += Db[j2*32 + t];
            if (type == 0) val1[P0 + t] = v;
            else if (type == 2) val2[P0 + t - NN - MCN*NN] = v;
        }
        __syncthreads();
    }
    if (type == 2) return;

    // ---- backward ----
    float ds[4][4];
    {
        float4 wv4 = *(const float4*)(wv + j0);
        #pragma unroll
        for (int p = 0; p < 4; p++){ ds[p][0]=wv4.x; ds[p][1]=wv4.y; ds[p][2]=wv4.z; ds[p][3]=wv4.w; }
    }
    float proj[4] = {0.f, 0.f, 0.f, 0.f};
    float dxp[3] = {0.f, 0.f, 0.f};
    const int pi = t >> 3, il = t & 7;

    const float* WTz = WT;
    const float* WTg = WT + 16384;
    const float* WTr = WT + 2*16384;
    const float* WTh = WT + 3*16384;

#define DX_DOT(UMAT) \
    { _Pragma("unroll") for (int ii = 0; ii < 3; ii++){ \
        int i = il + 8*ii; \
        if (i < DD){ \
            const float* Urow = UMAT + i*UNITS; \
            float a = 0.f; \
            for (int j2 = 0; j2 < UNITS; j2++) a = fmaf(Db[offs(j2, pi)], Urow[j2], a); \
            dxp[ii] += a; \
        } } }

// K=20 direct-global U pass; reads only own Vb/SEL; no barriers, ~20 transient regs
#define PROJ_D(UMAT, SEL) \
    { float uv[4][4]; \
      ELT44(uv[p][jj] = 0.f) \
      const float* up_ = UMAT + 4*jg; \
      for (int k = 0; k < DIMN; k++){ \
          float4 w4 = *(const float4*)(up_ + k*UNITS); \
          float4 s4 = *(const float4*)(Vb + offq(k, p0)); \
          FMA16(uv, s4, w4) \
      } \
      ELT44(proj[p] += uv[p][jj]*SEL[p][jj]) }

// MODE 0: sl=s2r, gates live | MODE 1: sl from SLP, recompute GATES(SLP, sl) | MODE 2: stash
#define BWD_LAYER(SLP, MODE) \
    { \
    float sl[4][4]; \
    if (MODE == 0){ ELT44(sl[p][jj] = s2r[p][jj]) } \
    else if (MODE == 2){ \
        stash_r(gb + ST_S1, sl, t); \
        stash_r(gb + ST_Z, zt, t); stash_r(gb + ST_G, gt, t); \
        stash_r(gb + ST_R, rt, t); stash_r(gb + ST_H, ht, t); \
    } else { \
        read_own(SLP, sl, j0, p0); \
        GATES(SLP, sl) \
    } \
    float dhp[4][4], dzp[4][4], dgp[4][4], dsn[4][4]; \
    ELT44(float d=ds[p][jj]; float g=gt[p][jj]; float h=ht[p][jj]; float z=zt[p][jj]; float s=sl[p][jj]; \
        dhp[p][jj] = d*(1.f - g)*(1.f - h*h); \
        dgp[p][jj] = -d*h*(1.f - g*g); \
        dzp[p][jj] = d*s*(1.f - z*z); \
        dsn[p][jj] = d*z) \
    write_own(Db, dhp, j0, p0); \
    if (type == 1){ PROJ_D(uh, dhp) } else { __syncthreads(); DX_DOT(uh) } \
    float dsr[4][4]; \
    ELT44(dsr[p][jj] = 0.f) \
    mm_acc(WTh, UNITS, Db, dsr, Wc, jg, p0); \
    float drp[4][4]; \
    ELT44(float dr=dsr[p][jj]; float r=rt[p][jj]; float s=sl[p][jj]; \
        drp[p][jj] = dr*s*(1.f - r*r); \
        dsn[p][jj] += dr*r) \
    write_own(Db, dzp, j0, p0); \
    if (type == 1){ PROJ_D(uz, dzp) } else { __syncthreads(); DX_DOT(uz) } \
    mm_acc(WTz, UNITS, Db, dsn, Wc, jg, p0); \
    write_own(Db, dgp, j0, p0); \
    if (type == 1){ PROJ_D(ug, dgp) } else { __syncthreads(); DX_DOT(ug) } \
    mm_acc(WTg, UNITS, Db, dsn, Wc, jg, p0); \
    write_own(Db, drp, j0, p0); \
    if (type == 1){ PROJ_D(ur, drp) } else { __syncthreads(); DX_DOT(ur) } \
    mm_acc(WTr, UNITS, Db, dsn, Wc, jg, p0); \
    ELT44(ds[p][jj] = dsn[p][jj]) \
    }

    BWD_LAYER(S0, 0)                   // layer 3: gates live, sl = s2r
    BWD_LAYER(S1, (SG ? 2 : 1))        // layer 2: stash (or recompute from S1)
    BWD_LAYER(S0, 1)                   // layer 1: recompute from S0

    // first-layer backward + epilogue
    {
        float s0l[4][4];
        read_own(S0, s0l, j0, p0);
        float v0[4][4];
        ELT44(v0[p][jj] = ds[p][jj]*(1.f - s0l[p][jj]*s0l[p][jj]))

        if (type == 1){
            PROJ_D(w1, v0)
            __syncthreads();
            *(float4*)(Db + jg*32 + p0) = make_float4(proj[0], proj[1], proj[2], proj[3]);
            __syncthreads();
            if (t < TM){
                float s = 0.f;
                for (int j2 = 0; j2 < 32; j2++) s += Db[j2*32 + t];
                atomicAdd(t12acc + base_n + t, s);
            }
        } else {
            write_own(Db, v0, j0, p0);
            __syncthreads();
            DX_DOT(w1)
            #pragma unroll
            for (int ii = 0; ii < 3; ii++){
                int i = il + 8*ii;
                if (i < DD) fp1[(P0 + pi)*DD + i] = dxp[ii];
            }
        }
    }
}

__global__ __launch_bounds__(256, 3) void dgm_sg(DGM_PARAMS){
    __shared__ float lds[L_TOT_SG];
    dgm_body<1>(lds, DGM_ARGS);
}
__global__ __launch_bounds__(256, 2) void dgm_rc(DGM_PARAMS){
    __shared__ float lds[L_TOT_RC];
    dgm_body<0>(lds, DGM_ARGS);
}

__global__ void finalize_k(const float* __restrict__ inputs, const float* __restrict__ eps,
    const float* __restrict__ Lm, const float* __restrict__ fp1, const float* __restrict__ val1,
    const float* __restrict__ val2, const float* __restrict__ t12acc, float* __restrict__ out)
{
    int n = blockIdx.x*256 + threadIdx.x;
    if (n >= NN) return;
    float fp[DD];
    #pragma unroll
    for (int k = 0; k < DD; k++) fp[k] = fp1[n*DD + k];
    float t11 = fp[DIMN];
    #pragma unroll
    for (int k = 0; k < DIMN; k++) t11 = fmaf(MUC*inputs[n*DD + k], fp[k], t11);
    float esum[DIMN];
    #pragma unroll
    for (int d = 0; d < DIMN; d++){
        float a = 0.f;
        for (int m = 0; m < MCN; m++) a += eps[(size_t)(m*NN + n)*DIMN + d];
        esum[d] = a;
    }
    float t12b = 0.f;
    #pragma unroll
    for (int k = 0; k < DIMN; k++){
        float loc = inputs[n*DD + k];
        float ssum = (float)MCN * loc;
        #pragma unroll
        for (int d = 0; d < DIMN; d++) ssum = fmaf(esum[d], Lm[k*DIMN + d], ssum);
        float vsum = ssum * (SIGC*loc);
        t12b = fmaf(fp[k], vsum, t12b);
    }
    float term12 = (t12acc[n] - t12b) * (1.0f/(DELTAC*(float)MCN));
    out[n] = t11 + 0.5f*term12 - RC*val1[n];

    float prod = 1.f;
    #pragma unroll
    for (int k = 0; k < DIMN; k++) prod *= inputs[(NN + n)*DD + k];
    float payoff = powf(prod, 1.0f/(float)DIMN);
    if (!(payoff > 0.f)) payoff = 0.f;
    out[NN + n] = val2[n] - payoff;
}

extern "C" void kernel_launch(void* const* d_in, const int* in_sizes, int n_in,
                              void* d_out, int out_size, void* d_ws, size_t ws_size,
                              hipStream_t stream)
{
    const float* inputs = (const float*)d_in[0];
    const float* eps    = (const float*)d_in[1];
    const float* w1     = (const float*)d_in[2];
    const float* b1     = (const float*)d_in[3];
    const float* uz     = (const float*)d_in[4];
    const float* wz     = (const float*)d_in[5];
    const float* bz     = (const float*)d_in[6];
    const float* ug     = (const float*)d_in[7];
    const float* wg     = (const float*)d_in[8];
    const float* bg     = (const float*)d_in[9];
    const float* urr    = (const float*)d_in[10];
    const float* wr     = (const float*)d_in[11];
    const float* br     = (const float*)d_in[12];
    const float* uh     = (const float*)d_in[13];
    const float* wh     = (const float*)d_in[14];
    const float* bh     = (const float*)d_in[15];
    const float* wv     = (const float*)d_in[16];
    const float* bv     = (const float*)d_in[17];

    float* ws    = (float*)d_ws;
    float* Lm    = ws + OFF_L;
    float* WT    = ws + OFF_WT;
    float* Uzgr  = ws + OFF_UZGR;
    float* Wzgr  = ws + OFF_WZGR;
    float* fp1   = ws + OFF_FP1;
    float* val1  = ws + OFF_VAL1;
    float* val2  = ws + OFF_VAL2;
    float* t12   = ws + OFF_T12;
    float* gates = ws + OFF_GATES;
    float* out   = (float*)d_out;

    hipMemsetAsync(t12, 0, NN*sizeof(float), stream);
    hipLaunchKernelGGL(chol_kernel, dim3(1), dim3(64), 0, stream, Lm);
    hipLaunchKernelGGL(transpose_k, dim3(256), dim3(256), 0, stream, wz, wg, wr, wh, WT);
    hipLaunchKernelGGL(pack_zgr, dim3(224), dim3(256), 0, stream, uz, ug, urr, wz, wg, wr, Uzgr, Wzgr);

    size_t need_bytes = ((size_t)OFF_GATES + (size_t)NBLK * (size_t)GB_STRIDE) * sizeof(float);
    if (ws_size >= need_bytes){
        hipLaunchKernelGGL(dgm_sg, dim3(NBLK), dim3(256), 0, stream,
            inputs, eps, w1, b1, uz, bz, ug, bg, urr, br, uh, wh, bh, wv, bv,
            Lm, WT, Uzgr, Wzgr, gates, fp1, val1, val2, t12);
    } else {
        hipLaunchKernelGGL(dgm_rc, dim3(NBLK), dim3(256), 0, stream,
            inputs, eps, w1, b1, uz, bz, ug, bg, urr, br, uh, wh, bh, wv, bv,
            Lm, WT, Uzgr, Wzgr, gates, fp1, val1, val2, t12);
    }
    hipLaunchKernelGGL(finalize_k, dim3(8), dim3(256), 0, stream,
        inputs, eps, Lm, fp1, val1, val2, t12, out);
}

// Round 6
// 1918.791 us; speedup vs baseline: 3.6658x; 1.4857x over previous
//
#include <hip/hip_runtime.h>
#include <math.h>

#define DIMN 20
#define DD 21
#define NN 2048
#define MCN 32
#define UNITS 128
#define SIGC 0.2f
#define MUC 0.05f
#define RC 0.05f
#define DELTAC 0.01f

#define TM 32
#define KCH 16
#define KC3 8
#define PTOT (NN + MCN*NN + NN)
#define NBLK (PTOT/TM)

// ws layout (floats)
#define OFF_L 0
#define OFF_WT 512
#define OFF_UZGR (OFF_WT + 4*16384)      // 66048 : packed [Uz|Ug|Ur] 21x384 (pad to 8192)
#define OFF_WZGR (OFF_UZGR + 8192)       // 74240 : packed [Wz|Wg|Wr] 128x384
#define OFF_FP1  (OFF_WZGR + 49152)      // 123392
#define OFF_VAL1 (OFF_FP1 + NN*DD)       // 166400
#define OFF_VAL2 (OFF_VAL1 + NN)         // 168448
#define OFF_T12  (OFF_VAL2 + NN)         // 170496
#define OFF_GATES (OFF_T12 + NN)         // 172544 : per-block stash

// per-block stash (floats), per-thread-linear layout; h recovered, not stashed
#define ST_S1 0
#define ST_Z1 4096
#define ST_G1 8192
#define ST_R1 12288
#define ST_Z2 16384
#define ST_G2 20480
#define ST_R2 24576
#define GB_STRIDE 28672     // total stash = (172544 + 2176*28672)*4 B = 250.3 MB

// LDS layouts (floats); Wc sized for max(2*KCH*128, 2*KC3*384) = 6144
// SG: S0 0 | Db 4096 | Wc 8192 | xT 14336 | Vb 15008 | tot 15680 (62.7KB -> 2 blk/CU)
// RC: S0 0 | S1 4096 | Db 8192 | Wc 12288 | xT 18432 | Vb 19104 | tot 19776 (79.1KB -> 2)
#define L_TOT_SG 15680
#define L_TOT_RC 19776

#define ELT44(...) _Pragma("unroll") for (int p = 0; p < 4; p++){ _Pragma("unroll") for (int jj = 0; jj < 4; jj++){ __VA_ARGS__; } }

__device__ __forceinline__ int offq(int row, int p0){
    return row*32 + ((p0 + 4*(row&7)) & 31);
}
__device__ __forceinline__ int offs(int row, int p){
    return row*32 + (((p & 28) + 4*(row&7)) & 31) + (p & 3);
}

// stage `units` 16B-units from global g into contiguous LDS wc
__device__ __forceinline__ void stageW(const float* __restrict__ g, float* wc, int units){
#if defined(__has_builtin) && __has_builtin(__builtin_amdgcn_global_load_lds)
    int lane = threadIdx.x & 63, wid = threadIdx.x >> 6;
    for (int base = wid*64; base < units; base += 256){
        int u = base + lane;
        if (u < units)
            __builtin_amdgcn_global_load_lds(
                (const __attribute__((address_space(1))) unsigned int*)(g) + (size_t)u*4,
                (__attribute__((address_space(3))) unsigned int*)(wc) + (size_t)base*4,
                16, 0, 0);
    }
#else
    int t = threadIdx.x;
    for (int u = t; u < units; u += 256){
        float4 v = *(const float4*)(g + u*4);
        *(float4*)(wc + u*4) = v;
    }
#endif
}

#define FMA16(acc, s4, w4) \
  acc[0][0]=fmaf(s4.x,w4.x,acc[0][0]); acc[0][1]=fmaf(s4.x,w4.y,acc[0][1]); \
  acc[0][2]=fmaf(s4.x,w4.z,acc[0][2]); acc[0][3]=fmaf(s4.x,w4.w,acc[0][3]); \
  acc[1][0]=fmaf(s4.y,w4.x,acc[1][0]); acc[1][1]=fmaf(s4.y,w4.y,acc[1][1]); \
  acc[1][2]=fmaf(s4.y,w4.z,acc[1][2]); acc[1][3]=fmaf(s4.y,w4.w,acc[1][3]); \
  acc[2][0]=fmaf(s4.z,w4.x,acc[2][0]); acc[2][1]=fmaf(s4.z,w4.y,acc[2][1]); \
  acc[2][2]=fmaf(s4.z,w4.z,acc[2][2]); acc[2][3]=fmaf(s4.z,w4.w,acc[2][3]); \
  acc[3][0]=fmaf(s4.w,w4.x,acc[3][0]); acc[3][1]=fmaf(s4.w,w4.y,acc[3][1]); \
  acc[3][2]=fmaf(s4.w,w4.z,acc[3][2]); acc[3][3]=fmaf(s4.w,w4.w,acc[3][3]);

// acc[p][jj] += sum_k vec[k][p0+p] * W[k][4jg+jj]; staged LDS double-buffer
__device__ __forceinline__ void mm_acc(const float* __restrict__ gW, int K,
    const float* __restrict__ vec, float acc[4][4], float* __restrict__ Wc,
    int jg, int p0)
{
    int nch = (K + KCH - 1) / KCH;
    {
        int r0 = (K < KCH) ? K : KCH;
        stageW(gW, Wc, r0*32);
    }
    for (int c = 0; c < nch; c++){
        __syncthreads();
        if (c + 1 < nch){
            int c0n = (c+1)*KCH;
            int rn = K - c0n; if (rn > KCH) rn = KCH;
            stageW(gW + c0n*UNITS, Wc + ((c+1)&1)*KCH*UNITS, rn*32);
        }
        int c0 = c*KCH;
        int rows = K - c0; if (rows > KCH) rows = KCH;
        const float* wb = Wc + (c&1)*KCH*UNITS;
        if (rows == KCH){
            #pragma unroll
            for (int kk = 0; kk < KCH; kk++){
                int k = c0 + kk;
                float4 w4 = *(const float4*)(wb + kk*UNITS + 4*jg);
                float4 s4 = *(const float4*)(vec + offq(k, p0));
                FMA16(acc, s4, w4)
            }
        } else {
            for (int kk = 0; kk < rows; kk++){
                int k = c0 + kk;
                float4 w4 = *(const float4*)(wb + kk*UNITS + 4*jg);
                float4 s4 = *(const float4*)(vec + offq(k, p0));
                FMA16(acc, s4, w4)
            }
        }
    }
    __syncthreads();
}

// fused z,g,r: W packed rows of 384 ([z|g|r]); staged
__device__ __forceinline__ void mm3_acc(const float* __restrict__ gW, int K,
    const float* __restrict__ vec, float az[4][4], float ag[4][4], float ar[4][4],
    float* __restrict__ Wc, int jg, int p0)
{
    int nch = (K + KC3 - 1) / KC3;
    {
        int r0 = (K < KC3) ? K : KC3;
        stageW(gW, Wc, r0*96);
    }
    for (int c = 0; c < nch; c++){
        __syncthreads();
        if (c + 1 < nch){
            int c0n = (c+1)*KC3;
            int rn = K - c0n; if (rn > KC3) rn = KC3;
            stageW(gW + c0n*384, Wc + ((c+1)&1)*(KC3*384), rn*96);
        }
        int c0 = c*KC3;
        int rows = K - c0; if (rows > KC3) rows = KC3;
        const float* wb = Wc + (c&1)*(KC3*384);
        if (rows == KC3){
            #pragma unroll
            for (int kk = 0; kk < KC3; kk++){
                int k = c0 + kk;
                const float* wrow = wb + kk*384 + 4*jg;
                float4 s4  = *(const float4*)(vec + offq(k, p0));
                float4 wz4 = *(const float4*)(wrow);
                float4 wg4 = *(const float4*)(wrow + 128);
                float4 wr4 = *(const float4*)(wrow + 256);
                FMA16(az, s4, wz4)
                FMA16(ag, s4, wg4)
                FMA16(ar, s4, wr4)
            }
        } else {
            for (int kk = 0; kk < rows; kk++){
                int k = c0 + kk;
                const float* wrow = wb + kk*384 + 4*jg;
                float4 s4  = *(const float4*)(vec + offq(k, p0));
                float4 wz4 = *(const float4*)(wrow);
                float4 wg4 = *(const float4*)(wrow + 128);
                float4 wr4 = *(const float4*)(wrow + 256);
                FMA16(az, s4, wz4)
                FMA16(ag, s4, wg4)
                FMA16(ar, s4, wr4)
            }
        }
    }
    __syncthreads();
}

__device__ __forceinline__ void write_own(float* buf, const float v[4][4], int j0, int p0){
    #pragma unroll
    for (int jj = 0; jj < 4; jj++){
        int j = j0 + jj;
        float4 q = make_float4(v[0][jj], v[1][jj], v[2][jj], v[3][jj]);
        *(float4*)(buf + offq(j, p0)) = q;
    }
}
__device__ __forceinline__ void read_own(const float* buf, float v[4][4], int j0, int p0){
    #pragma unroll
    for (int jj = 0; jj < 4; jj++){
        int j = j0 + jj;
        float4 q = *(const float4*)(buf + offq(j, p0));
        v[0][jj]=q.x; v[1][jj]=q.y; v[2][jj]=q.z; v[3][jj]=q.w;
    }
}
// per-thread-linear global stash (coalesced; only same thread reads back)
__device__ __forceinline__ void stash_w(float* buf, const float v[4][4], int t){
    #pragma unroll
    for (int jj = 0; jj < 4; jj++)
        *(float4*)(buf + (jj*256 + t)*4) = make_float4(v[0][jj], v[1][jj], v[2][jj], v[3][jj]);
}
__device__ __forceinline__ void stash_r(const float* buf, float v[4][4], int t){
    #pragma unroll
    for (int jj = 0; jj < 4; jj++){
        float4 q = *(const float4*)(buf + (jj*256 + t)*4);
        v[0][jj]=q.x; v[1][jj]=q.y; v[2][jj]=q.z; v[3][jj]=q.w;
    }
}

// out = tanh(bias + x@U + vec@W)   (h gate)
__device__ __forceinline__ void gate_f(const float* __restrict__ U, const float* __restrict__ W,
    const float* __restrict__ bias, const float* __restrict__ xT, const float* __restrict__ Sin,
    float* __restrict__ Wc, float out[4][4], int jg, int p0, int j0)
{
    float acc[4][4];
    float4 b = *(const float4*)(bias + j0);
    #pragma unroll
    for (int p = 0; p < 4; p++){ acc[p][0]=b.x; acc[p][1]=b.y; acc[p][2]=b.z; acc[p][3]=b.w; }
    mm_acc(U, DD, xT, acc, Wc, jg, p0);
    mm_acc(W, UNITS, Sin, acc, Wc, jg, p0);
    #pragma unroll
    for (int p = 0; p < 4; p++)
        #pragma unroll
        for (int jj = 0; jj < 4; jj++) out[p][jj] = tanhf(acc[p][jj]);
}

// fused z,g,r gates
__device__ __forceinline__ void gate3_f(const float* __restrict__ Uzgr, const float* __restrict__ Wzgr,
    const float* __restrict__ bz, const float* __restrict__ bg, const float* __restrict__ br,
    const float* __restrict__ xT, const float* __restrict__ Sin,
    float* __restrict__ Wc, float zt[4][4], float gt[4][4], float rt[4][4],
    int jg, int p0, int j0)
{
    float4 b0 = *(const float4*)(bz + j0);
    float4 b1 = *(const float4*)(bg + j0);
    float4 b2 = *(const float4*)(br + j0);
    #pragma unroll
    for (int p = 0; p < 4; p++){
        zt[p][0]=b0.x; zt[p][1]=b0.y; zt[p][2]=b0.z; zt[p][3]=b0.w;
        gt[p][0]=b1.x; gt[p][1]=b1.y; gt[p][2]=b1.z; gt[p][3]=b1.w;
        rt[p][0]=b2.x; rt[p][1]=b2.y; rt[p][2]=b2.z; rt[p][3]=b2.w;
    }
    mm3_acc(Uzgr, DD, xT, zt, gt, rt, Wc, jg, p0);
    mm3_acc(Wzgr, UNITS, Sin, zt, gt, rt, Wc, jg, p0);
    ELT44(zt[p][jj]=tanhf(zt[p][jj]); gt[p][jj]=tanhf(gt[p][jj]); rt[p][jj]=tanhf(rt[p][jj]))
}

// closed-form Cholesky of DELTA*((1-RHO)I + RHO*J): equicorrelated structure.
// L[i][j] = c[j] (i>j), d[j] (i==j); same recurrence the dense loop performs.
__global__ void chol_kernel(float* __restrict__ Lout)
{
    if (threadIdx.x == 0 && blockIdx.x == 0) {
        const double beta = 0.01 * 0.5;          // off-diagonal
        const double diag = 0.01;                // alpha + beta
        double c[DIMN], d[DIMN];
        double S = 0.0;
        for (int j = 0; j < DIMN; j++){
            double dj = sqrt(diag - S);
            double cj = (beta - S) / dj;
            d[j] = dj; c[j] = cj;
            S += cj*cj;
        }
        for (int i = 0; i < DIMN; i++)
            for (int j = 0; j < DIMN; j++)
                Lout[i*DIMN + j] = (j < i) ? (float)c[j] : (j == i) ? (float)d[i] : 0.0f;
    }
}

__global__ void transpose_k(const float* __restrict__ wz, const float* __restrict__ wg,
                            const float* __restrict__ wr, const float* __restrict__ wh,
                            float* __restrict__ WT)
{
    int idx = blockIdx.x*256 + threadIdx.x;           // 0..65535
    int q = idx >> 14, r2 = idx & 16383, k = r2 >> 7, j = r2 & 127;
    const float* src = (q==0)? wz : (q==1)? wg : (q==2)? wr : wh;
    WT[(q<<14) + j*UNITS + k] = src[k*UNITS + j];
}

// pack [Uz|Ug|Ur] 21x384 and [Wz|Wg|Wr] 128x384
__global__ void pack_zgr(const float* __restrict__ uz, const float* __restrict__ ug,
                         const float* __restrict__ ur,
                         const float* __restrict__ wz, const float* __restrict__ wg,
                         const float* __restrict__ wr,
                         float* __restrict__ Uzgr, float* __restrict__ Wzgr)
{
    int idx = blockIdx.x*256 + threadIdx.x;
    if (idx < 128*384){
        int k = idx/384, c = idx - k*384, g = c >> 7, j = c & 127;
        const float* s = (g==0)? wz : (g==1)? wg : wr;
        Wzgr[idx] = s[k*UNITS + j];
        return;
    }
    int i2 = idx - 128*384;
    if (i2 < 21*384){
        int k = i2/384, c = i2 - k*384, g = c >> 7, j = c & 127;
        const float* s = (g==0)? uz : (g==1)? ug : ur;
        Uzgr[i2] = s[k*UNITS + j];
    }
}

#define DGM_PARAMS \
    const float* __restrict__ inputs, const float* __restrict__ eps, \
    const float* __restrict__ w1, const float* __restrict__ b1, \
    const float* __restrict__ uz, const float* __restrict__ bz, \
    const float* __restrict__ ug, const float* __restrict__ bg, \
    const float* __restrict__ ur, const float* __restrict__ br, \
    const float* __restrict__ uh, const float* __restrict__ wh, const float* __restrict__ bh, \
    const float* __restrict__ wv, const float* __restrict__ bv, \
    const float* __restrict__ Lm, const float* __restrict__ WT, \
    const float* __restrict__ Uzgr, const float* __restrict__ Wzgr, \
    float* __restrict__ gws, \
    float* __restrict__ fp1, float* __restrict__ val1, float* __restrict__ val2, \
    float* __restrict__ t12acc

#define DGM_ARGS inputs, eps, w1, b1, uz, bz, ug, bg, ur, br, uh, wh, bh, wv, bv, \
    Lm, WT, Uzgr, Wzgr, gws, fp1, val1, val2, t12acc

template<int SG>
__device__ __forceinline__ void dgm_body(float* lds, DGM_PARAMS)
{
    float* S0 = lds;
    float* S1 = SG ? lds : lds + 4096;          // RC only
    float* Db = lds + (SG ? 4096 : 8192);
    float* Wc = lds + (SG ? 8192 : 12288);
    float* xT = lds + (SG ? 14336 : 18432);
    float* Vb = lds + (SG ? 15008 : 19104);

    const int t  = threadIdx.x;
    const int jg = t & 31;
    const int pg = t >> 5;
    const int p0 = pg * 4;
    const int j0 = jg * 4;
    const int P0 = blockIdx.x * TM;
    const int type = (P0 < NN) ? 0 : (P0 < NN + MCN*NN) ? 1 : 2;
    int base_n = 0, mrow = 0;
    if (type == 1){ int q = P0 - NN; mrow = q >> 11; base_n = q & (NN-1); }

    float* gb = gws + (size_t)blockIdx.x * GB_STRIDE;

    // ---- build x tile (and violation V for type 1) ----
    {
        int p = t & 31, kq = t >> 5;
        for (int ki = 0; ki < 3; ki++){
            int k = kq + 8*ki;
            if (k > DIMN) break;
            float xv;
            if (type == 0){
                xv = inputs[(P0 + p)*DD + k];
            } else if (type == 2){
                xv = inputs[(NN + (P0 - NN - MCN*NN) + p)*DD + k];
            } else {
                int n = base_n + p;
                float x1v = inputs[n*DD + k];
                if (k == DIMN) xv = x1v;
                else {
                    const float* ep = eps + (size_t)(mrow*NN + n)*DIMN;
                    float a = x1v;
                    for (int d = 0; d < DIMN; d++) a = fmaf(ep[d], Lm[k*DIMN + d], a);
                    float viol = a * (SIGC * x1v);
                    Vb[offs(k, p)] = viol;
                    xv = x1v + viol;
                }
            }
            xT[offs(k, p)] = xv;
        }
    }
    __syncthreads();

    // ---- forward ----
    float s_own[4][4];
    {
        float acc[4][4];
        float4 b = *(const float4*)(b1 + j0);
        #pragma unroll
        for (int p = 0; p < 4; p++){ acc[p][0]=b.x; acc[p][1]=b.y; acc[p][2]=b.z; acc[p][3]=b.w; }
        mm_acc(w1, DD, xT, acc, Wc, jg, p0);
        ELT44(s_own[p][jj] = tanhf(acc[p][jj]))
        write_own(S0, s_own, j0, p0);
        __syncthreads();
    }

    float zt[4][4], gt[4][4], rt[4][4], ht[4][4];

#define GATES(SIN, SMUL) \
    gate3_f(Uzgr, Wzgr, bz, bg, br, xT, SIN, Wc, zt, gt, rt, jg, p0, j0); \
    { float tt[4][4]; ELT44(tt[p][jj] = SMUL[p][jj]*rt[p][jj]) write_own(Db, tt, j0, p0); } \
    gate_f(uh, wh, bh, xT, Db, Wc, ht, jg, p0, j0);

#define FWD_LAYER(SIN) \
    GATES(SIN, s_own) \
    ELT44(s_own[p][jj] = (1.f - gt[p][jj])*ht[p][jj] + zt[p][jj]*s_own[p][jj])

    FWD_LAYER(S0)                      // layer 1
    if (SG){ if (type != 2){
        stash_w(gb + ST_S1, s_own, t);
        stash_w(gb + ST_Z1, zt, t); stash_w(gb + ST_G1, gt, t); stash_w(gb + ST_R1, rt, t);
    } }
    else   { write_own(S1, s_own, j0, p0); }
    write_own(Db, s_own, j0, p0);      // Sin for layer 2 (safe: wh-pass sync'd)

    FWD_LAYER(Db)                      // layer 2
    if (SG && type != 2){
        stash_w(gb + ST_Z2, zt, t); stash_w(gb + ST_G2, gt, t); stash_w(gb + ST_R2, rt, t);
    }
    float s2r[4][4];
    ELT44(s2r[p][jj] = s_own[p][jj])
    write_own(Db, s_own, j0, p0);      // Sin for layer 3

    FWD_LAYER(Db)                      // layer 3 -- zt/gt/rt/ht stay live

    // ---- value head ----
    {
        float4 wv4 = *(const float4*)(wv + j0);
        float vs[4];
        #pragma unroll
        for (int p = 0; p < 4; p++)
            vs[p] = s_own[p][0]*wv4.x + s_own[p][1]*wv4.y + s_own[p][2]*wv4.z + s_own[p][3]*wv4.w;
        __syncthreads();
        *(float4*)(Db + jg*32 + p0) = make_float4(vs[0], vs[1], vs[2], vs[3]);
        __syncthreads();
        if (t < TM){
            float v = bv[0];
            for (int j2 = 0; j2 < 32; j2++) v += Db[j2*32 + t];
            if (type == 0) val1[P0 + t] = v;
            else if (type == 2) val2[P0 + t - NN - MCN*NN] = v;
        }
        __syncthreads();
    }
    if (type == 2) return;

    // ---- backward ----
    float ds[4][4];
    {
        float4 wv4 = *(const float4*)(wv + j0);
        #pragma unroll
        for (int p = 0; p < 4; p++){ ds[p][0]=wv4.x; ds[p][1]=wv4.y; ds[p][2]=wv4.z; ds[p][3]=wv4.w; }
    }
    float proj[4] = {0.f, 0.f, 0.f, 0.f};
    float dxp[3] = {0.f, 0.f, 0.f};
    const int pi = t >> 3, il = t & 7;

    const float* WTz = WT;
    const float* WTg = WT + 16384;
    const float* WTr = WT + 2*16384;
    const float* WTh = WT + 3*16384;

#define DX_DOT(UMAT) \
    { _Pragma("unroll") for (int ii = 0; ii < 3; ii++){ \
        int i = il + 8*ii; \
        if (i < DD){ \
            const float* Urow = UMAT + i*UNITS; \
            float a = 0.f; \
            for (int j2 = 0; j2 < UNITS; j2++) a = fmaf(Db[offs(j2, pi)], Urow[j2], a); \
            dxp[ii] += a; \
        } } }

// K=20 direct-global U pass; reads only own Vb/SEL; no barriers
#define PROJ_D(UMAT, SEL) \
    { float uv[4][4]; \
      ELT44(uv[p][jj] = 0.f) \
      const float* up_ = UMAT + 4*jg; \
      for (int k = 0; k < DIMN; k++){ \
          float4 w4 = *(const float4*)(up_ + k*UNITS); \
          float4 s4 = *(const float4*)(Vb + offq(k, p0)); \
          FMA16(uv, s4, w4) \
      } \
      ELT44(proj[p] += uv[p][jj]*SEL[p][jj]) }

// MODE 0: sl=s2r, gates live (layer 3)
// MODE 1: sl from SLP, recompute gates (RC fallback)
// MODE 2: sl from ST_S1, z/g/r from stash(GZ..), h=(s2r - z*sl)/(1-g)  (SG layer 2)
// MODE 3: sl from SLP(LDS), z/g/r from stash, h=(s1_stash - z*sl)/(1-g) (SG layer 1)
#define BWD_LAYER(SLP, MODE, GZ, GG, GR) \
    { \
    float sl[4][4]; \
    if (MODE == 0){ ELT44(sl[p][jj] = s2r[p][jj]) } \
    else if (MODE == 2){ stash_r(gb + ST_S1, sl, t); } \
    else { read_own(SLP, sl, j0, p0); } \
    if (MODE == 2 || MODE == 3){ \
        stash_r(gb + GZ, zt, t); stash_r(gb + GG, gt, t); stash_r(gb + GR, rt, t); \
        float sn[4][4]; \
        if (MODE == 2){ ELT44(sn[p][jj] = s2r[p][jj]) } \
        else { stash_r(gb + ST_S1, sn, t); } \
        ELT44(ht[p][jj] = (sn[p][jj] - zt[p][jj]*sl[p][jj]) / (1.f - gt[p][jj])) \
    } \
    if (MODE == 1){ GATES(SLP, sl) } \
    float dhp[4][4], dzp[4][4], dgp[4][4], dsn[4][4]; \
    ELT44(float d=ds[p][jj]; float g=gt[p][jj]; float h=ht[p][jj]; float z=zt[p][jj]; float s=sl[p][jj]; \
        dhp[p][jj] = d*(1.f - g)*(1.f - h*h); \
        dgp[p][jj] = -d*h*(1.f - g*g); \
        dzp[p][jj] = d*s*(1.f - z*z); \
        dsn[p][jj] = d*z) \
    write_own(Db, dhp, j0, p0); \
    if (type == 1){ PROJ_D(uh, dhp) } else { __syncthreads(); DX_DOT(uh) } \
    float dsr[4][4]; \
    ELT44(dsr[p][jj] = 0.f) \
    mm_acc(WTh, UNITS, Db, dsr, Wc, jg, p0); \
    float drp[4][4]; \
    ELT44(float dr=dsr[p][jj]; float r=rt[p][jj]; float s=sl[p][jj]; \
        drp[p][jj] = dr*s*(1.f - r*r); \
        dsn[p][jj] += dr*r) \
    write_own(Db, dzp, j0, p0); \
    if (type == 1){ PROJ_D(uz, dzp) } else { __syncthreads(); DX_DOT(uz) } \
    mm_acc(WTz, UNITS, Db, dsn, Wc, jg, p0); \
    write_own(Db, dgp, j0, p0); \
    if (type == 1){ PROJ_D(ug, dgp) } else { __syncthreads(); DX_DOT(ug) } \
    mm_acc(WTg, UNITS, Db, dsn, Wc, jg, p0); \
    write_own(Db, drp, j0, p0); \
    if (type == 1){ PROJ_D(ur, drp) } else { __syncthreads(); DX_DOT(ur) } \
    mm_acc(WTr, UNITS, Db, dsn, Wc, jg, p0); \
    if (type == 1){ if (MODE == 3) {} PROJ_FOLD_R(MODE) } \
    ELT44(ds[p][jj] = dsn[p][jj]) \
    }
#define PROJ_FOLD_R(MODE) /* placeholder keeps macro structure simple */

    BWD_LAYER(S0, 0, ST_Z2, ST_G2, ST_R2)                  // layer 3: gates live
    BWD_LAYER(S0, (SG ? 2 : 1), ST_Z2, ST_G2, ST_R2)       // layer 2
    if (SG){ BWD_LAYER(S0, 3, ST_Z1, ST_G1, ST_R1) }       // layer 1 (stash)
    else   { BWD_LAYER(S0, 1, ST_Z1, ST_G1, ST_R1) }       // layer 1 (recompute)

    // first-layer backward + epilogue
    {
        float s0l[4][4];
        read_own(S0, s0l, j0, p0);
        float v0[4][4];
        ELT44(v0[p][jj] = ds[p][jj]*(1.f - s0l[p][jj]*s0l[p][jj]))

        if (type == 1){
            PROJ_D(w1, v0)
            __syncthreads();
            *(float4*)(Db + jg*32 + p0) = make_float4(proj[0], proj[1], proj[2], proj[3]);
            __syncthreads();
            if (t < TM){
                float s = 0.f;
                for (int j2 = 0; j2 < 32; j2++) s += Db[j2*32 + t];
                atomicAdd(t12acc + base_n + t, s);
            }
        } else {
            write_own(Db, v0, j0, p0);
            __syncthreads();
            DX_DOT(w1)
            #pragma unroll
            for (int ii = 0; ii < 3; ii++){
                int i = il + 8*ii;
                if (i < DD) fp1[(P0 + pi)*DD + i] = dxp[ii];
            }
        }
    }
}

__global__ __launch_bounds__(256, 1) void dgm_sg(DGM_PARAMS){
    __shared__ float lds[L_TOT_SG];
    dgm_body<1>(lds, DGM_ARGS);
}
__global__ __launch_bounds__(256, 1) void dgm_rc(DGM_PARAMS){
    __shared__ float lds[L_TOT_RC];
    dgm_body<0>(lds, DGM_ARGS);
}

__global__ void finalize_k(const float* __restrict__ inputs, const float* __restrict__ eps,
    const float* __restrict__ Lm, const float* __restrict__ fp1, const float* __restrict__ val1,
    const float* __restrict__ val2, const float* __restrict__ t12acc, float* __restrict__ out)
{
    int n = blockIdx.x*256 + threadIdx.x;
    if (n >= NN) return;
    float fp[DD];
    #pragma unroll
    for (int k = 0; k < DD; k++) fp[k] = fp1[n*DD + k];
    float t11 = fp[DIMN];
    #pragma unroll
    for (int k = 0; k < DIMN; k++) t11 = fmaf(MUC*inputs[n*DD + k], fp[k], t11);
    float esum[DIMN];
    #pragma unroll
    for (int d = 0; d < DIMN; d++){
        float a = 0.f;
        for (int m = 0; m < MCN; m++) a += eps[(size_t)(m*NN + n)*DIMN + d];
        esum[d] = a;
    }
    float t12b = 0.f;
    #pragma unroll
    for (int k = 0; k < DIMN; k++){
        float loc = inputs[n*DD + k];
        float ssum = (float)MCN * loc;
        #pragma unroll
        for (int d = 0; d < DIMN; d++) ssum = fmaf(esum[d], Lm[k*DIMN + d], ssum);
        float vsum = ssum * (SIGC*loc);
        t12b = fmaf(fp[k], vsum, t12b);
    }
    float term12 = (t12acc[n] - t12b) * (1.0f/(DELTAC*(float)MCN));
    out[n] = t11 + 0.5f*term12 - RC*val1[n];

    float prod = 1.f;
    #pragma unroll
    for (int k = 0; k < DIMN; k++) prod *= inputs[(NN + n)*DD + k];
    float payoff = powf(prod, 1.0f/(float)DIMN);
    if (!(payoff > 0.f)) payoff = 0.f;
    out[NN + n] = val2[n] - payoff;
}

extern "C" void kernel_launch(void* const* d_in, const int* in_sizes, int n_in,
                              void* d_out, int out_size, void* d_ws, size_t ws_size,
                              hipStream_t stream)
{
    const float* inputs = (const float*)d_in[0];
    const float* eps    = (const float*)d_in[1];
    const float* w1     = (const float*)d_in[2];
    const float* b1     = (const float*)d_in[3];
    const float* uz     = (const float*)d_in[4];
    const float* wz     = (const float*)d_in[5];
    const float* bz     = (const float*)d_in[6];
    const float* ug     = (const float*)d_in[7];
    const float* wg     = (const float*)d_in[8];
    const float* bg     = (const float*)d_in[9];
    const float* urr    = (const float*)d_in[10];
    const float* wr     = (const float*)d_in[11];
    const float* br     = (const float*)d_in[12];
    const float* uh     = (const float*)d_in[13];
    const float* wh     = (const float*)d_in[14];
    const float* bh     = (const float*)d_in[15];
    const float* wv     = (const float*)d_in[16];
    const float* bv     = (const float*)d_in[17];

    float* ws    = (float*)d_ws;
    float* Lm    = ws + OFF_L;
    float* WT    = ws + OFF_WT;
    float* Uzgr  = ws + OFF_UZGR;
    float* Wzgr  = ws + OFF_WZGR;
    float* fp1   = ws + OFF_FP1;
    float* val1  = ws + OFF_VAL1;
    float* val2  = ws + OFF_VAL2;
    float* t12   = ws + OFF_T12;
    float* gates = ws + OFF_GATES;
    float* out   = (float*)d_out;

    hipMemsetAsync(t12, 0, NN*sizeof(float), stream);
    hipLaunchKernelGGL(chol_kernel, dim3(1), dim3(64), 0, stream, Lm);
    hipLaunchKernelGGL(transpose_k, dim3(256), dim3(256), 0, stream, wz, wg, wr, wh, WT);
    hipLaunchKernelGGL(pack_zgr, dim3(224), dim3(256), 0, stream, uz, ug, urr, wz, wg, wr, Uzgr, Wzgr);

    size_t need_bytes = ((size_t)OFF_GATES + (size_t)NBLK * (size_t)GB_STRIDE) * sizeof(float);
    if (ws_size >= need_bytes){
        hipLaunchKernelGGL(dgm_sg, dim3(NBLK), dim3(256), 0, stream,
            inputs, eps, w1, b1, uz, bz, ug, bg, urr, br, uh, wh, bh, wv, bv,
            Lm, WT, Uzgr, Wzgr, gates, fp1, val1, val2, t12);
    } else {
        hipLaunchKernelGGL(dgm_rc, dim3(NBLK), dim3(256), 0, stream,
            inputs, eps, w1, b1, uz, bz, ug, bg, urr, br, uh, wh, bh, wv, bv,
            Lm, WT, Uzgr, Wzgr, gates, fp1, val1, val2, t12);
    }
    hipLaunchKernelGGL(finalize_k, dim3(8), dim3(256), 0, stream,
        inputs, eps, Lm, fp1, val1, val2, t12, out);
}

// Round 7
// 1567.508 us; speedup vs baseline: 4.4873x; 1.2241x over previous
//
#include <hip/hip_runtime.h>
#include <math.h>

#define DIMN 20
#define DD 21
#define NN 2048
#define MCN 32
#define UNITS 128
#define SIGC 0.2f
#define MUC 0.05f
#define RC 0.05f
#define DELTAC 0.01f

#define TM 32
#define KCH 16
#define KC3 8
#define PTOT (NN + MCN*NN + NN)
#define NBLK (PTOT/TM)

// ws layout (floats)
#define OFF_L 0
#define OFF_WT 512
#define OFF_UZGR (OFF_WT + 4*16384)      // 66048 : packed [Uz|Ug|Ur] 21x384 (pad to 8192)
#define OFF_WZGR (OFF_UZGR + 8192)       // 74240 : packed [Wz|Wg|Wr] 128x384
#define OFF_FP1  (OFF_WZGR + 49152)      // 123392
#define OFF_VAL1 (OFF_FP1 + NN*DD)       // 166400
#define OFF_VAL2 (OFF_VAL1 + NN)         // 168448
#define OFF_T12  (OFF_VAL2 + NN)         // 170496
#define OFF_GATES (OFF_T12 + NN)         // 172544 : per-block stash

// per-block stash (floats), per-thread-linear layout; h recovered, not stashed
#define ST_S1 0
#define ST_Z1 4096
#define ST_G1 8192
#define ST_R1 12288
#define ST_Z2 16384
#define ST_G2 20480
#define ST_R2 24576
#define GB_STRIDE 28672     // total stash = (172544 + 2176*28672)*4 B = 250.3 MB

// LDS layouts (floats); Wc sized for max(2*KCH*128, 2*KC3*384) = 6144
// SG: S0 0 | Db 4096 | Wc 8192 | xT 14336 | Vb 15008 | tot 15680 (62.7KB -> 2 blk/CU)
// RC: S0 0 | S1 4096 | Db 8192 | Wc 12288 | xT 18432 | Vb 19104 | tot 19776 (79.1KB -> 2)
#define L_TOT_SG 15680
#define L_TOT_RC 19776

#define ELT44(...) _Pragma("unroll") for (int p = 0; p < 4; p++){ _Pragma("unroll") for (int jj = 0; jj < 4; jj++){ __VA_ARGS__; } }

__device__ __forceinline__ int offq(int row, int p0){
    return row*32 + ((p0 + 4*(row&7)) & 31);
}
__device__ __forceinline__ int offs(int row, int p){
    return row*32 + (((p & 28) + 4*(row&7)) & 31) + (p & 3);
}

// stage `units` 16B-units from global g into contiguous LDS wc
__device__ __forceinline__ void stageW(const float* __restrict__ g, float* wc, int units){
#if defined(__has_builtin) && __has_builtin(__builtin_amdgcn_global_load_lds)
    int lane = threadIdx.x & 63, wid = threadIdx.x >> 6;
    for (int base = wid*64; base < units; base += 256){
        int u = base + lane;
        if (u < units)
            __builtin_amdgcn_global_load_lds(
                (const __attribute__((address_space(1))) unsigned int*)(g) + (size_t)u*4,
                (__attribute__((address_space(3))) unsigned int*)(wc) + (size_t)base*4,
                16, 0, 0);
    }
#else
    int t = threadIdx.x;
    for (int u = t; u < units; u += 256){
        float4 v = *(const float4*)(g + u*4);
        *(float4*)(wc + u*4) = v;
    }
#endif
}

#define FMA16(acc, s4, w4) \
  acc[0][0]=fmaf(s4.x,w4.x,acc[0][0]); acc[0][1]=fmaf(s4.x,w4.y,acc[0][1]); \
  acc[0][2]=fmaf(s4.x,w4.z,acc[0][2]); acc[0][3]=fmaf(s4.x,w4.w,acc[0][3]); \
  acc[1][0]=fmaf(s4.y,w4.x,acc[1][0]); acc[1][1]=fmaf(s4.y,w4.y,acc[1][1]); \
  acc[1][2]=fmaf(s4.y,w4.z,acc[1][2]); acc[1][3]=fmaf(s4.y,w4.w,acc[1][3]); \
  acc[2][0]=fmaf(s4.z,w4.x,acc[2][0]); acc[2][1]=fmaf(s4.z,w4.y,acc[2][1]); \
  acc[2][2]=fmaf(s4.z,w4.z,acc[2][2]); acc[2][3]=fmaf(s4.z,w4.w,acc[2][3]); \
  acc[3][0]=fmaf(s4.w,w4.x,acc[3][0]); acc[3][1]=fmaf(s4.w,w4.y,acc[3][1]); \
  acc[3][2]=fmaf(s4.w,w4.z,acc[3][2]); acc[3][3]=fmaf(s4.w,w4.w,acc[3][3]);

// acc[p][jj] += sum_k vec[k][p0+p] * W[k][4jg+jj]; staged LDS double-buffer
__device__ __forceinline__ void mm_acc(const float* __restrict__ gW, int K,
    const float* __restrict__ vec, float acc[4][4], float* __restrict__ Wc,
    int jg, int p0)
{
    int nch = (K + KCH - 1) / KCH;
    {
        int r0 = (K < KCH) ? K : KCH;
        stageW(gW, Wc, r0*32);
    }
    for (int c = 0; c < nch; c++){
        __syncthreads();
        if (c + 1 < nch){
            int c0n = (c+1)*KCH;
            int rn = K - c0n; if (rn > KCH) rn = KCH;
            stageW(gW + c0n*UNITS, Wc + ((c+1)&1)*KCH*UNITS, rn*32);
        }
        int c0 = c*KCH;
        int rows = K - c0; if (rows > KCH) rows = KCH;
        const float* wb = Wc + (c&1)*KCH*UNITS;
        if (rows == KCH){
            #pragma unroll
            for (int kk = 0; kk < KCH; kk++){
                int k = c0 + kk;
                float4 w4 = *(const float4*)(wb + kk*UNITS + 4*jg);
                float4 s4 = *(const float4*)(vec + offq(k, p0));
                FMA16(acc, s4, w4)
            }
        } else {
            for (int kk = 0; kk < rows; kk++){
                int k = c0 + kk;
                float4 w4 = *(const float4*)(wb + kk*UNITS + 4*jg);
                float4 s4 = *(const float4*)(vec + offq(k, p0));
                FMA16(acc, s4, w4)
            }
        }
    }
    __syncthreads();
}

// fused z,g,r: W packed rows of 384 ([z|g|r]); staged
__device__ __forceinline__ void mm3_acc(const float* __restrict__ gW, int K,
    const float* __restrict__ vec, float az[4][4], float ag[4][4], float ar[4][4],
    float* __restrict__ Wc, int jg, int p0)
{
    int nch = (K + KC3 - 1) / KC3;
    {
        int r0 = (K < KC3) ? K : KC3;
        stageW(gW, Wc, r0*96);
    }
    for (int c = 0; c < nch; c++){
        __syncthreads();
        if (c + 1 < nch){
            int c0n = (c+1)*KC3;
            int rn = K - c0n; if (rn > KC3) rn = KC3;
            stageW(gW + c0n*384, Wc + ((c+1)&1)*(KC3*384), rn*96);
        }
        int c0 = c*KC3;
        int rows = K - c0; if (rows > KC3) rows = KC3;
        const float* wb = Wc + (c&1)*(KC3*384);
        if (rows == KC3){
            #pragma unroll
            for (int kk = 0; kk < KC3; kk++){
                int k = c0 + kk;
                const float* wrow = wb + kk*384 + 4*jg;
                float4 s4  = *(const float4*)(vec + offq(k, p0));
                float4 wz4 = *(const float4*)(wrow);
                float4 wg4 = *(const float4*)(wrow + 128);
                float4 wr4 = *(const float4*)(wrow + 256);
                FMA16(az, s4, wz4)
                FMA16(ag, s4, wg4)
                FMA16(ar, s4, wr4)
            }
        } else {
            for (int kk = 0; kk < rows; kk++){
                int k = c0 + kk;
                const float* wrow = wb + kk*384 + 4*jg;
                float4 s4  = *(const float4*)(vec + offq(k, p0));
                float4 wz4 = *(const float4*)(wrow);
                float4 wg4 = *(const float4*)(wrow + 128);
                float4 wr4 = *(const float4*)(wrow + 256);
                FMA16(az, s4, wz4)
                FMA16(ag, s4, wg4)
                FMA16(ar, s4, wr4)
            }
        }
    }
    __syncthreads();
}

__device__ __forceinline__ void write_own(float* buf, const float v[4][4], int j0, int p0){
    #pragma unroll
    for (int jj = 0; jj < 4; jj++){
        int j = j0 + jj;
        float4 q = make_float4(v[0][jj], v[1][jj], v[2][jj], v[3][jj]);
        *(float4*)(buf + offq(j, p0)) = q;
    }
}
__device__ __forceinline__ void read_own(const float* buf, float v[4][4], int j0, int p0){
    #pragma unroll
    for (int jj = 0; jj < 4; jj++){
        int j = j0 + jj;
        float4 q = *(const float4*)(buf + offq(j, p0));
        v[0][jj]=q.x; v[1][jj]=q.y; v[2][jj]=q.z; v[3][jj]=q.w;
    }
}
// per-thread-linear global stash (coalesced; only same thread reads back)
__device__ __forceinline__ void stash_w(float* buf, const float v[4][4], int t){
    #pragma unroll
    for (int jj = 0; jj < 4; jj++)
        *(float4*)(buf + (jj*256 + t)*4) = make_float4(v[0][jj], v[1][jj], v[2][jj], v[3][jj]);
}
__device__ __forceinline__ void stash_r(const float* buf, float v[4][4], int t){
    #pragma unroll
    for (int jj = 0; jj < 4; jj++){
        float4 q = *(const float4*)(buf + (jj*256 + t)*4);
        v[0][jj]=q.x; v[1][jj]=q.y; v[2][jj]=q.z; v[3][jj]=q.w;
    }
}

// out = tanh(bias + x@U + vec@W)   (h gate)
__device__ __forceinline__ void gate_f(const float* __restrict__ U, const float* __restrict__ W,
    const float* __restrict__ bias, const float* __restrict__ xT, const float* __restrict__ Sin,
    float* __restrict__ Wc, float out[4][4], int jg, int p0, int j0)
{
    float acc[4][4];
    float4 b = *(const float4*)(bias + j0);
    #pragma unroll
    for (int p = 0; p < 4; p++){ acc[p][0]=b.x; acc[p][1]=b.y; acc[p][2]=b.z; acc[p][3]=b.w; }
    mm_acc(U, DD, xT, acc, Wc, jg, p0);
    mm_acc(W, UNITS, Sin, acc, Wc, jg, p0);
    #pragma unroll
    for (int p = 0; p < 4; p++)
        #pragma unroll
        for (int jj = 0; jj < 4; jj++) out[p][jj] = tanhf(acc[p][jj]);
}

// fused z,g,r gates
__device__ __forceinline__ void gate3_f(const float* __restrict__ Uzgr, const float* __restrict__ Wzgr,
    const float* __restrict__ bz, const float* __restrict__ bg, const float* __restrict__ br,
    const float* __restrict__ xT, const float* __restrict__ Sin,
    float* __restrict__ Wc, float zt[4][4], float gt[4][4], float rt[4][4],
    int jg, int p0, int j0)
{
    float4 b0 = *(const float4*)(bz + j0);
    float4 b1 = *(const float4*)(bg + j0);
    float4 b2 = *(const float4*)(br + j0);
    #pragma unroll
    for (int p = 0; p < 4; p++){
        zt[p][0]=b0.x; zt[p][1]=b0.y; zt[p][2]=b0.z; zt[p][3]=b0.w;
        gt[p][0]=b1.x; gt[p][1]=b1.y; gt[p][2]=b1.z; gt[p][3]=b1.w;
        rt[p][0]=b2.x; rt[p][1]=b2.y; rt[p][2]=b2.z; rt[p][3]=b2.w;
    }
    mm3_acc(Uzgr, DD, xT, zt, gt, rt, Wc, jg, p0);
    mm3_acc(Wzgr, UNITS, Sin, zt, gt, rt, Wc, jg, p0);
    ELT44(zt[p][jj]=tanhf(zt[p][jj]); gt[p][jj]=tanhf(gt[p][jj]); rt[p][jj]=tanhf(rt[p][jj]))
}

// closed-form Cholesky of DELTA*((1-RHO)I + RHO*J): equicorrelated structure.
__global__ void chol_kernel(float* __restrict__ Lout)
{
    if (threadIdx.x == 0 && blockIdx.x == 0) {
        const double beta = 0.01 * 0.5;          // off-diagonal
        const double diag = 0.01;                // alpha + beta
        double c[DIMN], d[DIMN];
        double S = 0.0;
        for (int j = 0; j < DIMN; j++){
            double dj = sqrt(diag - S);
            double cj = (beta - S) / dj;
            d[j] = dj; c[j] = cj;
            S += cj*cj;
        }
        for (int i = 0; i < DIMN; i++)
            for (int j = 0; j < DIMN; j++)
                Lout[i*DIMN + j] = (j < i) ? (float)c[j] : (j == i) ? (float)d[i] : 0.0f;
    }
}

__global__ void transpose_k(const float* __restrict__ wz, const float* __restrict__ wg,
                            const float* __restrict__ wr, const float* __restrict__ wh,
                            float* __restrict__ WT)
{
    int idx = blockIdx.x*256 + threadIdx.x;           // 0..65535
    int q = idx >> 14, r2 = idx & 16383, k = r2 >> 7, j = r2 & 127;
    const float* src = (q==0)? wz : (q==1)? wg : (q==2)? wr : wh;
    WT[(q<<14) + j*UNITS + k] = src[k*UNITS + j];
}

// pack [Uz|Ug|Ur] 21x384 and [Wz|Wg|Wr] 128x384
__global__ void pack_zgr(const float* __restrict__ uz, const float* __restrict__ ug,
                         const float* __restrict__ ur,
                         const float* __restrict__ wz, const float* __restrict__ wg,
                         const float* __restrict__ wr,
                         float* __restrict__ Uzgr, float* __restrict__ Wzgr)
{
    int idx = blockIdx.x*256 + threadIdx.x;
    if (idx < 128*384){
        int k = idx/384, c = idx - k*384, g = c >> 7, j = c & 127;
        const float* s = (g==0)? wz : (g==1)? wg : wr;
        Wzgr[idx] = s[k*UNITS + j];
        return;
    }
    int i2 = idx - 128*384;
    if (i2 < 21*384){
        int k = i2/384, c = i2 - k*384, g = c >> 7, j = c & 127;
        const float* s = (g==0)? uz : (g==1)? ug : ur;
        Uzgr[i2] = s[k*UNITS + j];
    }
}

#define DGM_PARAMS \
    const float* __restrict__ inputs, const float* __restrict__ eps, \
    const float* __restrict__ w1, const float* __restrict__ b1, \
    const float* __restrict__ uz, const float* __restrict__ bz, \
    const float* __restrict__ ug, const float* __restrict__ bg, \
    const float* __restrict__ ur, const float* __restrict__ br, \
    const float* __restrict__ uh, const float* __restrict__ wh, const float* __restrict__ bh, \
    const float* __restrict__ wv, const float* __restrict__ bv, \
    const float* __restrict__ Lm, const float* __restrict__ WT, \
    const float* __restrict__ Uzgr, const float* __restrict__ Wzgr, \
    float* __restrict__ gws, \
    float* __restrict__ fp1, float* __restrict__ val1, float* __restrict__ val2, \
    float* __restrict__ t12acc

#define DGM_ARGS inputs, eps, w1, b1, uz, bz, ug, bg, ur, br, uh, wh, bh, wv, bv, \
    Lm, WT, Uzgr, Wzgr, gws, fp1, val1, val2, t12acc

template<int SG>
__device__ __forceinline__ void dgm_body(float* lds, DGM_PARAMS)
{
    float* S0 = lds;
    float* S1 = SG ? lds : lds + 4096;          // RC only
    float* Db = lds + (SG ? 4096 : 8192);
    float* Wc = lds + (SG ? 8192 : 12288);
    float* xT = lds + (SG ? 14336 : 18432);
    float* Vb = lds + (SG ? 15008 : 19104);

    const int t  = threadIdx.x;
    const int jg = t & 31;
    const int pg = t >> 5;
    const int p0 = pg * 4;
    const int j0 = jg * 4;
    const int P0 = blockIdx.x * TM;
    const int type = (P0 < NN) ? 0 : (P0 < NN + MCN*NN) ? 1 : 2;
    int base_n = 0, mrow = 0;
    if (type == 1){ int q = P0 - NN; mrow = q >> 11; base_n = q & (NN-1); }

    float* gb = gws + (size_t)blockIdx.x * GB_STRIDE;

    // ---- build x tile (and violation V for type 1) ----
    {
        int p = t & 31, kq = t >> 5;
        for (int ki = 0; ki < 3; ki++){
            int k = kq + 8*ki;
            if (k > DIMN) break;
            float xv;
            if (type == 0){
                xv = inputs[(P0 + p)*DD + k];
            } else if (type == 2){
                xv = inputs[(NN + (P0 - NN - MCN*NN) + p)*DD + k];
            } else {
                int n = base_n + p;
                float x1v = inputs[n*DD + k];
                if (k == DIMN) xv = x1v;
                else {
                    const float* ep = eps + (size_t)(mrow*NN + n)*DIMN;
                    float a = x1v;
                    for (int d = 0; d < DIMN; d++) a = fmaf(ep[d], Lm[k*DIMN + d], a);
                    float viol = a * (SIGC * x1v);
                    Vb[offs(k, p)] = viol;
                    xv = x1v + viol;
                }
            }
            xT[offs(k, p)] = xv;
        }
    }
    __syncthreads();

    // ---- forward ----
    float s_own[4][4];
    {
        float acc[4][4];
        float4 b = *(const float4*)(b1 + j0);
        #pragma unroll
        for (int p = 0; p < 4; p++){ acc[p][0]=b.x; acc[p][1]=b.y; acc[p][2]=b.z; acc[p][3]=b.w; }
        mm_acc(w1, DD, xT, acc, Wc, jg, p0);
        ELT44(s_own[p][jj] = tanhf(acc[p][jj]))
        write_own(S0, s_own, j0, p0);
        __syncthreads();
    }

    float zt[4][4], gt[4][4], rt[4][4], ht[4][4];

#define GATES(SIN, SMUL) \
    gate3_f(Uzgr, Wzgr, bz, bg, br, xT, SIN, Wc, zt, gt, rt, jg, p0, j0); \
    { float tt[4][4]; ELT44(tt[p][jj] = SMUL[p][jj]*rt[p][jj]) write_own(Db, tt, j0, p0); } \
    gate_f(uh, wh, bh, xT, Db, Wc, ht, jg, p0, j0);

#define FWD_LAYER(SIN) \
    GATES(SIN, s_own) \
    ELT44(s_own[p][jj] = (1.f - gt[p][jj])*ht[p][jj] + zt[p][jj]*s_own[p][jj])

    FWD_LAYER(S0)                      // layer 1
    if (SG){ if (type != 2){
        stash_w(gb + ST_S1, s_own, t);
        stash_w(gb + ST_Z1, zt, t); stash_w(gb + ST_G1, gt, t); stash_w(gb + ST_R1, rt, t);
    } }
    else   { write_own(S1, s_own, j0, p0); }
    write_own(Db, s_own, j0, p0);      // Sin for layer 2 (safe: wh-pass sync'd)

    FWD_LAYER(Db)                      // layer 2
    if (SG && type != 2){
        stash_w(gb + ST_Z2, zt, t); stash_w(gb + ST_G2, gt, t); stash_w(gb + ST_R2, rt, t);
    }
    float s2r[4][4];
    ELT44(s2r[p][jj] = s_own[p][jj])
    write_own(Db, s_own, j0, p0);      // Sin for layer 3

    FWD_LAYER(Db)                      // layer 3 -- zt/gt/rt/ht stay live

    // ---- value head ----
    {
        float4 wv4 = *(const float4*)(wv + j0);
        float vs[4];
        #pragma unroll
        for (int p = 0; p < 4; p++)
            vs[p] = s_own[p][0]*wv4.x + s_own[p][1]*wv4.y + s_own[p][2]*wv4.z + s_own[p][3]*wv4.w;
        __syncthreads();
        *(float4*)(Db + jg*32 + p0) = make_float4(vs[0], vs[1], vs[2], vs[3]);
        __syncthreads();
        if (t < TM){
            float v = bv[0];
            for (int j2 = 0; j2 < 32; j2++) v += Db[j2*32 + t];
            if (type == 0) val1[P0 + t] = v;
            else if (type == 2) val2[P0 + t - NN - MCN*NN] = v;
        }
        __syncthreads();
    }
    if (type == 2) return;

    // ---- backward ----
    float ds[4][4];
    {
        float4 wv4 = *(const float4*)(wv + j0);
        #pragma unroll
        for (int p = 0; p < 4; p++){ ds[p][0]=wv4.x; ds[p][1]=wv4.y; ds[p][2]=wv4.z; ds[p][3]=wv4.w; }
    }
    float proj[4] = {0.f, 0.f, 0.f, 0.f};
    float dxp[3] = {0.f, 0.f, 0.f};
    const int pi = t >> 3, il = t & 7;

    const float* WTz = WT;
    const float* WTg = WT + 16384;
    const float* WTr = WT + 2*16384;
    const float* WTh = WT + 3*16384;

#define DX_DOT(UMAT) \
    { _Pragma("unroll") for (int ii = 0; ii < 3; ii++){ \
        int i = il + 8*ii; \
        if (i < DD){ \
            const float* Urow = UMAT + i*UNITS; \
            float a = 0.f; \
            for (int j2 = 0; j2 < UNITS; j2++) a = fmaf(Db[offs(j2, pi)], Urow[j2], a); \
            dxp[ii] += a; \
        } } }

// K=20 direct-global U pass; reads only own Vb/SEL; no barriers
#define PROJ_D(UMAT, SEL) \
    { float uv[4][4]; \
      ELT44(uv[p][jj] = 0.f) \
      const float* up_ = UMAT + 4*jg; \
      for (int k = 0; k < DIMN; k++){ \
          float4 w4 = *(const float4*)(up_ + k*UNITS); \
          float4 s4 = *(const float4*)(Vb + offq(k, p0)); \
          FMA16(uv, s4, w4) \
      } \
      ELT44(proj[p] += uv[p][jj]*SEL[p][jj]) }

// MODE 0: sl=s2r, gates live (layer 3)
// MODE 1: sl from SLP, recompute gates (RC fallback)
// MODE 2: sl from ST_S1, z/g/r from stash, h=(s2r - z*sl)/(1-g)  (SG layer 2)
// MODE 3: sl from SLP(LDS), z/g/r from stash, h=(s1_stash - z*sl)/(1-g) (SG layer 1)
#define BWD_LAYER(SLP, MODE, GZ, GG, GR) \
    { \
    float sl[4][4]; \
    if (MODE == 0){ ELT44(sl[p][jj] = s2r[p][jj]) } \
    else if (MODE == 2){ stash_r(gb + ST_S1, sl, t); } \
    else { read_own(SLP, sl, j0, p0); } \
    if (MODE == 2 || MODE == 3){ \
        stash_r(gb + GZ, zt, t); stash_r(gb + GG, gt, t); stash_r(gb + GR, rt, t); \
        float sn[4][4]; \
        if (MODE == 2){ ELT44(sn[p][jj] = s2r[p][jj]) } \
        else { stash_r(gb + ST_S1, sn, t); } \
        ELT44(ht[p][jj] = (sn[p][jj] - zt[p][jj]*sl[p][jj]) / (1.f - gt[p][jj])) \
    } \
    if (MODE == 1){ GATES(SLP, sl) } \
    float dhp[4][4], dzp[4][4], dgp[4][4], dsn[4][4]; \
    ELT44(float d=ds[p][jj]; float g=gt[p][jj]; float h=ht[p][jj]; float z=zt[p][jj]; float s=sl[p][jj]; \
        dhp[p][jj] = d*(1.f - g)*(1.f - h*h); \
        dgp[p][jj] = -d*h*(1.f - g*g); \
        dzp[p][jj] = d*s*(1.f - z*z); \
        dsn[p][jj] = d*z) \
    write_own(Db, dhp, j0, p0); \
    if (type == 1){ PROJ_D(uh, dhp) } else { __syncthreads(); DX_DOT(uh) } \
    float dsr[4][4]; \
    ELT44(dsr[p][jj] = 0.f) \
    mm_acc(WTh, UNITS, Db, dsr, Wc, jg, p0); \
    float drp[4][4]; \
    ELT44(float dr=dsr[p][jj]; float r=rt[p][jj]; float s=sl[p][jj]; \
        drp[p][jj] = dr*s*(1.f - r*r); \
        dsn[p][jj] += dr*r) \
    write_own(Db, dzp, j0, p0); \
    if (type == 1){ PROJ_D(uz, dzp) } else { __syncthreads(); DX_DOT(uz) } \
    mm_acc(WTz, UNITS, Db, dsn, Wc, jg, p0); \
    write_own(Db, dgp, j0, p0); \
    if (type == 1){ PROJ_D(ug, dgp) } else { __syncthreads(); DX_DOT(ug) } \
    mm_acc(WTg, UNITS, Db, dsn, Wc, jg, p0); \
    write_own(Db, drp, j0, p0); \
    if (type == 1){ PROJ_D(ur, drp) } else { __syncthreads(); DX_DOT(ur) } \
    mm_acc(WTr, UNITS, Db, dsn, Wc, jg, p0); \
    ELT44(ds[p][jj] = dsn[p][jj]) \
    }

    BWD_LAYER(S0, 0, ST_Z2, ST_G2, ST_R2)                  // layer 3: gates live
    BWD_LAYER(S0, (SG ? 2 : 1), ST_Z2, ST_G2, ST_R2)       // layer 2
    if (SG){ BWD_LAYER(S0, 3, ST_Z1, ST_G1, ST_R1) }       // layer 1 (stash)
    else   { BWD_LAYER(S0, 1, ST_Z1, ST_G1, ST_R1) }       // layer 1 (recompute)

    // first-layer backward + epilogue
    {
        float s0l[4][4];
        read_own(S0, s0l, j0, p0);
        float v0[4][4];
        ELT44(v0[p][jj] = ds[p][jj]*(1.f - s0l[p][jj]*s0l[p][jj]))

        if (type == 1){
            PROJ_D(w1, v0)
            __syncthreads();
            *(float4*)(Db + jg*32 + p0) = make_float4(proj[0], proj[1], proj[2], proj[3]);
            __syncthreads();
            if (t < TM){
                float s = 0.f;
                for (int j2 = 0; j2 < 32; j2++) s += Db[j2*32 + t];
                atomicAdd(t12acc + base_n + t, s);
            }
        } else {
            write_own(Db, v0, j0, p0);
            __syncthreads();
            DX_DOT(w1)
            #pragma unroll
            for (int ii = 0; ii < 3; ii++){
                int i = il + 8*ii;
                if (i < DD) fp1[(P0 + pi)*DD + i] = dxp[ii];
            }
        }
    }
}

__global__ __launch_bounds__(256) __attribute__((amdgpu_waves_per_eu(2,2))) void dgm_sg(DGM_PARAMS){
    __shared__ float lds[L_TOT_SG];
    dgm_body<1>(lds, DGM_ARGS);
}
__global__ __launch_bounds__(256) __attribute__((amdgpu_waves_per_eu(2,2))) void dgm_rc(DGM_PARAMS){
    __shared__ float lds[L_TOT_RC];
    dgm_body<0>(lds, DGM_ARGS);
}

__global__ void finalize_k(const float* __restrict__ inputs, const float* __restrict__ eps,
    const float* __restrict__ Lm, const float* __restrict__ fp1, const float* __restrict__ val1,
    const float* __restrict__ val2, const float* __restrict__ t12acc, float* __restrict__ out)
{
    int n = blockIdx.x*256 + threadIdx.x;
    if (n >= NN) return;
    float fp[DD];
    #pragma unroll
    for (int k = 0; k < DD; k++) fp[k] = fp1[n*DD + k];
    float t11 = fp[DIMN];
    #pragma unroll
    for (int k = 0; k < DIMN; k++) t11 = fmaf(MUC*inputs[n*DD + k], fp[k], t11);
    float esum[DIMN];
    #pragma unroll
    for (int d = 0; d < DIMN; d++){
        float a = 0.f;
        for (int m = 0; m < MCN; m++) a += eps[(size_t)(m*NN + n)*DIMN + d];
        esum[d] = a;
    }
    float t12b = 0.f;
    #pragma unroll
    for (int k = 0; k < DIMN; k++){
        float loc = inputs[n*DD + k];
        float ssum = (float)MCN * loc;
        #pragma unroll
        for (int d = 0; d < DIMN; d++) ssum = fmaf(esum[d], Lm[k*DIMN + d], ssum);
        float vsum = ssum * (SIGC*loc);
        t12b = fmaf(fp[k], vsum, t12b);
    }
    float term12 = (t12acc[n] - t12b) * (1.0f/(DELTAC*(float)MCN));
    out[n] = t11 + 0.5f*term12 - RC*val1[n];

    float prod = 1.f;
    #pragma unroll
    for (int k = 0; k < DIMN; k++) prod *= inputs[(NN + n)*DD + k];
    float payoff = powf(prod, 1.0f/(float)DIMN);
    if (!(payoff > 0.f)) payoff = 0.f;
    out[NN + n] = val2[n] - payoff;
}

extern "C" void kernel_launch(void* const* d_in, const int* in_sizes, int n_in,
                              void* d_out, int out_size, void* d_ws, size_t ws_size,
                              hipStream_t stream)
{
    const float* inputs = (const float*)d_in[0];
    const float* eps    = (const float*)d_in[1];
    const float* w1     = (const float*)d_in[2];
    const float* b1     = (const float*)d_in[3];
    const float* uz     = (const float*)d_in[4];
    const float* wz     = (const float*)d_in[5];
    const float* bz     = (const float*)d_in[6];
    const float* ug     = (const float*)d_in[7];
    const float* wg     = (const float*)d_in[8];
    const float* bg     = (const float*)d_in[9];
    const float* urr    = (const float*)d_in[10];
    const float* wr     = (const float*)d_in[11];
    const float* br     = (const float*)d_in[12];
    const float* uh     = (const float*)d_in[13];
    const float* wh     = (const float*)d_in[14];
    const float* bh     = (const float*)d_in[15];
    const float* wv     = (const float*)d_in[16];
    const float* bv     = (const float*)d_in[17];

    float* ws    = (float*)d_ws;
    float* Lm    = ws + OFF_L;
    float* WT    = ws + OFF_WT;
    float* Uzgr  = ws + OFF_UZGR;
    float* Wzgr  = ws + OFF_WZGR;
    float* fp1   = ws + OFF_FP1;
    float* val1  = ws + OFF_VAL1;
    float* val2  = ws + OFF_VAL2;
    float* t12   = ws + OFF_T12;
    float* gates = ws + OFF_GATES;
    float* out   = (float*)d_out;

    hipMemsetAsync(t12, 0, NN*sizeof(float), stream);
    hipLaunchKernelGGL(chol_kernel, dim3(1), dim3(64), 0, stream, Lm);
    hipLaunchKernelGGL(transpose_k, dim3(256), dim3(256), 0, stream, wz, wg, wr, wh, WT);
    hipLaunchKernelGGL(pack_zgr, dim3(224), dim3(256), 0, stream, uz, ug, urr, wz, wg, wr, Uzgr, Wzgr);

    size_t need_bytes = ((size_t)OFF_GATES + (size_t)NBLK * (size_t)GB_STRIDE) * sizeof(float);
    if (ws_size >= need_bytes){
        hipLaunchKernelGGL(dgm_sg, dim3(NBLK), dim3(256), 0, stream,
            inputs, eps, w1, b1, uz, bz, ug, bg, urr, br, uh, wh, bh, wv, bv,
            Lm, WT, Uzgr, Wzgr, gates, fp1, val1, val2, t12);
    } else {
        hipLaunchKernelGGL(dgm_rc, dim3(NBLK), dim3(256), 0, stream,
            inputs, eps, w1, b1, uz, bz, ug, bg, urr, br, uh, wh, bh, wv, bv,
            Lm, WT, Uzgr, Wzgr, gates, fp1, val1, val2, t12);
    }
    hipLaunchKernelGGL(finalize_k, dim3(8), dim3(256), 0, stream,
        inputs, eps, Lm, fp1, val1, val2, t12, out);
}

// Round 8
// 1524.589 us; speedup vs baseline: 4.6137x; 1.0282x over previous
//
#include <hip/hip_runtime.h>
#include <math.h>

#define DIMN 20
#define DD 21
#define NN 2048
#define MCN 32
#define UNITS 128
#define SIGC 0.2f
#define MUC 0.05f
#define RC 0.05f
#define DELTAC 0.01f

#define TM 32
#define KCH 16
#define KC3 8
#define PTOT (NN + MCN*NN + NN)
#define NBLK (PTOT/TM)

// ws layout (floats)
#define OFF_L 0
#define OFF_WT 512
#define OFF_UZGR (OFF_WT + 4*16384)      // 66048 : packed [Uz|Ug|Ur] 21x384 (pad to 8192)
#define OFF_WZGR (OFF_UZGR + 8192)       // 74240 : packed [Wz|Wg|Wr] 128x384
#define OFF_FP1  (OFF_WZGR + 49152)      // 123392
#define OFF_VAL1 (OFF_FP1 + NN*DD)       // 166400
#define OFF_VAL2 (OFF_VAL1 + NN)         // 168448
#define OFF_T12  (OFF_VAL2 + NN)         // 170496
#define OFF_GATES (OFF_T12 + NN)         // 172544 : per-block stash

// per-block stash (floats), per-thread-linear layout; h recovered, not stashed
#define ST_S1 0
#define ST_Z1 4096
#define ST_G1 8192
#define ST_R1 12288
#define ST_Z2 16384
#define ST_G2 20480
#define ST_R2 24576
#define GB_STRIDE 28672     // total stash = (172544 + 2176*28672)*4 B = 250.3 MB

// LDS layouts (floats); Wc sized for max(2*KCH*128, 2*KC3*384) = 6144
// SG: S0 0 | S2 4096 | Db 8192 | Wc 12288 | xT 18432 | Vb 19104 | tot 19776 (79.1KB -> 2 blk/CU)
// RC: S0 0 | S1 4096 | S2 8192 | Db 12288 | Wc 16384 | xT 22528 | Vb 23200 | tot 23872 (95.5KB -> 1)
#define L_TOT_SG 19776
#define L_TOT_RC 23872

#define ELT44(...) _Pragma("unroll") for (int p = 0; p < 4; p++){ _Pragma("unroll") for (int jj = 0; jj < 4; jj++){ __VA_ARGS__; } }

__device__ __forceinline__ int offq(int row, int p0){
    return row*32 + ((p0 + 4*(row&7)) & 31);
}
__device__ __forceinline__ int offs(int row, int p){
    return row*32 + (((p & 28) + 4*(row&7)) & 31) + (p & 3);
}

// stage `units` 16B-units from global g into contiguous LDS wc
__device__ __forceinline__ void stageW(const float* __restrict__ g, float* wc, int units){
#if defined(__has_builtin) && __has_builtin(__builtin_amdgcn_global_load_lds)
    int lane = threadIdx.x & 63, wid = threadIdx.x >> 6;
    for (int base = wid*64; base < units; base += 256){
        int u = base + lane;
        if (u < units)
            __builtin_amdgcn_global_load_lds(
                (const __attribute__((address_space(1))) unsigned int*)(g) + (size_t)u*4,
                (__attribute__((address_space(3))) unsigned int*)(wc) + (size_t)base*4,
                16, 0, 0);
    }
#else
    int t = threadIdx.x;
    for (int u = t; u < units; u += 256){
        float4 v = *(const float4*)(g + u*4);
        *(float4*)(wc + u*4) = v;
    }
#endif
}

#define FMA16(acc, s4, w4) \
  acc[0][0]=fmaf(s4.x,w4.x,acc[0][0]); acc[0][1]=fmaf(s4.x,w4.y,acc[0][1]); \
  acc[0][2]=fmaf(s4.x,w4.z,acc[0][2]); acc[0][3]=fmaf(s4.x,w4.w,acc[0][3]); \
  acc[1][0]=fmaf(s4.y,w4.x,acc[1][0]); acc[1][1]=fmaf(s4.y,w4.y,acc[1][1]); \
  acc[1][2]=fmaf(s4.y,w4.z,acc[1][2]); acc[1][3]=fmaf(s4.y,w4.w,acc[1][3]); \
  acc[2][0]=fmaf(s4.z,w4.x,acc[2][0]); acc[2][1]=fmaf(s4.z,w4.y,acc[2][1]); \
  acc[2][2]=fmaf(s4.z,w4.z,acc[2][2]); acc[2][3]=fmaf(s4.z,w4.w,acc[2][3]); \
  acc[3][0]=fmaf(s4.w,w4.x,acc[3][0]); acc[3][1]=fmaf(s4.w,w4.y,acc[3][1]); \
  acc[3][2]=fmaf(s4.w,w4.z,acc[3][2]); acc[3][3]=fmaf(s4.w,w4.w,acc[3][3]);

// acc[p][jj] += sum_k vec[k][p0+p] * W[k][4jg+jj]; staged LDS double-buffer
__device__ __forceinline__ void mm_acc(const float* __restrict__ gW, int K,
    const float* __restrict__ vec, float acc[4][4], float* __restrict__ Wc,
    int jg, int p0)
{
    int nch = (K + KCH - 1) / KCH;
    {
        int r0 = (K < KCH) ? K : KCH;
        stageW(gW, Wc, r0*32);
    }
    for (int c = 0; c < nch; c++){
        __syncthreads();
        if (c + 1 < nch){
            int c0n = (c+1)*KCH;
            int rn = K - c0n; if (rn > KCH) rn = KCH;
            stageW(gW + c0n*UNITS, Wc + ((c+1)&1)*KCH*UNITS, rn*32);
        }
        int c0 = c*KCH;
        int rows = K - c0; if (rows > KCH) rows = KCH;
        const float* wb = Wc + (c&1)*KCH*UNITS;
        if (rows == KCH){
            #pragma unroll
            for (int kk = 0; kk < KCH; kk++){
                int k = c0 + kk;
                float4 w4 = *(const float4*)(wb + kk*UNITS + 4*jg);
                float4 s4 = *(const float4*)(vec + offq(k, p0));
                FMA16(acc, s4, w4)
            }
        } else {
            for (int kk = 0; kk < rows; kk++){
                int k = c0 + kk;
                float4 w4 = *(const float4*)(wb + kk*UNITS + 4*jg);
                float4 s4 = *(const float4*)(vec + offq(k, p0));
                FMA16(acc, s4, w4)
            }
        }
    }
    __syncthreads();
}

// fused z,g,r: W packed rows of 384 ([z|g|r]); staged
__device__ __forceinline__ void mm3_acc(const float* __restrict__ gW, int K,
    const float* __restrict__ vec, float az[4][4], float ag[4][4], float ar[4][4],
    float* __restrict__ Wc, int jg, int p0)
{
    int nch = (K + KC3 - 1) / KC3;
    {
        int r0 = (K < KC3) ? K : KC3;
        stageW(gW, Wc, r0*96);
    }
    for (int c = 0; c < nch; c++){
        __syncthreads();
        if (c + 1 < nch){
            int c0n = (c+1)*KC3;
            int rn = K - c0n; if (rn > KC3) rn = KC3;
            stageW(gW + c0n*384, Wc + ((c+1)&1)*(KC3*384), rn*96);
        }
        int c0 = c*KC3;
        int rows = K - c0; if (rows > KC3) rows = KC3;
        const float* wb = Wc + (c&1)*(KC3*384);
        if (rows == KC3){
            #pragma unroll
            for (int kk = 0; kk < KC3; kk++){
                int k = c0 + kk;
                const float* wrow = wb + kk*384 + 4*jg;
                float4 s4  = *(const float4*)(vec + offq(k, p0));
                float4 wz4 = *(const float4*)(wrow);
                float4 wg4 = *(const float4*)(wrow + 128);
                float4 wr4 = *(const float4*)(wrow + 256);
                FMA16(az, s4, wz4)
                FMA16(ag, s4, wg4)
                FMA16(ar, s4, wr4)
            }
        } else {
            for (int kk = 0; kk < rows; kk++){
                int k = c0 + kk;
                const float* wrow = wb + kk*384 + 4*jg;
                float4 s4  = *(const float4*)(vec + offq(k, p0));
                float4 wz4 = *(const float4*)(wrow);
                float4 wg4 = *(const float4*)(wrow + 128);
                float4 wr4 = *(const float4*)(wrow + 256);
                FMA16(az, s4, wz4)
                FMA16(ag, s4, wg4)
                FMA16(ar, s4, wr4)
            }
        }
    }
    __syncthreads();
}

__device__ __forceinline__ void write_own(float* buf, const float v[4][4], int j0, int p0){
    #pragma unroll
    for (int jj = 0; jj < 4; jj++){
        int j = j0 + jj;
        float4 q = make_float4(v[0][jj], v[1][jj], v[2][jj], v[3][jj]);
        *(float4*)(buf + offq(j, p0)) = q;
    }
}
__device__ __forceinline__ void read_own(const float* buf, float v[4][4], int j0, int p0){
    #pragma unroll
    for (int jj = 0; jj < 4; jj++){
        int j = j0 + jj;
        float4 q = *(const float4*)(buf + offq(j, p0));
        v[0][jj]=q.x; v[1][jj]=q.y; v[2][jj]=q.z; v[3][jj]=q.w;
    }
}
// per-thread-linear global stash (coalesced; only same thread reads back)
__device__ __forceinline__ void stash_w(float* buf, const float v[4][4], int t){
    #pragma unroll
    for (int jj = 0; jj < 4; jj++)
        *(float4*)(buf + (jj*256 + t)*4) = make_float4(v[0][jj], v[1][jj], v[2][jj], v[3][jj]);
}
__device__ __forceinline__ void stash_r(const float* buf, float v[4][4], int t){
    #pragma unroll
    for (int jj = 0; jj < 4; jj++){
        float4 q = *(const float4*)(buf + (jj*256 + t)*4);
        v[0][jj]=q.x; v[1][jj]=q.y; v[2][jj]=q.z; v[3][jj]=q.w;
    }
}

// out = tanh(bias + x@U + vec@W)   (h gate)
__device__ __forceinline__ void gate_f(const float* __restrict__ U, const float* __restrict__ W,
    const float* __restrict__ bias, const float* __restrict__ xT, const float* __restrict__ Sin,
    float* __restrict__ Wc, float out[4][4], int jg, int p0, int j0)
{
    float acc[4][4];
    float4 b = *(const float4*)(bias + j0);
    #pragma unroll
    for (int p = 0; p < 4; p++){ acc[p][0]=b.x; acc[p][1]=b.y; acc[p][2]=b.z; acc[p][3]=b.w; }
    mm_acc(U, DD, xT, acc, Wc, jg, p0);
    mm_acc(W, UNITS, Sin, acc, Wc, jg, p0);
    #pragma unroll
    for (int p = 0; p < 4; p++)
        #pragma unroll
        for (int jj = 0; jj < 4; jj++) out[p][jj] = tanhf(acc[p][jj]);
}

// fused z,g,r gates
__device__ __forceinline__ void gate3_f(const float* __restrict__ Uzgr, const float* __restrict__ Wzgr,
    const float* __restrict__ bz, const float* __restrict__ bg, const float* __restrict__ br,
    const float* __restrict__ xT, const float* __restrict__ Sin,
    float* __restrict__ Wc, float zt[4][4], float gt[4][4], float rt[4][4],
    int jg, int p0, int j0)
{
    float4 b0 = *(const float4*)(bz + j0);
    float4 b1 = *(const float4*)(bg + j0);
    float4 b2 = *(const float4*)(br + j0);
    #pragma unroll
    for (int p = 0; p < 4; p++){
        zt[p][0]=b0.x; zt[p][1]=b0.y; zt[p][2]=b0.z; zt[p][3]=b0.w;
        gt[p][0]=b1.x; gt[p][1]=b1.y; gt[p][2]=b1.z; gt[p][3]=b1.w;
        rt[p][0]=b2.x; rt[p][1]=b2.y; rt[p][2]=b2.z; rt[p][3]=b2.w;
    }
    mm3_acc(Uzgr, DD, xT, zt, gt, rt, Wc, jg, p0);
    mm3_acc(Wzgr, UNITS, Sin, zt, gt, rt, Wc, jg, p0);
    ELT44(zt[p][jj]=tanhf(zt[p][jj]); gt[p][jj]=tanhf(gt[p][jj]); rt[p][jj]=tanhf(rt[p][jj]))
}

// closed-form Cholesky of DELTA*((1-RHO)I + RHO*J): equicorrelated structure.
__global__ void chol_kernel(float* __restrict__ Lout)
{
    if (threadIdx.x == 0 && blockIdx.x == 0) {
        const double beta = 0.01 * 0.5;          // off-diagonal
        const double diag = 0.01;                // alpha + beta
        double c[DIMN], d[DIMN];
        double S = 0.0;
        for (int j = 0; j < DIMN; j++){
            double dj = sqrt(diag - S);
            double cj = (beta - S) / dj;
            d[j] = dj; c[j] = cj;
            S += cj*cj;
        }
        for (int i = 0; i < DIMN; i++)
            for (int j = 0; j < DIMN; j++)
                Lout[i*DIMN + j] = (j < i) ? (float)c[j] : (j == i) ? (float)d[i] : 0.0f;
    }
}

__global__ void transpose_k(const float* __restrict__ wz, const float* __restrict__ wg,
                            const float* __restrict__ wr, const float* __restrict__ wh,
                            float* __restrict__ WT)
{
    int idx = blockIdx.x*256 + threadIdx.x;           // 0..65535
    int q = idx >> 14, r2 = idx & 16383, k = r2 >> 7, j = r2 & 127;
    const float* src = (q==0)? wz : (q==1)? wg : (q==2)? wr : wh;
    WT[(q<<14) + j*UNITS + k] = src[k*UNITS + j];
}

// pack [Uz|Ug|Ur] 21x384 and [Wz|Wg|Wr] 128x384
__global__ void pack_zgr(const float* __restrict__ uz, const float* __restrict__ ug,
                         const float* __restrict__ ur,
                         const float* __restrict__ wz, const float* __restrict__ wg,
                         const float* __restrict__ wr,
                         float* __restrict__ Uzgr, float* __restrict__ Wzgr)
{
    int idx = blockIdx.x*256 + threadIdx.x;
    if (idx < 128*384){
        int k = idx/384, c = idx - k*384, g = c >> 7, j = c & 127;
        const float* s = (g==0)? wz : (g==1)? wg : wr;
        Wzgr[idx] = s[k*UNITS + j];
        return;
    }
    int i2 = idx - 128*384;
    if (i2 < 21*384){
        int k = i2/384, c = i2 - k*384, g = c >> 7, j = c & 127;
        const float* s = (g==0)? uz : (g==1)? ug : ur;
        Uzgr[i2] = s[k*UNITS + j];
    }
}

#define DGM_PARAMS \
    const float* __restrict__ inputs, const float* __restrict__ eps, \
    const float* __restrict__ w1, const float* __restrict__ b1, \
    const float* __restrict__ uz, const float* __restrict__ bz, \
    const float* __restrict__ ug, const float* __restrict__ bg, \
    const float* __restrict__ ur, const float* __restrict__ br, \
    const float* __restrict__ uh, const float* __restrict__ wh, const float* __restrict__ bh, \
    const float* __restrict__ wv, const float* __restrict__ bv, \
    const float* __restrict__ Lm, const float* __restrict__ WT, \
    const float* __restrict__ Uzgr, const float* __restrict__ Wzgr, \
    float* __restrict__ gws, \
    float* __restrict__ fp1, float* __restrict__ val1, float* __restrict__ val2, \
    float* __restrict__ t12acc

#define DGM_ARGS inputs, eps, w1, b1, uz, bz, ug, bg, ur, br, uh, wh, bh, wv, bv, \
    Lm, WT, Uzgr, Wzgr, gws, fp1, val1, val2, t12acc

template<int SG>
__device__ __forceinline__ void dgm_body(float* lds, DGM_PARAMS)
{
    float* S0 = lds;
    float* S1 = SG ? lds : lds + 4096;                // RC only
    float* S2 = lds + (SG ? 4096 : 8192);
    float* Db = lds + (SG ? 8192 : 12288);
    float* Wc = lds + (SG ? 12288 : 16384);
    float* xT = lds + (SG ? 18432 : 22528);
    float* Vb = lds + (SG ? 19104 : 23200);

    const int t  = threadIdx.x;
    const int jg = t & 31;
    const int pg = t >> 5;
    const int p0 = pg * 4;
    const int j0 = jg * 4;
    const int P0 = blockIdx.x * TM;
    const int type = (P0 < NN) ? 0 : (P0 < NN + MCN*NN) ? 1 : 2;
    int base_n = 0, mrow = 0;
    if (type == 1){ int q = P0 - NN; mrow = q >> 11; base_n = q & (NN-1); }

    float* gb = gws + (size_t)blockIdx.x * GB_STRIDE;

    // ---- build x tile (and violation V for type 1) ----
    {
        int p = t & 31, kq = t >> 5;
        for (int ki = 0; ki < 3; ki++){
            int k = kq + 8*ki;
            if (k > DIMN) break;
            float xv;
            if (type == 0){
                xv = inputs[(P0 + p)*DD + k];
            } else if (type == 2){
                xv = inputs[(NN + (P0 - NN - MCN*NN) + p)*DD + k];
            } else {
                int n = base_n + p;
                float x1v = inputs[n*DD + k];
                if (k == DIMN) xv = x1v;
                else {
                    const float* ep = eps + (size_t)(mrow*NN + n)*DIMN;
                    float a = x1v;
                    for (int d = 0; d < DIMN; d++) a = fmaf(ep[d], Lm[k*DIMN + d], a);
                    float viol = a * (SIGC * x1v);
                    Vb[offs(k, p)] = viol;
                    xv = x1v + viol;
                }
            }
            xT[offs(k, p)] = xv;
        }
    }
    __syncthreads();

    // ---- forward ----
    float s_own[4][4];
    {
        float acc[4][4];
        float4 b = *(const float4*)(b1 + j0);
        #pragma unroll
        for (int p = 0; p < 4; p++){ acc[p][0]=b.x; acc[p][1]=b.y; acc[p][2]=b.z; acc[p][3]=b.w; }
        mm_acc(w1, DD, xT, acc, Wc, jg, p0);
        ELT44(s_own[p][jj] = tanhf(acc[p][jj]))
        write_own(S0, s_own, j0, p0);
        __syncthreads();
    }

    float zt[4][4], gt[4][4], rt[4][4], ht[4][4];

#define GATES(SIN, SMUL) \
    gate3_f(Uzgr, Wzgr, bz, bg, br, xT, SIN, Wc, zt, gt, rt, jg, p0, j0); \
    { float tt[4][4]; ELT44(tt[p][jj] = SMUL[p][jj]*rt[p][jj]) write_own(Db, tt, j0, p0); } \
    gate_f(uh, wh, bh, xT, Db, Wc, ht, jg, p0, j0);

#define FWD_LAYER(SIN) \
    GATES(SIN, s_own) \
    ELT44(s_own[p][jj] = (1.f - gt[p][jj])*ht[p][jj] + zt[p][jj]*s_own[p][jj])

    FWD_LAYER(S0)                      // layer 1
    if (SG){ if (type != 2){
        stash_w(gb + ST_S1, s_own, t);
        stash_w(gb + ST_Z1, zt, t); stash_w(gb + ST_G1, gt, t); stash_w(gb + ST_R1, rt, t);
    } }
    else   { write_own(S1, s_own, j0, p0); }
    write_own(Db, s_own, j0, p0);      // Sin for layer 2 (safe: wh-pass sync'd)

    FWD_LAYER(Db)                      // layer 2
    if (SG && type != 2){
        stash_w(gb + ST_Z2, zt, t); stash_w(gb + ST_G2, gt, t); stash_w(gb + ST_R2, rt, t);
    }
    write_own(S2, s_own, j0, p0);      // s2 kept in LDS for backward (not registers)

    FWD_LAYER(S2)                      // layer 3 -- zt/gt/rt/ht stay live into backward

    // ---- value head ----
    {
        float4 wv4 = *(const float4*)(wv + j0);
        float vs[4];
        #pragma unroll
        for (int p = 0; p < 4; p++)
            vs[p] = s_own[p][0]*wv4.x + s_own[p][1]*wv4.y + s_own[p][2]*wv4.z + s_own[p][3]*wv4.w;
        __syncthreads();
        *(float4*)(Db + jg*32 + p0) = make_float4(vs[0], vs[1], vs[2], vs[3]);
        __syncthreads();
        if (t < TM){
            float v = bv[0];
            for (int j2 = 0; j2 < 32; j2++) v += Db[j2*32 + t];
            if (type == 0) val1[P0 + t] = v;
            else if (type == 2) val2[P0 + t - NN - MCN*NN] = v;
        }
        __syncthreads();
    }
    if (type == 2) return;

    // ---- backward ----
    float ds[4][4];
    {
        float4 wv4 = *(const float4*)(wv + j0);
        #pragma unroll
        for (int p = 0; p < 4; p++){ ds[p][0]=wv4.x; ds[p][1]=wv4.y; ds[p][2]=wv4.z; ds[p][3]=wv4.w; }
    }
    float proj[4] = {0.f, 0.f, 0.f, 0.f};
    float dxp[3] = {0.f, 0.f, 0.f};
    const int pi = t >> 3, il = t & 7;

    const float* WTz = WT;
    const float* WTg = WT + 16384;
    const float* WTr = WT + 2*16384;
    const float* WTh = WT + 3*16384;

#define DX_DOT(UMAT) \
    { _Pragma("unroll") for (int ii = 0; ii < 3; ii++){ \
        int i = il + 8*ii; \
        if (i < DD){ \
            const float* Urow = UMAT + i*UNITS; \
            float a = 0.f; \
            for (int j2 = 0; j2 < UNITS; j2++) a = fmaf(Db[offs(j2, pi)], Urow[j2], a); \
            dxp[ii] += a; \
        } } }

// K=20 direct-global U pass; reads only own Vb/SEL; no barriers
#define PROJ_D(UMAT, SEL) \
    { float uv[4][4]; \
      ELT44(uv[p][jj] = 0.f) \
      const float* up_ = UMAT + 4*jg; \
      for (int k = 0; k < DIMN; k++){ \
          float4 w4 = *(const float4*)(up_ + k*UNITS); \
          float4 s4 = *(const float4*)(Vb + offq(k, p0)); \
          FMA16(uv, s4, w4) \
      } \
      ELT44(proj[p] += uv[p][jj]*SEL[p][jj]) }

// MODE 0: sl = s2 from S2 LDS, gates live in regs (layer 3)
// MODE 1: sl from SLP, recompute gates (RC fallback)
// MODE 2: sl = s1 from stash, z/g from stash, h=(s2_lds - z*sl)/(1-g)   (SG layer 2)
// MODE 3: sl = s0 from SLP LDS, z/g from stash, h=(s1_stash - z*sl)/(1-g) (SG layer 1)
// rt / sl are re-read (not held) across the WTh matmul in stash modes.
#define BWD_LAYER(SLP, MODE, GZ, GG, GR) \
    { \
    float dhp[4][4], dgp[4][4], dzp[4][4], dsn[4][4]; \
    { \
    float sl[4][4]; \
    if (MODE == 0){ read_own(S2, sl, j0, p0); } \
    else if (MODE == 2){ stash_r(gb + ST_S1, sl, t); } \
    else { read_own(SLP, sl, j0, p0); } \
    if (MODE == 2 || MODE == 3){ \
        stash_r(gb + GZ, zt, t); stash_r(gb + GG, gt, t); \
        float sn[4][4]; \
        if (MODE == 2){ read_own(S2, sn, j0, p0); } \
        else { stash_r(gb + ST_S1, sn, t); } \
        ELT44(ht[p][jj] = (sn[p][jj] - zt[p][jj]*sl[p][jj]) / (1.f - gt[p][jj])) \
    } \
    if (MODE == 1){ GATES(SLP, sl) } \
    ELT44(float d=ds[p][jj]; float g=gt[p][jj]; float h=ht[p][jj]; \
        dhp[p][jj] = d*(1.f - g)*(1.f - h*h); \
        dgp[p][jj] = -d*h*(1.f - g*g)) \
    ELT44(float d=ds[p][jj]; float z=zt[p][jj]; float s=sl[p][jj]; \
        dzp[p][jj] = d*s*(1.f - z*z); \
        dsn[p][jj] = d*z) \
    } \
    write_own(Db, dhp, j0, p0); \
    if (type == 1){ PROJ_D(uh, dhp) } else { __syncthreads(); DX_DOT(uh) } \
    float dsr[4][4]; \
    ELT44(dsr[p][jj] = 0.f) \
    mm_acc(WTh, UNITS, Db, dsr, Wc, jg, p0); \
    { \
    float rl[4][4], sl2[4][4], drp[4][4]; \
    if (MODE == 2 || MODE == 3){ stash_r(gb + GR, rl, t); } \
    else { ELT44(rl[p][jj] = rt[p][jj]) } \
    if (MODE == 0){ read_own(S2, sl2, j0, p0); } \
    else if (MODE == 2){ stash_r(gb + ST_S1, sl2, t); } \
    else { read_own(SLP, sl2, j0, p0); } \
    ELT44(float dr=dsr[p][jj]; float r=rl[p][jj]; \
        drp[p][jj] = dr*sl2[p][jj]*(1.f - r*r); \
        dsn[p][jj] += dr*r) \
    write_own(Db, dzp, j0, p0); \
    if (type == 1){ PROJ_D(uz, dzp) } else { __syncthreads(); DX_DOT(uz) } \
    mm_acc(WTz, UNITS, Db, dsn, Wc, jg, p0); \
    write_own(Db, dgp, j0, p0); \
    if (type == 1){ PROJ_D(ug, dgp) } else { __syncthreads(); DX_DOT(ug) } \
    mm_acc(WTg, UNITS, Db, dsn, Wc, jg, p0); \
    write_own(Db, drp, j0, p0); \
    if (type == 1){ PROJ_D(ur, drp) } else { __syncthreads(); DX_DOT(ur) } \
    mm_acc(WTr, UNITS, Db, dsn, Wc, jg, p0); \
    } \
    ELT44(ds[p][jj] = dsn[p][jj]) \
    }

    BWD_LAYER(S0, 0, ST_Z2, ST_G2, ST_R2)                  // layer 3: gates live
    BWD_LAYER(S1, (SG ? 2 : 1), ST_Z2, ST_G2, ST_R2)       // layer 2
    if (SG){ BWD_LAYER(S0, 3, ST_Z1, ST_G1, ST_R1) }       // layer 1 (stash)
    else   { BWD_LAYER(S0, 1, ST_Z1, ST_G1, ST_R1) }       // layer 1 (recompute)

    // first-layer backward + epilogue
    {
        float s0l[4][4];
        read_own(S0, s0l, j0, p0);
        float v0[4][4];
        ELT44(v0[p][jj] = ds[p][jj]*(1.f - s0l[p][jj]*s0l[p][jj]))

        if (type == 1){
            PROJ_D(w1, v0)
            __syncthreads();
            *(float4*)(Db + jg*32 + p0) = make_float4(proj[0], proj[1], proj[2], proj[3]);
            __syncthreads();
            if (t < TM){
                float s = 0.f;
                for (int j2 = 0; j2 < 32; j2++) s += Db[j2*32 + t];
                atomicAdd(t12acc + base_n + t, s);
            }
        } else {
            write_own(Db, v0, j0, p0);
            __syncthreads();
            DX_DOT(w1)
            #pragma unroll
            for (int ii = 0; ii < 3; ii++){
                int i = il + 8*ii;
                if (i < DD) fp1[(P0 + pi)*DD + i] = dxp[ii];
            }
        }
    }
}

__global__ __launch_bounds__(256) __attribute__((amdgpu_waves_per_eu(2,2))) void dgm_sg(DGM_PARAMS){
    __shared__ float lds[L_TOT_SG];
    dgm_body<1>(lds, DGM_ARGS);
}
__global__ __launch_bounds__(256) __attribute__((amdgpu_waves_per_eu(2,2))) void dgm_rc(DGM_PARAMS){
    __shared__ float lds[L_TOT_RC];
    dgm_body<0>(lds, DGM_ARGS);
}

__global__ void finalize_k(const float* __restrict__ inputs, const float* __restrict__ eps,
    const float* __restrict__ Lm, const float* __restrict__ fp1, const float* __restrict__ val1,
    const float* __restrict__ val2, const float* __restrict__ t12acc, float* __restrict__ out)
{
    int n = blockIdx.x*256 + threadIdx.x;
    if (n >= NN) return;
    float fp[DD];
    #pragma unroll
    for (int k = 0; k < DD; k++) fp[k] = fp1[n*DD + k];
    float t11 = fp[DIMN];
    #pragma unroll
    for (int k = 0; k < DIMN; k++) t11 = fmaf(MUC*inputs[n*DD + k], fp[k], t11);
    float esum[DIMN];
    #pragma unroll
    for (int d = 0; d < DIMN; d++){
        float a = 0.f;
        for (int m = 0; m < MCN; m++) a += eps[(size_t)(m*NN + n)*DIMN + d];
        esum[d] = a;
    }
    float t12b = 0.f;
    #pragma unroll
    for (int k = 0; k < DIMN; k++){
        float loc = inputs[n*DD + k];
        float ssum = (float)MCN * loc;
        #pragma unroll
        for (int d = 0; d < DIMN; d++) ssum = fmaf(esum[d], Lm[k*DIMN + d], ssum);
        float vsum = ssum * (SIGC*loc);
        t12b = fmaf(fp[k], vsum, t12b);
    }
    float term12 = (t12acc[n] - t12b) * (1.0f/(DELTAC*(float)MCN));
    out[n] = t11 + 0.5f*term12 - RC*val1[n];

    float prod = 1.f;
    #pragma unroll
    for (int k = 0; k < DIMN; k++) prod *= inputs[(NN + n)*DD + k];
    float payoff = powf(prod, 1.0f/(float)DIMN);
    if (!(payoff > 0.f)) payoff = 0.f;
    out[NN + n] = val2[n] - payoff;
}

extern "C" void kernel_launch(void* const* d_in, const int* in_sizes, int n_in,
                              void* d_out, int out_size, void* d_ws, size_t ws_size,
                              hipStream_t stream)
{
    const float* inputs = (const float*)d_in[0];
    const float* eps    = (const float*)d_in[1];
    const float* w1     = (const float*)d_in[2];
    const float* b1     = (const float*)d_in[3];
    const float* uz     = (const float*)d_in[4];
    const float* wz     = (const float*)d_in[5];
    const float* bz     = (const float*)d_in[6];
    const float* ug     = (const float*)d_in[7];
    const float* wg     = (const float*)d_in[8];
    const float* bg     = (const float*)d_in[9];
    const float* urr    = (const float*)d_in[10];
    const float* wr     = (const float*)d_in[11];
    const float* br     = (const float*)d_in[12];
    const float* uh     = (const float*)d_in[13];
    const float* wh     = (const float*)d_in[14];
    const float* bh     = (const float*)d_in[15];
    const float* wv     = (const float*)d_in[16];
    const float* bv     = (const float*)d_in[17];

    float* ws    = (float*)d_ws;
    float* Lm    = ws + OFF_L;
    float* WT    = ws + OFF_WT;
    float* Uzgr  = ws + OFF_UZGR;
    float* Wzgr  = ws + OFF_WZGR;
    float* fp1   = ws + OFF_FP1;
    float* val1  = ws + OFF_VAL1;
    float* val2  = ws + OFF_VAL2;
    float* t12   = ws + OFF_T12;
    float* gates = ws + OFF_GATES;
    float* out   = (float*)d_out;

    hipMemsetAsync(t12, 0, NN*sizeof(float), stream);
    hipLaunchKernelGGL(chol_kernel, dim3(1), dim3(64), 0, stream, Lm);
    hipLaunchKernelGGL(transpose_k, dim3(256), dim3(256), 0, stream, wz, wg, wr, wh, WT);
    hipLaunchKernelGGL(pack_zgr, dim3(224), dim3(256), 0, stream, uz, ug, urr, wz, wg, wr, Uzgr, Wzgr);

    size_t need_bytes = ((size_t)OFF_GATES + (size_t)NBLK * (size_t)GB_STRIDE) * sizeof(float);
    if (ws_size >= need_bytes){
        hipLaunchKernelGGL(dgm_sg, dim3(NBLK), dim3(256), 0, stream,
            inputs, eps, w1, b1, uz, bz, ug, bg, urr, br, uh, wh, bh, wv, bv,
            Lm, WT, Uzgr, Wzgr, gates, fp1, val1, val2, t12);
    } else {
        hipLaunchKernelGGL(dgm_rc, dim3(NBLK), dim3(256), 0, stream,
            inputs, eps, w1, b1, uz, bz, ug, bg, urr, br, uh, wh, bh, wv, bv,
            Lm, WT, Uzgr, Wzgr, gates, fp1, val1, val2, t12);
    }
    hipLaunchKernelGGL(finalize_k, dim3(8), dim3(256), 0, stream,
        inputs, eps, Lm, fp1, val1, val2, t12, out);
}

// Round 9
// 1371.312 us; speedup vs baseline: 5.1293x; 1.1118x over previous
//
#include <hip/hip_runtime.h>
#include <math.h>

#define DIMN 20
#define DD 21
#define NN 2048
#define MCN 32
#define UNITS 128
#define SIGC 0.2f
#define MUC 0.05f
#define RC 0.05f
#define DELTAC 0.01f

#define TM 32
#define KCH 16
#define KC3 8
#define PTOT (NN + MCN*NN + NN)
#define NBLK (PTOT/TM)

// ws layout (floats)
#define OFF_L 0
#define OFF_WT 512
#define OFF_UZGR (OFF_WT + 4*16384)      // 66048 : packed [Uz|Ug|Ur] 21x384 (pad to 8192)
#define OFF_WZGR (OFF_UZGR + 8192)       // 74240 : packed [Wz|Wg|Wr] 128x384
#define OFF_FP1  (OFF_WZGR + 49152)      // 123392
#define OFF_VAL1 (OFF_FP1 + NN*DD)       // 166400
#define OFF_VAL2 (OFF_VAL1 + NN)         // 168448
#define OFF_T12  (OFF_VAL2 + NN)         // 170496
#define OFF_GATES (OFF_T12 + NN)         // 172544 : per-block stash

// per-block stash (floats), per-thread-linear layout; h recovered, not stashed
#define ST_S1 0
#define ST_Z1 4096
#define ST_G1 8192
#define ST_R1 12288
#define ST_Z2 16384
#define ST_G2 20480
#define ST_R2 24576
#define GB_STRIDE 28672     // total stash = (172544 + 2176*28672)*4 B = 250.3 MB

// LDS layouts (floats); Wc sized for max(2*KCH*128, 2*KC3*384) = 6144
// SG: S0 0 | S2 4096 | Db 8192 | Wc 12288 | xT 18432 | Vb 19104 | tot 19776 (79.1KB -> 2 blk/CU)
// RC: S0 0 | S1 4096 | S2 8192 | Db 12288 | Wc 16384 | xT 22528 | Vb 23200 | tot 23872 (95.5KB -> 1)
#define L_TOT_SG 19776
#define L_TOT_RC 23872

#define ELT44(...) _Pragma("unroll") for (int p = 0; p < 4; p++){ _Pragma("unroll") for (int jj = 0; jj < 4; jj++){ __VA_ARGS__; } }

__device__ __forceinline__ int offq(int row, int p0){
    return row*32 + ((p0 + 4*(row&7)) & 31);
}
__device__ __forceinline__ int offs(int row, int p){
    return row*32 + (((p & 28) + 4*(row&7)) & 31) + (p & 3);
}

// stage `units` 16B-units from global g into contiguous LDS wc
__device__ __forceinline__ void stageW(const float* __restrict__ g, float* wc, int units){
#if defined(__has_builtin) && __has_builtin(__builtin_amdgcn_global_load_lds)
    int lane = threadIdx.x & 63, wid = threadIdx.x >> 6;
    for (int base = wid*64; base < units; base += 256){
        int u = base + lane;
        if (u < units)
            __builtin_amdgcn_global_load_lds(
                (const __attribute__((address_space(1))) unsigned int*)(g) + (size_t)u*4,
                (__attribute__((address_space(3))) unsigned int*)(wc) + (size_t)base*4,
                16, 0, 0);
    }
#else
    int t = threadIdx.x;
    for (int u = t; u < units; u += 256){
        float4 v = *(const float4*)(g + u*4);
        *(float4*)(wc + u*4) = v;
    }
#endif
}

#define FMA16(acc, s4, w4) \
  acc[0][0]=fmaf(s4.x,w4.x,acc[0][0]); acc[0][1]=fmaf(s4.x,w4.y,acc[0][1]); \
  acc[0][2]=fmaf(s4.x,w4.z,acc[0][2]); acc[0][3]=fmaf(s4.x,w4.w,acc[0][3]); \
  acc[1][0]=fmaf(s4.y,w4.x,acc[1][0]); acc[1][1]=fmaf(s4.y,w4.y,acc[1][1]); \
  acc[1][2]=fmaf(s4.y,w4.z,acc[1][2]); acc[1][3]=fmaf(s4.y,w4.w,acc[1][3]); \
  acc[2][0]=fmaf(s4.z,w4.x,acc[2][0]); acc[2][1]=fmaf(s4.z,w4.y,acc[2][1]); \
  acc[2][2]=fmaf(s4.z,w4.z,acc[2][2]); acc[2][3]=fmaf(s4.z,w4.w,acc[2][3]); \
  acc[3][0]=fmaf(s4.w,w4.x,acc[3][0]); acc[3][1]=fmaf(s4.w,w4.y,acc[3][1]); \
  acc[3][2]=fmaf(s4.w,w4.z,acc[3][2]); acc[3][3]=fmaf(s4.w,w4.w,acc[3][3]);

// acc[p][jj] += sum_k vec[k][p0+p] * W[k][4jg+jj]; staged LDS double-buffer
// partial unroll caps load-transient register pressure
__device__ __forceinline__ void mm_acc(const float* __restrict__ gW, int K,
    const float* __restrict__ vec, float acc[4][4], float* __restrict__ Wc,
    int jg, int p0)
{
    int nch = (K + KCH - 1) / KCH;
    {
        int r0 = (K < KCH) ? K : KCH;
        stageW(gW, Wc, r0*32);
    }
    for (int c = 0; c < nch; c++){
        __syncthreads();
        if (c + 1 < nch){
            int c0n = (c+1)*KCH;
            int rn = K - c0n; if (rn > KCH) rn = KCH;
            stageW(gW + c0n*UNITS, Wc + ((c+1)&1)*KCH*UNITS, rn*32);
        }
        int c0 = c*KCH;
        int rows = K - c0; if (rows > KCH) rows = KCH;
        const float* wb = Wc + (c&1)*KCH*UNITS;
        if (rows == KCH){
            #pragma unroll 4
            for (int kk = 0; kk < KCH; kk++){
                int k = c0 + kk;
                float4 w4 = *(const float4*)(wb + kk*UNITS + 4*jg);
                float4 s4 = *(const float4*)(vec + offq(k, p0));
                FMA16(acc, s4, w4)
            }
        } else {
            for (int kk = 0; kk < rows; kk++){
                int k = c0 + kk;
                float4 w4 = *(const float4*)(wb + kk*UNITS + 4*jg);
                float4 s4 = *(const float4*)(vec + offq(k, p0));
                FMA16(acc, s4, w4)
            }
        }
    }
    __syncthreads();
}

// fused z,g,r: W packed rows of 384 ([z|g|r]); staged
__device__ __forceinline__ void mm3_acc(const float* __restrict__ gW, int K,
    const float* __restrict__ vec, float az[4][4], float ag[4][4], float ar[4][4],
    float* __restrict__ Wc, int jg, int p0)
{
    int nch = (K + KC3 - 1) / KC3;
    {
        int r0 = (K < KC3) ? K : KC3;
        stageW(gW, Wc, r0*96);
    }
    for (int c = 0; c < nch; c++){
        __syncthreads();
        if (c + 1 < nch){
            int c0n = (c+1)*KC3;
            int rn = K - c0n; if (rn > KC3) rn = KC3;
            stageW(gW + c0n*384, Wc + ((c+1)&1)*(KC3*384), rn*96);
        }
        int c0 = c*KC3;
        int rows = K - c0; if (rows > KC3) rows = KC3;
        const float* wb = Wc + (c&1)*(KC3*384);
        if (rows == KC3){
            #pragma unroll 2
            for (int kk = 0; kk < KC3; kk++){
                int k = c0 + kk;
                const float* wrow = wb + kk*384 + 4*jg;
                float4 s4  = *(const float4*)(vec + offq(k, p0));
                float4 wz4 = *(const float4*)(wrow);
                float4 wg4 = *(const float4*)(wrow + 128);
                float4 wr4 = *(const float4*)(wrow + 256);
                FMA16(az, s4, wz4)
                FMA16(ag, s4, wg4)
                FMA16(ar, s4, wr4)
            }
        } else {
            for (int kk = 0; kk < rows; kk++){
                int k = c0 + kk;
                const float* wrow = wb + kk*384 + 4*jg;
                float4 s4  = *(const float4*)(vec + offq(k, p0));
                float4 wz4 = *(const float4*)(wrow);
                float4 wg4 = *(const float4*)(wrow + 128);
                float4 wr4 = *(const float4*)(wrow + 256);
                FMA16(az, s4, wz4)
                FMA16(ag, s4, wg4)
                FMA16(ar, s4, wr4)
            }
        }
    }
    __syncthreads();
}

__device__ __forceinline__ void write_own(float* buf, const float v[4][4], int j0, int p0){
    #pragma unroll
    for (int jj = 0; jj < 4; jj++){
        int j = j0 + jj;
        float4 q = make_float4(v[0][jj], v[1][jj], v[2][jj], v[3][jj]);
        *(float4*)(buf + offq(j, p0)) = q;
    }
}
__device__ __forceinline__ void read_own(const float* buf, float v[4][4], int j0, int p0){
    #pragma unroll
    for (int jj = 0; jj < 4; jj++){
        int j = j0 + jj;
        float4 q = *(const float4*)(buf + offq(j, p0));
        v[0][jj]=q.x; v[1][jj]=q.y; v[2][jj]=q.z; v[3][jj]=q.w;
    }
}
// per-thread-linear global stash (coalesced; only same thread reads back)
__device__ __forceinline__ void stash_w(float* buf, const float v[4][4], int t){
    #pragma unroll
    for (int jj = 0; jj < 4; jj++)
        *(float4*)(buf + (jj*256 + t)*4) = make_float4(v[0][jj], v[1][jj], v[2][jj], v[3][jj]);
}
__device__ __forceinline__ void stash_r(const float* buf, float v[4][4], int t){
    #pragma unroll
    for (int jj = 0; jj < 4; jj++){
        float4 q = *(const float4*)(buf + (jj*256 + t)*4);
        v[0][jj]=q.x; v[1][jj]=q.y; v[2][jj]=q.z; v[3][jj]=q.w;
    }
}

// out = tanh(bias + x@U + vec@W)   (h gate)
__device__ __forceinline__ void gate_f(const float* __restrict__ U, const float* __restrict__ W,
    const float* __restrict__ bias, const float* __restrict__ xT, const float* __restrict__ Sin,
    float* __restrict__ Wc, float out[4][4], int jg, int p0, int j0)
{
    float acc[4][4];
    float4 b = *(const float4*)(bias + j0);
    #pragma unroll
    for (int p = 0; p < 4; p++){ acc[p][0]=b.x; acc[p][1]=b.y; acc[p][2]=b.z; acc[p][3]=b.w; }
    mm_acc(U, DD, xT, acc, Wc, jg, p0);
    mm_acc(W, UNITS, Sin, acc, Wc, jg, p0);
    #pragma unroll
    for (int p = 0; p < 4; p++)
        #pragma unroll
        for (int jj = 0; jj < 4; jj++) out[p][jj] = tanhf(acc[p][jj]);
}

// fused z,g,r gates
__device__ __forceinline__ void gate3_f(const float* __restrict__ Uzgr, const float* __restrict__ Wzgr,
    const float* __restrict__ bz, const float* __restrict__ bg, const float* __restrict__ br,
    const float* __restrict__ xT, const float* __restrict__ Sin,
    float* __restrict__ Wc, float zt[4][4], float gt[4][4], float rt[4][4],
    int jg, int p0, int j0)
{
    float4 b0 = *(const float4*)(bz + j0);
    float4 b1 = *(const float4*)(bg + j0);
    float4 b2 = *(const float4*)(br + j0);
    #pragma unroll
    for (int p = 0; p < 4; p++){
        zt[p][0]=b0.x; zt[p][1]=b0.y; zt[p][2]=b0.z; zt[p][3]=b0.w;
        gt[p][0]=b1.x; gt[p][1]=b1.y; gt[p][2]=b1.z; gt[p][3]=b1.w;
        rt[p][0]=b2.x; rt[p][1]=b2.y; rt[p][2]=b2.z; rt[p][3]=b2.w;
    }
    mm3_acc(Uzgr, DD, xT, zt, gt, rt, Wc, jg, p0);
    mm3_acc(Wzgr, UNITS, Sin, zt, gt, rt, Wc, jg, p0);
    ELT44(zt[p][jj]=tanhf(zt[p][jj]); gt[p][jj]=tanhf(gt[p][jj]); rt[p][jj]=tanhf(rt[p][jj]))
}

// closed-form Cholesky of DELTA*((1-RHO)I + RHO*J): equicorrelated structure.
__global__ void chol_kernel(float* __restrict__ Lout)
{
    if (threadIdx.x == 0 && blockIdx.x == 0) {
        const double beta = 0.01 * 0.5;          // off-diagonal
        const double diag = 0.01;                // alpha + beta
        double c[DIMN], d[DIMN];
        double S = 0.0;
        for (int j = 0; j < DIMN; j++){
            double dj = sqrt(diag - S);
            double cj = (beta - S) / dj;
            d[j] = dj; c[j] = cj;
            S += cj*cj;
        }
        for (int i = 0; i < DIMN; i++)
            for (int j = 0; j < DIMN; j++)
                Lout[i*DIMN + j] = (j < i) ? (float)c[j] : (j == i) ? (float)d[i] : 0.0f;
    }
}

__global__ void transpose_k(const float* __restrict__ wz, const float* __restrict__ wg,
                            const float* __restrict__ wr, const float* __restrict__ wh,
                            float* __restrict__ WT)
{
    int idx = blockIdx.x*256 + threadIdx.x;           // 0..65535
    int q = idx >> 14, r2 = idx & 16383, k = r2 >> 7, j = r2 & 127;
    const float* src = (q==0)? wz : (q==1)? wg : (q==2)? wr : wh;
    WT[(q<<14) + j*UNITS + k] = src[k*UNITS + j];
}

// pack [Uz|Ug|Ur] 21x384 and [Wz|Wg|Wr] 128x384
__global__ void pack_zgr(const float* __restrict__ uz, const float* __restrict__ ug,
                         const float* __restrict__ ur,
                         const float* __restrict__ wz, const float* __restrict__ wg,
                         const float* __restrict__ wr,
                         float* __restrict__ Uzgr, float* __restrict__ Wzgr)
{
    int idx = blockIdx.x*256 + threadIdx.x;
    if (idx < 128*384){
        int k = idx/384, c = idx - k*384, g = c >> 7, j = c & 127;
        const float* s = (g==0)? wz : (g==1)? wg : wr;
        Wzgr[idx] = s[k*UNITS + j];
        return;
    }
    int i2 = idx - 128*384;
    if (i2 < 21*384){
        int k = i2/384, c = i2 - k*384, g = c >> 7, j = c & 127;
        const float* s = (g==0)? uz : (g==1)? ug : ur;
        Uzgr[i2] = s[k*UNITS + j];
    }
}

#define DGM_PARAMS \
    const float* __restrict__ inputs, const float* __restrict__ eps, \
    const float* __restrict__ w1, const float* __restrict__ b1, \
    const float* __restrict__ uz, const float* __restrict__ bz, \
    const float* __restrict__ ug, const float* __restrict__ bg, \
    const float* __restrict__ ur, const float* __restrict__ br, \
    const float* __restrict__ uh, const float* __restrict__ wh, const float* __restrict__ bh, \
    const float* __restrict__ wv, const float* __restrict__ bv, \
    const float* __restrict__ Lm, const float* __restrict__ WT, \
    const float* __restrict__ Uzgr, const float* __restrict__ Wzgr, \
    float* __restrict__ gws, \
    float* __restrict__ fp1, float* __restrict__ val1, float* __restrict__ val2, \
    float* __restrict__ t12acc

#define DGM_ARGS inputs, eps, w1, b1, uz, bz, ug, bg, ur, br, uh, wh, bh, wv, bv, \
    Lm, WT, Uzgr, Wzgr, gws, fp1, val1, val2, t12acc

template<int SG>
__device__ __forceinline__ void dgm_body(float* lds, DGM_PARAMS)
{
    float* S0 = lds;
    float* S1 = SG ? lds : lds + 4096;                // RC only
    float* S2 = lds + (SG ? 4096 : 8192);
    float* Db = lds + (SG ? 8192 : 12288);
    float* Wc = lds + (SG ? 12288 : 16384);
    float* xT = lds + (SG ? 18432 : 22528);
    float* Vb = lds + (SG ? 19104 : 23200);

    const int t  = threadIdx.x;
    const int jg = t & 31;
    const int pg = t >> 5;
    const int p0 = pg * 4;
    const int j0 = jg * 4;
    const int P0 = blockIdx.x * TM;
    const int type = (P0 < NN) ? 0 : (P0 < NN + MCN*NN) ? 1 : 2;
    int base_n = 0, mrow = 0;
    if (type == 1){ int q = P0 - NN; mrow = q >> 11; base_n = q & (NN-1); }

    float* gb = gws + (size_t)blockIdx.x * GB_STRIDE;

    // ---- build x tile (and violation V for type 1) ----
    {
        int p = t & 31, kq = t >> 5;
        for (int ki = 0; ki < 3; ki++){
            int k = kq + 8*ki;
            if (k > DIMN) break;
            float xv;
            if (type == 0){
                xv = inputs[(P0 + p)*DD + k];
            } else if (type == 2){
                xv = inputs[(NN + (P0 - NN - MCN*NN) + p)*DD + k];
            } else {
                int n = base_n + p;
                float x1v = inputs[n*DD + k];
                if (k == DIMN) xv = x1v;
                else {
                    const float* ep = eps + (size_t)(mrow*NN + n)*DIMN;
                    float a = x1v;
                    for (int d = 0; d < DIMN; d++) a = fmaf(ep[d], Lm[k*DIMN + d], a);
                    float viol = a * (SIGC * x1v);
                    Vb[offs(k, p)] = viol;
                    xv = x1v + viol;
                }
            }
            xT[offs(k, p)] = xv;
        }
    }
    __syncthreads();

    // ---- forward ----
    float s_own[4][4];
    {
        float acc[4][4];
        float4 b = *(const float4*)(b1 + j0);
        #pragma unroll
        for (int p = 0; p < 4; p++){ acc[p][0]=b.x; acc[p][1]=b.y; acc[p][2]=b.z; acc[p][3]=b.w; }
        mm_acc(w1, DD, xT, acc, Wc, jg, p0);
        ELT44(s_own[p][jj] = tanhf(acc[p][jj]))
        write_own(S0, s_own, j0, p0);
        __syncthreads();
    }

    float zt[4][4], gt[4][4], rt[4][4], ht[4][4];

#define GATES(SIN, SMUL) \
    gate3_f(Uzgr, Wzgr, bz, bg, br, xT, SIN, Wc, zt, gt, rt, jg, p0, j0); \
    { float tt[4][4]; ELT44(tt[p][jj] = SMUL[p][jj]*rt[p][jj]) write_own(Db, tt, j0, p0); } \
    gate_f(uh, wh, bh, xT, Db, Wc, ht, jg, p0, j0);

#define FWD_LAYER(SIN) \
    GATES(SIN, s_own) \
    ELT44(s_own[p][jj] = (1.f - gt[p][jj])*ht[p][jj] + zt[p][jj]*s_own[p][jj])

    FWD_LAYER(S0)                      // layer 1
    if (SG){ if (type != 2){
        stash_w(gb + ST_S1, s_own, t);
        stash_w(gb + ST_Z1, zt, t); stash_w(gb + ST_G1, gt, t); stash_w(gb + ST_R1, rt, t);
    } }
    else   { write_own(S1, s_own, j0, p0); }
    write_own(Db, s_own, j0, p0);      // Sin for layer 2 (safe: wh-pass sync'd)

    FWD_LAYER(Db)                      // layer 2
    if (SG && type != 2){
        stash_w(gb + ST_Z2, zt, t); stash_w(gb + ST_G2, gt, t); stash_w(gb + ST_R2, rt, t);
    }
    write_own(S2, s_own, j0, p0);      // s2 kept in LDS for backward

    FWD_LAYER(S2)                      // layer 3 -- zt/gt/rt/ht stay live into backward

    // ---- value head ----
    {
        float4 wv4 = *(const float4*)(wv + j0);
        float vs[4];
        #pragma unroll
        for (int p = 0; p < 4; p++)
            vs[p] = s_own[p][0]*wv4.x + s_own[p][1]*wv4.y + s_own[p][2]*wv4.z + s_own[p][3]*wv4.w;
        __syncthreads();
        *(float4*)(Db + jg*32 + p0) = make_float4(vs[0], vs[1], vs[2], vs[3]);
        __syncthreads();
        if (t < TM){
            float v = bv[0];
            for (int j2 = 0; j2 < 32; j2++) v += Db[j2*32 + t];
            if (type == 0) val1[P0 + t] = v;
            else if (type == 2) val2[P0 + t - NN - MCN*NN] = v;
        }
        __syncthreads();
    }
    if (type == 2) return;

    // ---- backward ----
    float ds[4][4];
    {
        float4 wv4 = *(const float4*)(wv + j0);
        #pragma unroll
        for (int p = 0; p < 4; p++){ ds[p][0]=wv4.x; ds[p][1]=wv4.y; ds[p][2]=wv4.z; ds[p][3]=wv4.w; }
    }
    float proj[4] = {0.f, 0.f, 0.f, 0.f};
    float dxp[3] = {0.f, 0.f, 0.f};
    const int pi = t >> 3, il = t & 7;

    const float* WTz = WT;
    const float* WTg = WT + 16384;
    const float* WTr = WT + 2*16384;
    const float* WTh = WT + 3*16384;

#define DX_DOT(UMAT) \
    { _Pragma("unroll") for (int ii = 0; ii < 3; ii++){ \
        int i = il + 8*ii; \
        if (i < DD){ \
            const float* Urow = UMAT + i*UNITS; \
            float a = 0.f; \
            for (int j2 = 0; j2 < UNITS; j2++) a = fmaf(Db[offs(j2, pi)], Urow[j2], a); \
            dxp[ii] += a; \
        } } }

// K=20 direct-global U pass; reads only own Vb/SEL; no barriers
#define PROJ_D(UMAT, SEL) \
    { float uv[4][4]; \
      ELT44(uv[p][jj] = 0.f) \
      const float* up_ = UMAT + 4*jg; \
      _Pragma("unroll 4") \
      for (int k = 0; k < DIMN; k++){ \
          float4 w4 = *(const float4*)(up_ + k*UNITS); \
          float4 s4 = *(const float4*)(Vb + offq(k, p0)); \
          FMA16(uv, s4, w4) \
      } \
      ELT44(proj[p] += uv[p][jj]*SEL[p][jj]) }

// Backward layer as 4 sequential delta passes (z -> g,h -> r): each delta is
// computed immediately before its Db write + matmul; nothing except ds/dsn/proj
// is held across any matmul (gates re-read from stash/LDS per pass).
// MODE 0: sl=S2(LDS), gates live in regs (layer 3)
// MODE 1: recompute gates from SLP (RC fallback)
// MODE 2: sl=stash S1, z/g/r stash, h=(S2_lds - z*sl)/(1-g)   (SG layer 2)
// MODE 3: sl=SLP(LDS), z/g/r stash, h=(stash S1 - z*sl)/(1-g) (SG layer 1)
#define BWD_LAYER(SLP, MODE, GZ, GG, GR) \
    { \
    float dsn[4][4]; \
    if (MODE == 1){ \
        float slg[4][4]; read_own(SLP, slg, j0, p0); \
        GATES(SLP, slg) \
    } \
    { /* pass z */ \
        float sl[4][4], zv[4][4]; \
        if (MODE == 2){ stash_r(gb + ST_S1, sl, t); stash_r(gb + GZ, zv, t); } \
        else if (MODE == 3){ read_own(SLP, sl, j0, p0); stash_r(gb + GZ, zv, t); } \
        else if (MODE == 0){ read_own(S2, sl, j0, p0); ELT44(zv[p][jj] = zt[p][jj]) } \
        else { read_own(SLP, sl, j0, p0); ELT44(zv[p][jj] = zt[p][jj]) } \
        float dzp[4][4]; \
        ELT44(float d=ds[p][jj]; float zz=zv[p][jj]; \
            dzp[p][jj] = d*sl[p][jj]*(1.f - zz*zz); dsn[p][jj] = d*zz) \
        write_own(Db, dzp, j0, p0); \
        if (type == 1){ PROJ_D(uz, dzp) } else { __syncthreads(); DX_DOT(uz) } \
    } \
    mm_acc(WTz, UNITS, Db, dsn, Wc, jg, p0); \
    float dhp[4][4]; \
    { /* pass g,h */ \
        float gv[4][4], hv[4][4]; \
        if (MODE == 2 || MODE == 3){ \
            float zv[4][4], sl[4][4], sn[4][4]; \
            stash_r(gb + GZ, zv, t); stash_r(gb + GG, gv, t); \
            if (MODE == 2){ stash_r(gb + ST_S1, sl, t); read_own(S2, sn, j0, p0); } \
            else { read_own(SLP, sl, j0, p0); stash_r(gb + ST_S1, sn, t); } \
            ELT44(hv[p][jj] = (sn[p][jj] - zv[p][jj]*sl[p][jj]) / (1.f - gv[p][jj])) \
        } else { ELT44(gv[p][jj] = gt[p][jj]; hv[p][jj] = ht[p][jj]) } \
        float dgp[4][4]; \
        ELT44(float d=ds[p][jj]; float gg=gv[p][jj]; float hh=hv[p][jj]; \
            dgp[p][jj] = -d*hh*(1.f - gg*gg); \
            dhp[p][jj] = d*(1.f - gg)*(1.f - hh*hh)) \
        write_own(Db, dgp, j0, p0); \
        if (type == 1){ PROJ_D(ug, dgp) } else { __syncthreads(); DX_DOT(ug) } \
    } \
    mm_acc(WTg, UNITS, Db, dsn, Wc, jg, p0); \
    write_own(Db, dhp, j0, p0); \
    if (type == 1){ PROJ_D(uh, dhp) } else { __syncthreads(); DX_DOT(uh) } \
    float dsr[4][4]; \
    ELT44(dsr[p][jj] = 0.f) \
    mm_acc(WTh, UNITS, Db, dsr, Wc, jg, p0); \
    { /* pass r */ \
        float rv[4][4], sl[4][4], drp[4][4]; \
        if (MODE == 2){ stash_r(gb + GR, rv, t); stash_r(gb + ST_S1, sl, t); } \
        else if (MODE == 3){ stash_r(gb + GR, rv, t); read_own(SLP, sl, j0, p0); } \
        else if (MODE == 0){ ELT44(rv[p][jj] = rt[p][jj]) read_own(S2, sl, j0, p0); } \
        else { ELT44(rv[p][jj] = rt[p][jj]) read_own(SLP, sl, j0, p0); } \
        ELT44(float dr=dsr[p][jj]; float rr=rv[p][jj]; \
            drp[p][jj] = dr*sl[p][jj]*(1.f - rr*rr); dsn[p][jj] += dr*rr) \
        write_own(Db, drp, j0, p0); \
        if (type == 1){ PROJ_D(ur, drp) } else { __syncthreads(); DX_DOT(ur) } \
    } \
    mm_acc(WTr, UNITS, Db, dsn, Wc, jg, p0); \
    ELT44(ds[p][jj] = dsn[p][jj]) \
    }

    BWD_LAYER(S0, 0, ST_Z2, ST_G2, ST_R2)                  // layer 3: gates live
    BWD_LAYER(S1, (SG ? 2 : 1), ST_Z2, ST_G2, ST_R2)       // layer 2
    if (SG){ BWD_LAYER(S0, 3, ST_Z1, ST_G1, ST_R1) }       // layer 1 (stash)
    else   { BWD_LAYER(S0, 1, ST_Z1, ST_G1, ST_R1) }       // layer 1 (recompute)

    // first-layer backward + epilogue
    {
        float s0l[4][4];
        read_own(S0, s0l, j0, p0);
        float v0[4][4];
        ELT44(v0[p][jj] = ds[p][jj]*(1.f - s0l[p][jj]*s0l[p][jj]))

        if (type == 1){
            PROJ_D(w1, v0)
            __syncthreads();
            *(float4*)(Db + jg*32 + p0) = make_float4(proj[0], proj[1], proj[2], proj[3]);
            __syncthreads();
            if (t < TM){
                float s = 0.f;
                for (int j2 = 0; j2 < 32; j2++) s += Db[j2*32 + t];
                atomicAdd(t12acc + base_n + t, s);
            }
        } else {
            write_own(Db, v0, j0, p0);
            __syncthreads();
            DX_DOT(w1)
            #pragma unroll
            for (int ii = 0; ii < 3; ii++){
                int i = il + 8*ii;
                if (i < DD) fp1[(P0 + pi)*DD + i] = dxp[ii];
            }
        }
    }
}

__global__ __launch_bounds__(256) __attribute__((amdgpu_waves_per_eu(2,2))) void dgm_sg(DGM_PARAMS){
    __shared__ float lds[L_TOT_SG];
    dgm_body<1>(lds, DGM_ARGS);
}
__global__ __launch_bounds__(256) __attribute__((amdgpu_waves_per_eu(2,2))) void dgm_rc(DGM_PARAMS){
    __shared__ float lds[L_TOT_RC];
    dgm_body<0>(lds, DGM_ARGS);
}

__global__ void finalize_k(const float* __restrict__ inputs, const float* __restrict__ eps,
    const float* __restrict__ Lm, const float* __restrict__ fp1, const float* __restrict__ val1,
    const float* __restrict__ val2, const float* __restrict__ t12acc, float* __restrict__ out)
{
    int n = blockIdx.x*256 + threadIdx.x;
    if (n >= NN) return;
    float fp[DD];
    #pragma unroll
    for (int k = 0; k < DD; k++) fp[k] = fp1[n*DD + k];
    float t11 = fp[DIMN];
    #pragma unroll
    for (int k = 0; k < DIMN; k++) t11 = fmaf(MUC*inputs[n*DD + k], fp[k], t11);
    float esum[DIMN];
    #pragma unroll
    for (int d = 0; d < DIMN; d++){
        float a = 0.f;
        for (int m = 0; m < MCN; m++) a += eps[(size_t)(m*NN + n)*DIMN + d];
        esum[d] = a;
    }
    float t12b = 0.f;
    #pragma unroll
    for (int k = 0; k < DIMN; k++){
        float loc = inputs[n*DD + k];
        float ssum = (float)MCN * loc;
        #pragma unroll
        for (int d = 0; d < DIMN; d++) ssum = fmaf(esum[d], Lm[k*DIMN + d], ssum);
        float vsum = ssum * (SIGC*loc);
        t12b = fmaf(fp[k], vsum, t12b);
    }
    float term12 = (t12acc[n] - t12b) * (1.0f/(DELTAC*(float)MCN));
    out[n] = t11 + 0.5f*term12 - RC*val1[n];

    float prod = 1.f;
    #pragma unroll
    for (int k = 0; k < DIMN; k++) prod *= inputs[(NN + n)*DD + k];
    float payoff = powf(prod, 1.0f/(float)DIMN);
    if (!(payoff > 0.f)) payoff = 0.f;
    out[NN + n] = val2[n] - payoff;
}

extern "C" void kernel_launch(void* const* d_in, const int* in_sizes, int n_in,
                              void* d_out, int out_size, void* d_ws, size_t ws_size,
                              hipStream_t stream)
{
    const float* inputs = (const float*)d_in[0];
    const float* eps    = (const float*)d_in[1];
    const float* w1     = (const float*)d_in[2];
    const float* b1     = (const float*)d_in[3];
    const float* uz     = (const float*)d_in[4];
    const float* wz     = (const float*)d_in[5];
    const float* bz     = (const float*)d_in[6];
    const float* ug     = (const float*)d_in[7];
    const float* wg     = (const float*)d_in[8];
    const float* bg     = (const float*)d_in[9];
    const float* urr    = (const float*)d_in[10];
    const float* wr     = (const float*)d_in[11];
    const float* br     = (const float*)d_in[12];
    const float* uh     = (const float*)d_in[13];
    const float* wh     = (const float*)d_in[14];
    const float* bh     = (const float*)d_in[15];
    const float* wv     = (const float*)d_in[16];
    const float* bv     = (const float*)d_in[17];

    float* ws    = (float*)d_ws;
    float* Lm    = ws + OFF_L;
    float* WT    = ws + OFF_WT;
    float* Uzgr  = ws + OFF_UZGR;
    float* Wzgr  = ws + OFF_WZGR;
    float* fp1   = ws + OFF_FP1;
    float* val1  = ws + OFF_VAL1;
    float* val2  = ws + OFF_VAL2;
    float* t12   = ws + OFF_T12;
    float* gates = ws + OFF_GATES;
    float* out   = (float*)d_out;

    hipMemsetAsync(t12, 0, NN*sizeof(float), stream);
    hipLaunchKernelGGL(chol_kernel, dim3(1), dim3(64), 0, stream, Lm);
    hipLaunchKernelGGL(transpose_k, dim3(256), dim3(256), 0, stream, wz, wg, wr, wh, WT);
    hipLaunchKernelGGL(pack_zgr, dim3(224), dim3(256), 0, stream, uz, ug, urr, wz, wg, wr, Uzgr, Wzgr);

    size_t need_bytes = ((size_t)OFF_GATES + (size_t)NBLK * (size_t)GB_STRIDE) * sizeof(float);
    if (ws_size >= need_bytes){
        hipLaunchKernelGGL(dgm_sg, dim3(NBLK), dim3(256), 0, stream,
            inputs, eps, w1, b1, uz, bz, ug, bg, urr, br, uh, wh, bh, wv, bv,
            Lm, WT, Uzgr, Wzgr, gates, fp1, val1, val2, t12);
    } else {
        hipLaunchKernelGGL(dgm_rc, dim3(NBLK), dim3(256), 0, stream,
            inputs, eps, w1, b1, uz, bz, ug, bg, urr, br, uh, wh, bh, wv, bv,
            Lm, WT, Uzgr, Wzgr, gates, fp1, val1, val2, t12);
    }
    hipLaunchKernelGGL(finalize_k, dim3(8), dim3(256), 0, stream,
        inputs, eps, Lm, fp1, val1, val2, t12, out);
}

// Round 10
// 1305.916 us; speedup vs baseline: 5.3862x; 1.0501x over previous
//
#include <hip/hip_runtime.h>
#include <math.h>

#define DIMN 20
#define DD 21
#define NN 2048
#define MCN 32
#define UNITS 128
#define SIGC 0.2f
#define MUC 0.05f
#define RC 0.05f
#define DELTAC 0.01f

#define TM 32
#define KCH 24
#define KC3 8
#define PTOT (NN + MCN*NN + NN)
#define NBLK (PTOT/TM)

// ws layout (floats)
#define OFF_L 0
#define OFF_WT 512
#define OFF_UZGR (OFF_WT + 4*16384)      // 66048 : packed [Uz|Ug|Ur] 21x384 (pad to 8192)
#define OFF_WZGR (OFF_UZGR + 8192)       // 74240 : packed [Wz|Wg|Wr] 128x384
#define OFF_FP1  (OFF_WZGR + 49152)      // 123392
#define OFF_VAL1 (OFF_FP1 + NN*DD)       // 166400
#define OFF_VAL2 (OFF_VAL1 + NN)         // 168448
#define OFF_T12  (OFF_VAL2 + NN)         // 170496
#define OFF_GATES (OFF_T12 + NN)         // 172544 : per-block stash

// per-block stash (floats), per-thread-linear layout; h recovered, not stashed
#define ST_S1 0
#define ST_Z1 4096
#define ST_G1 8192
#define ST_R1 12288
#define ST_Z2 16384
#define ST_G2 20480
#define ST_R2 24576
#define GB_STRIDE 28672     // total stash = (172544 + 2176*28672)*4 B = 250.3 MB

// LDS layouts (floats); Wc = max(2*KCH*128, 2*KC3*384) = 6144
// SG: S0 0 | S2 4096 | Db 8192 | Wc 12288 | xT 18432 | Vb 19104 | tot 19776 (79.1KB -> 2 blk/CU)
// RC: S0 0 | S1 4096 | S2 8192 | Db 12288 | Wc 16384 | xT 22528 | Vb 23200 | tot 23872 (95.5KB -> 1)
#define L_TOT_SG 19776
#define L_TOT_RC 23872

#define ELT44(...) _Pragma("unroll") for (int p = 0; p < 4; p++){ _Pragma("unroll") for (int jj = 0; jj < 4; jj++){ __VA_ARGS__; } }

__device__ __forceinline__ int offq(int row, int p0){
    return row*32 + ((p0 + 4*(row&7)) & 31);
}
__device__ __forceinline__ int offs(int row, int p){
    return row*32 + (((p & 28) + 4*(row&7)) & 31) + (p & 3);
}

// fast tanh: 1 - 2/(e^{2x}+1), clamp to +-9 (tanh(9)=1-2.7e-8), ~6 VALU vs ~25 libm
__device__ __forceinline__ float ftanh(float x){
    float cx = fminf(9.f, fmaxf(-9.f, x));
    float e  = __expf(2.f*cx);
    return fmaf(-2.f, __builtin_amdgcn_rcpf(e + 1.f), 1.f);
}

// stage `units` 16B-units from global g into contiguous LDS wc
__device__ __forceinline__ void stageW(const float* __restrict__ g, float* wc, int units){
#if defined(__has_builtin) && __has_builtin(__builtin_amdgcn_global_load_lds)
    int lane = threadIdx.x & 63, wid = threadIdx.x >> 6;
    for (int base = wid*64; base < units; base += 256){
        int u = base + lane;
        if (u < units)
            __builtin_amdgcn_global_load_lds(
                (const __attribute__((address_space(1))) unsigned int*)(g) + (size_t)u*4,
                (__attribute__((address_space(3))) unsigned int*)(wc) + (size_t)base*4,
                16, 0, 0);
    }
#else
    int t = threadIdx.x;
    for (int u = t; u < units; u += 256){
        float4 v = *(const float4*)(g + u*4);
        *(float4*)(wc + u*4) = v;
    }
#endif
}

#define FMA16(acc, s4, w4) \
  acc[0][0]=fmaf(s4.x,w4.x,acc[0][0]); acc[0][1]=fmaf(s4.x,w4.y,acc[0][1]); \
  acc[0][2]=fmaf(s4.x,w4.z,acc[0][2]); acc[0][3]=fmaf(s4.x,w4.w,acc[0][3]); \
  acc[1][0]=fmaf(s4.y,w4.x,acc[1][0]); acc[1][1]=fmaf(s4.y,w4.y,acc[1][1]); \
  acc[1][2]=fmaf(s4.y,w4.z,acc[1][2]); acc[1][3]=fmaf(s4.y,w4.w,acc[1][3]); \
  acc[2][0]=fmaf(s4.z,w4.x,acc[2][0]); acc[2][1]=fmaf(s4.z,w4.y,acc[2][1]); \
  acc[2][2]=fmaf(s4.z,w4.z,acc[2][2]); acc[2][3]=fmaf(s4.z,w4.w,acc[2][3]); \
  acc[3][0]=fmaf(s4.w,w4.x,acc[3][0]); acc[3][1]=fmaf(s4.w,w4.y,acc[3][1]); \
  acc[3][2]=fmaf(s4.w,w4.z,acc[3][2]); acc[3][3]=fmaf(s4.w,w4.w,acc[3][3]);

// ---- direct-global (barrier-free) small-K passes; U matrices are L1/L2-hot ----
__device__ __forceinline__ void mmU_d(const float* __restrict__ gU, int K,
    const float* __restrict__ vec, float acc[4][4], int jg, int p0)
{
    const float* up = gU + 4*jg;
    #pragma unroll 4
    for (int k = 0; k < K; k++){
        float4 w4 = *(const float4*)(up + k*UNITS);
        float4 s4 = *(const float4*)(vec + offq(k, p0));
        FMA16(acc, s4, w4)
    }
}
__device__ __forceinline__ void mmU3_d(const float* __restrict__ gU, int K,
    const float* __restrict__ vec, float a0[4][4], float a1[4][4], float a2[4][4],
    int jg, int p0)
{
    const float* up = gU + 4*jg;
    #pragma unroll 2
    for (int k = 0; k < K; k++){
        const float* r = up + k*384;
        float4 s4 = *(const float4*)(vec + offq(k, p0));
        float4 w0 = *(const float4*)(r);
        float4 w1v = *(const float4*)(r + 128);
        float4 w2 = *(const float4*)(r + 256);
        FMA16(a0, s4, w0) FMA16(a1, s4, w1v) FMA16(a2, s4, w2)
    }
}

// acc[p][jj] += sum_k vec[k][p0+p] * W[k][4jg+jj]; staged LDS double-buffer (K=128)
__device__ __forceinline__ void mm_acc(const float* __restrict__ gW, int K,
    const float* __restrict__ vec, float acc[4][4], float* __restrict__ Wc,
    int jg, int p0)
{
    int nch = (K + KCH - 1) / KCH;
    {
        int r0 = (K < KCH) ? K : KCH;
        stageW(gW, Wc, r0*32);
    }
    for (int c = 0; c < nch; c++){
        __syncthreads();
        if (c + 1 < nch){
            int c0n = (c+1)*KCH;
            int rn = K - c0n; if (rn > KCH) rn = KCH;
            stageW(gW + c0n*UNITS, Wc + ((c+1)&1)*KCH*UNITS, rn*32);
        }
        int c0 = c*KCH;
        int rows = K - c0; if (rows > KCH) rows = KCH;
        const float* wb = Wc + (c&1)*KCH*UNITS;
        if (rows == KCH){
            #pragma unroll 4
            for (int kk = 0; kk < KCH; kk++){
                int k = c0 + kk;
                float4 w4 = *(const float4*)(wb + kk*UNITS + 4*jg);
                float4 s4 = *(const float4*)(vec + offq(k, p0));
                FMA16(acc, s4, w4)
            }
        } else {
            for (int kk = 0; kk < rows; kk++){
                int k = c0 + kk;
                float4 w4 = *(const float4*)(wb + kk*UNITS + 4*jg);
                float4 s4 = *(const float4*)(vec + offq(k, p0));
                FMA16(acc, s4, w4)
            }
        }
    }
    __syncthreads();
}

// fused z,g,r: W packed rows of 384 ([z|g|r]); staged (K=128)
__device__ __forceinline__ void mm3_acc(const float* __restrict__ gW, int K,
    const float* __restrict__ vec, float az[4][4], float ag[4][4], float ar[4][4],
    float* __restrict__ Wc, int jg, int p0)
{
    int nch = (K + KC3 - 1) / KC3;
    {
        int r0 = (K < KC3) ? K : KC3;
        stageW(gW, Wc, r0*96);
    }
    for (int c = 0; c < nch; c++){
        __syncthreads();
        if (c + 1 < nch){
            int c0n = (c+1)*KC3;
            int rn = K - c0n; if (rn > KC3) rn = KC3;
            stageW(gW + c0n*384, Wc + ((c+1)&1)*(KC3*384), rn*96);
        }
        int c0 = c*KC3;
        int rows = K - c0; if (rows > KC3) rows = KC3;
        const float* wb = Wc + (c&1)*(KC3*384);
        if (rows == KC3){
            #pragma unroll 2
            for (int kk = 0; kk < KC3; kk++){
                int k = c0 + kk;
                const float* wrow = wb + kk*384 + 4*jg;
                float4 s4  = *(const float4*)(vec + offq(k, p0));
                float4 wz4 = *(const float4*)(wrow);
                float4 wg4 = *(const float4*)(wrow + 128);
                float4 wr4 = *(const float4*)(wrow + 256);
                FMA16(az, s4, wz4)
                FMA16(ag, s4, wg4)
                FMA16(ar, s4, wr4)
            }
        } else {
            for (int kk = 0; kk < rows; kk++){
                int k = c0 + kk;
                const float* wrow = wb + kk*384 + 4*jg;
                float4 s4  = *(const float4*)(vec + offq(k, p0));
                float4 wz4 = *(const float4*)(wrow);
                float4 wg4 = *(const float4*)(wrow + 128);
                float4 wr4 = *(const float4*)(wrow + 256);
                FMA16(az, s4, wz4)
                FMA16(ag, s4, wg4)
                FMA16(ar, s4, wr4)
            }
        }
    }
    __syncthreads();
}

__device__ __forceinline__ void write_own(float* buf, const float v[4][4], int j0, int p0){
    #pragma unroll
    for (int jj = 0; jj < 4; jj++){
        int j = j0 + jj;
        float4 q = make_float4(v[0][jj], v[1][jj], v[2][jj], v[3][jj]);
        *(float4*)(buf + offq(j, p0)) = q;
    }
}
__device__ __forceinline__ void read_own(const float* buf, float v[4][4], int j0, int p0){
    #pragma unroll
    for (int jj = 0; jj < 4; jj++){
        int j = j0 + jj;
        float4 q = *(const float4*)(buf + offq(j, p0));
        v[0][jj]=q.x; v[1][jj]=q.y; v[2][jj]=q.z; v[3][jj]=q.w;
    }
}
// per-thread-linear global stash (coalesced; only same thread reads back)
__device__ __forceinline__ void stash_w(float* buf, const float v[4][4], int t){
    #pragma unroll
    for (int jj = 0; jj < 4; jj++)
        *(float4*)(buf + (jj*256 + t)*4) = make_float4(v[0][jj], v[1][jj], v[2][jj], v[3][jj]);
}
__device__ __forceinline__ void stash_r(const float* buf, float v[4][4], int t){
    #pragma unroll
    for (int jj = 0; jj < 4; jj++){
        float4 q = *(const float4*)(buf + (jj*256 + t)*4);
        v[0][jj]=q.x; v[1][jj]=q.y; v[2][jj]=q.z; v[3][jj]=q.w;
    }
}

// out = tanh(bias + x@U + vec@W)   (h gate); U direct-global, W staged
__device__ __forceinline__ void gate_f(const float* __restrict__ U, const float* __restrict__ W,
    const float* __restrict__ bias, const float* __restrict__ xT, const float* __restrict__ Sin,
    float* __restrict__ Wc, float out[4][4], int jg, int p0, int j0)
{
    float acc[4][4];
    float4 b = *(const float4*)(bias + j0);
    #pragma unroll
    for (int p = 0; p < 4; p++){ acc[p][0]=b.x; acc[p][1]=b.y; acc[p][2]=b.z; acc[p][3]=b.w; }
    mmU_d(U, DD, xT, acc, jg, p0);
    mm_acc(W, UNITS, Sin, acc, Wc, jg, p0);
    #pragma unroll
    for (int p = 0; p < 4; p++)
        #pragma unroll
        for (int jj = 0; jj < 4; jj++) out[p][jj] = ftanh(acc[p][jj]);
}

// fused z,g,r gates; U-pass direct-global, W-pass staged
__device__ __forceinline__ void gate3_f(const float* __restrict__ Uzgr, const float* __restrict__ Wzgr,
    const float* __restrict__ bz, const float* __restrict__ bg, const float* __restrict__ br,
    const float* __restrict__ xT, const float* __restrict__ Sin,
    float* __restrict__ Wc, float zt[4][4], float gt[4][4], float rt[4][4],
    int jg, int p0, int j0)
{
    float4 b0 = *(const float4*)(bz + j0);
    float4 b1 = *(const float4*)(bg + j0);
    float4 b2 = *(const float4*)(br + j0);
    #pragma unroll
    for (int p = 0; p < 4; p++){
        zt[p][0]=b0.x; zt[p][1]=b0.y; zt[p][2]=b0.z; zt[p][3]=b0.w;
        gt[p][0]=b1.x; gt[p][1]=b1.y; gt[p][2]=b1.z; gt[p][3]=b1.w;
        rt[p][0]=b2.x; rt[p][1]=b2.y; rt[p][2]=b2.z; rt[p][3]=b2.w;
    }
    mmU3_d(Uzgr, DD, xT, zt, gt, rt, jg, p0);
    mm3_acc(Wzgr, UNITS, Sin, zt, gt, rt, Wc, jg, p0);
    ELT44(zt[p][jj]=ftanh(zt[p][jj]); gt[p][jj]=ftanh(gt[p][jj]); rt[p][jj]=ftanh(rt[p][jj]))
}

// closed-form Cholesky of DELTA*((1-RHO)I + RHO*J): equicorrelated structure.
__global__ void chol_kernel(float* __restrict__ Lout)
{
    if (threadIdx.x == 0 && blockIdx.x == 0) {
        const double beta = 0.01 * 0.5;          // off-diagonal
        const double diag = 0.01;                // alpha + beta
        double c[DIMN], d[DIMN];
        double S = 0.0;
        for (int j = 0; j < DIMN; j++){
            double dj = sqrt(diag - S);
            double cj = (beta - S) / dj;
            d[j] = dj; c[j] = cj;
            S += cj*cj;
        }
        for (int i = 0; i < DIMN; i++)
            for (int j = 0; j < DIMN; j++)
                Lout[i*DIMN + j] = (j < i) ? (float)c[j] : (j == i) ? (float)d[i] : 0.0f;
    }
}

__global__ void transpose_k(const float* __restrict__ wz, const float* __restrict__ wg,
                            const float* __restrict__ wr, const float* __restrict__ wh,
                            float* __restrict__ WT)
{
    int idx = blockIdx.x*256 + threadIdx.x;           // 0..65535
    int q = idx >> 14, r2 = idx & 16383, k = r2 >> 7, j = r2 & 127;
    const float* src = (q==0)? wz : (q==1)? wg : (q==2)? wr : wh;
    WT[(q<<14) + j*UNITS + k] = src[k*UNITS + j];
}

// pack [Uz|Ug|Ur] 21x384 and [Wz|Wg|Wr] 128x384
__global__ void pack_zgr(const float* __restrict__ uz, const float* __restrict__ ug,
                         const float* __restrict__ ur,
                         const float* __restrict__ wz, const float* __restrict__ wg,
                         const float* __restrict__ wr,
                         float* __restrict__ Uzgr, float* __restrict__ Wzgr)
{
    int idx = blockIdx.x*256 + threadIdx.x;
    if (idx < 128*384){
        int k = idx/384, c = idx - k*384, g = c >> 7, j = c & 127;
        const float* s = (g==0)? wz : (g==1)? wg : wr;
        Wzgr[idx] = s[k*UNITS + j];
        return;
    }
    int i2 = idx - 128*384;
    if (i2 < 21*384){
        int k = i2/384, c = i2 - k*384, g = c >> 7, j = c & 127;
        const float* s = (g==0)? uz : (g==1)? ug : ur;
        Uzgr[i2] = s[k*UNITS + j];
    }
}

#define DGM_PARAMS \
    const float* __restrict__ inputs, const float* __restrict__ eps, \
    const float* __restrict__ w1, const float* __restrict__ b1, \
    const float* __restrict__ uz, const float* __restrict__ bz, \
    const float* __restrict__ ug, const float* __restrict__ bg, \
    const float* __restrict__ ur, const float* __restrict__ br, \
    const float* __restrict__ uh, const float* __restrict__ wh, const float* __restrict__ bh, \
    const float* __restrict__ wv, const float* __restrict__ bv, \
    const float* __restrict__ Lm, const float* __restrict__ WT, \
    const float* __restrict__ Uzgr, const float* __restrict__ Wzgr, \
    float* __restrict__ gws, \
    float* __restrict__ fp1, float* __restrict__ val1, float* __restrict__ val2, \
    float* __restrict__ t12acc

#define DGM_ARGS inputs, eps, w1, b1, uz, bz, ug, bg, ur, br, uh, wh, bh, wv, bv, \
    Lm, WT, Uzgr, Wzgr, gws, fp1, val1, val2, t12acc

template<int SG>
__device__ __forceinline__ void dgm_body(float* lds, DGM_PARAMS)
{
    float* S0 = lds;
    float* S1 = SG ? lds : lds + 4096;                // RC only
    float* S2 = lds + (SG ? 4096 : 8192);
    float* Db = lds + (SG ? 8192 : 12288);
    float* Wc = lds + (SG ? 12288 : 16384);
    float* xT = lds + (SG ? 18432 : 22528);
    float* Vb = lds + (SG ? 19104 : 23200);

    const int t  = threadIdx.x;
    const int jg = t & 31;
    const int pg = t >> 5;
    const int p0 = pg * 4;
    const int j0 = jg * 4;
    const int P0 = blockIdx.x * TM;
    const int type = (P0 < NN) ? 0 : (P0 < NN + MCN*NN) ? 1 : 2;
    int base_n = 0, mrow = 0;
    if (type == 1){ int q = P0 - NN; mrow = q >> 11; base_n = q & (NN-1); }

    float* gb = gws + (size_t)blockIdx.x * GB_STRIDE;

    // ---- build x tile (and violation V for type 1) ----
    {
        int p = t & 31, kq = t >> 5;
        for (int ki = 0; ki < 3; ki++){
            int k = kq + 8*ki;
            if (k > DIMN) break;
            float xv;
            if (type == 0){
                xv = inputs[(P0 + p)*DD + k];
            } else if (type == 2){
                xv = inputs[(NN + (P0 - NN - MCN*NN) + p)*DD + k];
            } else {
                int n = base_n + p;
                float x1v = inputs[n*DD + k];
                if (k == DIMN) xv = x1v;
                else {
                    const float* ep = eps + (size_t)(mrow*NN + n)*DIMN;
                    float a = x1v;
                    for (int d = 0; d < DIMN; d++) a = fmaf(ep[d], Lm[k*DIMN + d], a);
                    float viol = a * (SIGC * x1v);
                    Vb[offs(k, p)] = viol;
                    xv = x1v + viol;
                }
            }
            xT[offs(k, p)] = xv;
        }
    }
    __syncthreads();

    // ---- forward ----
    float s_own[4][4];
    {
        float acc[4][4];
        float4 b = *(const float4*)(b1 + j0);
        #pragma unroll
        for (int p = 0; p < 4; p++){ acc[p][0]=b.x; acc[p][1]=b.y; acc[p][2]=b.z; acc[p][3]=b.w; }
        mmU_d(w1, DD, xT, acc, jg, p0);
        ELT44(s_own[p][jj] = ftanh(acc[p][jj]))
        write_own(S0, s_own, j0, p0);
        __syncthreads();
    }

    float zt[4][4], gt[4][4], rt[4][4], ht[4][4];

#define GATES(SIN, SMUL) \
    gate3_f(Uzgr, Wzgr, bz, bg, br, xT, SIN, Wc, zt, gt, rt, jg, p0, j0); \
    { float tt[4][4]; ELT44(tt[p][jj] = SMUL[p][jj]*rt[p][jj]) write_own(Db, tt, j0, p0); } \
    gate_f(uh, wh, bh, xT, Db, Wc, ht, jg, p0, j0);

#define FWD_LAYER(SIN) \
    GATES(SIN, s_own) \
    ELT44(s_own[p][jj] = (1.f - gt[p][jj])*ht[p][jj] + zt[p][jj]*s_own[p][jj])

    FWD_LAYER(S0)                      // layer 1
    if (SG){ if (type != 2){
        stash_w(gb + ST_S1, s_own, t);
        stash_w(gb + ST_Z1, zt, t); stash_w(gb + ST_G1, gt, t); stash_w(gb + ST_R1, rt, t);
    } }
    else   { write_own(S1, s_own, j0, p0); }
    write_own(Db, s_own, j0, p0);      // Sin for layer 2 (safe: wh-pass sync'd)

    FWD_LAYER(Db)                      // layer 2
    if (SG && type != 2){
        stash_w(gb + ST_Z2, zt, t); stash_w(gb + ST_G2, gt, t); stash_w(gb + ST_R2, rt, t);
    }
    write_own(S2, s_own, j0, p0);      // s2 kept in LDS for backward

    FWD_LAYER(S2)                      // layer 3 -- zt/gt/rt/ht stay live into backward

    // ---- value head ----
    {
        float4 wv4 = *(const float4*)(wv + j0);
        float vs[4];
        #pragma unroll
        for (int p = 0; p < 4; p++)
            vs[p] = s_own[p][0]*wv4.x + s_own[p][1]*wv4.y + s_own[p][2]*wv4.z + s_own[p][3]*wv4.w;
        __syncthreads();
        *(float4*)(Db + jg*32 + p0) = make_float4(vs[0], vs[1], vs[2], vs[3]);
        __syncthreads();
        if (t < TM){
            float v = bv[0];
            for (int j2 = 0; j2 < 32; j2++) v += Db[j2*32 + t];
            if (type == 0) val1[P0 + t] = v;
            else if (type == 2) val2[P0 + t - NN - MCN*NN] = v;
        }
        __syncthreads();
    }
    if (type == 2) return;

    // ---- backward ----
    float ds[4][4];
    {
        float4 wv4 = *(const float4*)(wv + j0);
        #pragma unroll
        for (int p = 0; p < 4; p++){ ds[p][0]=wv4.x; ds[p][1]=wv4.y; ds[p][2]=wv4.z; ds[p][3]=wv4.w; }
    }
    float proj[4] = {0.f, 0.f, 0.f, 0.f};
    float dxp[3] = {0.f, 0.f, 0.f};
    const int pi = t >> 3, il = t & 7;

    const float* WTz = WT;
    const float* WTg = WT + 16384;
    const float* WTr = WT + 2*16384;
    const float* WTh = WT + 3*16384;

#define DX_DOT(UMAT) \
    { _Pragma("unroll") for (int ii = 0; ii < 3; ii++){ \
        int i = il + 8*ii; \
        if (i < DD){ \
            const float* Urow = UMAT + i*UNITS; \
            float a = 0.f; \
            for (int j2 = 0; j2 < UNITS; j2++) a = fmaf(Db[offs(j2, pi)], Urow[j2], a); \
            dxp[ii] += a; \
        } } }

// K=20 direct-global U pass; reads only own Vb/SEL; no barriers
#define PROJ_D(UMAT, SEL) \
    { float uv[4][4]; \
      ELT44(uv[p][jj] = 0.f) \
      mmU_d(UMAT, DIMN, Vb, uv, jg, p0); \
      ELT44(proj[p] += uv[p][jj]*SEL[p][jj]) }

// Backward layer as 4 sequential delta passes (z -> g,h -> r)
// MODE 0: sl=S2(LDS), gates live in regs (layer 3)
// MODE 1: recompute gates from SLP (RC fallback)
// MODE 2: sl=stash S1, z/g/r stash, h=(S2_lds - z*sl)/(1-g)   (SG layer 2)
// MODE 3: sl=SLP(LDS), z/g/r stash, h=(stash S1 - z*sl)/(1-g) (SG layer 1)
#define BWD_LAYER(SLP, MODE, GZ, GG, GR) \
    { \
    float dsn[4][4]; \
    if (MODE == 1){ \
        float slg[4][4]; read_own(SLP, slg, j0, p0); \
        GATES(SLP, slg) \
    } \
    { /* pass z */ \
        float sl[4][4], zv[4][4]; \
        if (MODE == 2){ stash_r(gb + ST_S1, sl, t); stash_r(gb + GZ, zv, t); } \
        else if (MODE == 3){ read_own(SLP, sl, j0, p0); stash_r(gb + GZ, zv, t); } \
        else if (MODE == 0){ read_own(S2, sl, j0, p0); ELT44(zv[p][jj] = zt[p][jj]) } \
        else { read_own(SLP, sl, j0, p0); ELT44(zv[p][jj] = zt[p][jj]) } \
        float dzp[4][4]; \
        ELT44(float d=ds[p][jj]; float zz=zv[p][jj]; \
            dzp[p][jj] = d*sl[p][jj]*(1.f - zz*zz); dsn[p][jj] = d*zz) \
        write_own(Db, dzp, j0, p0); \
        if (type == 1){ PROJ_D(uz, dzp) } else { __syncthreads(); DX_DOT(uz) } \
    } \
    mm_acc(WTz, UNITS, Db, dsn, Wc, jg, p0); \
    float dhp[4][4]; \
    { /* pass g,h */ \
        float gv[4][4], hv[4][4]; \
        if (MODE == 2 || MODE == 3){ \
            float zv[4][4], sl[4][4], sn[4][4]; \
            stash_r(gb + GZ, zv, t); stash_r(gb + GG, gv, t); \
            if (MODE == 2){ stash_r(gb + ST_S1, sl, t); read_own(S2, sn, j0, p0); } \
            else { read_own(SLP, sl, j0, p0); stash_r(gb + ST_S1, sn, t); } \
            ELT44(hv[p][jj] = (sn[p][jj] - zv[p][jj]*sl[p][jj]) / (1.f - gv[p][jj])) \
        } else { ELT44(gv[p][jj] = gt[p][jj]; hv[p][jj] = ht[p][jj]) } \
        float dgp[4][4]; \
        ELT44(float d=ds[p][jj]; float gg=gv[p][jj]; float hh=hv[p][jj]; \
            dgp[p][jj] = -d*hh*(1.f - gg*gg); \
            dhp[p][jj] = d*(1.f - gg)*(1.f - hh*hh)) \
        write_own(Db, dgp, j0, p0); \
        if (type == 1){ PROJ_D(ug, dgp) } else { __syncthreads(); DX_DOT(ug) } \
    } \
    mm_acc(WTg, UNITS, Db, dsn, Wc, jg, p0); \
    write_own(Db, dhp, j0, p0); \
    if (type == 1){ PROJ_D(uh, dhp) } else { __syncthreads(); DX_DOT(uh) } \
    float dsr[4][4]; \
    ELT44(dsr[p][jj] = 0.f) \
    mm_acc(WTh, UNITS, Db, dsr, Wc, jg, p0); \
    { /* pass r */ \
        float rv[4][4], sl[4][4], drp[4][4]; \
        if (MODE == 2){ stash_r(gb + GR, rv, t); stash_r(gb + ST_S1, sl, t); } \
        else if (MODE == 3){ stash_r(gb + GR, rv, t); read_own(SLP, sl, j0, p0); } \
        else if (MODE == 0){ ELT44(rv[p][jj] = rt[p][jj]) read_own(S2, sl, j0, p0); } \
        else { ELT44(rv[p][jj] = rt[p][jj]) read_own(SLP, sl, j0, p0); } \
        ELT44(float dr=dsr[p][jj]; float rr=rv[p][jj]; \
            drp[p][jj] = dr*sl[p][jj]*(1.f - rr*rr); dsn[p][jj] += dr*rr) \
        write_own(Db, drp, j0, p0); \
        if (type == 1){ PROJ_D(ur, drp) } else { __syncthreads(); DX_DOT(ur) } \
    } \
    mm_acc(WTr, UNITS, Db, dsn, Wc, jg, p0); \
    ELT44(ds[p][jj] = dsn[p][jj]) \
    }

    BWD_LAYER(S0, 0, ST_Z2, ST_G2, ST_R2)                  // layer 3: gates live
    BWD_LAYER(S1, (SG ? 2 : 1), ST_Z2, ST_G2, ST_R2)       // layer 2
    if (SG){ BWD_LAYER(S0, 3, ST_Z1, ST_G1, ST_R1) }       // layer 1 (stash)
    else   { BWD_LAYER(S0, 1, ST_Z1, ST_G1, ST_R1) }       // layer 1 (recompute)

    // first-layer backward + epilogue
    {
        float s0l[4][4];
        read_own(S0, s0l, j0, p0);
        float v0[4][4];
        ELT44(v0[p][jj] = ds[p][jj]*(1.f - s0l[p][jj]*s0l[p][jj]))

        if (type == 1){
            PROJ_D(w1, v0)
            __syncthreads();
            *(float4*)(Db + jg*32 + p0) = make_float4(proj[0], proj[1], proj[2], proj[3]);
            __syncthreads();
            if (t < TM){
                float s = 0.f;
                for (int j2 = 0; j2 < 32; j2++) s += Db[j2*32 + t];
                atomicAdd(t12acc + base_n + t, s);
            }
        } else {
            write_own(Db, v0, j0, p0);
            __syncthreads();
            DX_DOT(w1)
            #pragma unroll
            for (int ii = 0; ii < 3; ii++){
                int i = il + 8*ii;
                if (i < DD) fp1[(P0 + pi)*DD + i] = dxp[ii];
            }
        }
    }
}

__global__ __launch_bounds__(256) __attribute__((amdgpu_waves_per_eu(2,2))) void dgm_sg(DGM_PARAMS){
    __shared__ float lds[L_TOT_SG];
    dgm_body<1>(lds, DGM_ARGS);
}
__global__ __launch_bounds__(256) __attribute__((amdgpu_waves_per_eu(2,2))) void dgm_rc(DGM_PARAMS){
    __shared__ float lds[L_TOT_RC];
    dgm_body<0>(lds, DGM_ARGS);
}

__global__ void finalize_k(const float* __restrict__ inputs, const float* __restrict__ eps,
    const float* __restrict__ Lm, const float* __restrict__ fp1, const float* __restrict__ val1,
    const float* __restrict__ val2, const float* __restrict__ t12acc, float* __restrict__ out)
{
    int n = blockIdx.x*256 + threadIdx.x;
    if (n >= NN) return;
    float fp[DD];
    #pragma unroll
    for (int k = 0; k < DD; k++) fp[k] = fp1[n*DD + k];
    float t11 = fp[DIMN];
    #pragma unroll
    for (int k = 0; k < DIMN; k++) t11 = fmaf(MUC*inputs[n*DD + k], fp[k], t11);
    float esum[DIMN];
    #pragma unroll
    for (int d = 0; d < DIMN; d++){
        float a = 0.f;
        for (int m = 0; m < MCN; m++) a += eps[(size_t)(m*NN + n)*DIMN + d];
        esum[d] = a;
    }
    float t12b = 0.f;
    #pragma unroll
    for (int k = 0; k < DIMN; k++){
        float loc = inputs[n*DD + k];
        float ssum = (float)MCN * loc;
        #pragma unroll
        for (int d = 0; d < DIMN; d++) ssum = fmaf(esum[d], Lm[k*DIMN + d], ssum);
        float vsum = ssum * (SIGC*loc);
        t12b = fmaf(fp[k], vsum, t12b);
    }
    float term12 = (t12acc[n] - t12b) * (1.0f/(DELTAC*(float)MCN));
    out[n] = t11 + 0.5f*term12 - RC*val1[n];

    float prod = 1.f;
    #pragma unroll
    for (int k = 0; k < DIMN; k++) prod *= inputs[(NN + n)*DD + k];
    float payoff = powf(prod, 1.0f/(float)DIMN);
    if (!(payoff > 0.f)) payoff = 0.f;
    out[NN + n] = val2[n] - payoff;
}

extern "C" void kernel_launch(void* const* d_in, const int* in_sizes, int n_in,
                              void* d_out, int out_size, void* d_ws, size_t ws_size,
                              hipStream_t stream)
{
    const float* inputs = (const float*)d_in[0];
    const float* eps    = (const float*)d_in[1];
    const float* w1     = (const float*)d_in[2];
    const float* b1     = (const float*)d_in[3];
    const float* uz     = (const float*)d_in[4];
    const float* wz     = (const float*)d_in[5];
    const float* bz     = (const float*)d_in[6];
    const float* ug     = (const float*)d_in[7];
    const float* wg     = (const float*)d_in[8];
    const float* bg     = (const float*)d_in[9];
    const float* urr    = (const float*)d_in[10];
    const float* wr     = (const float*)d_in[11];
    const float* br     = (const float*)d_in[12];
    const float* uh     = (const float*)d_in[13];
    const float* wh     = (const float*)d_in[14];
    const float* bh     = (const float*)d_in[15];
    const float* wv     = (const float*)d_in[16];
    const float* bv     = (const float*)d_in[17];

    float* ws    = (float*)d_ws;
    float* Lm    = ws + OFF_L;
    float* WT    = ws + OFF_WT;
    float* Uzgr  = ws + OFF_UZGR;
    float* Wzgr  = ws + OFF_WZGR;
    float* fp1   = ws + OFF_FP1;
    float* val1  = ws + OFF_VAL1;
    float* val2  = ws + OFF_VAL2;
    float* t12   = ws + OFF_T12;
    float* gates = ws + OFF_GATES;
    float* out   = (float*)d_out;

    hipMemsetAsync(t12, 0, NN*sizeof(float), stream);
    hipLaunchKernelGGL(chol_kernel, dim3(1), dim3(64), 0, stream, Lm);
    hipLaunchKernelGGL(transpose_k, dim3(256), dim3(256), 0, stream, wz, wg, wr, wh, WT);
    hipLaunchKernelGGL(pack_zgr, dim3(224), dim3(256), 0, stream, uz, ug, urr, wz, wg, wr, Uzgr, Wzgr);

    size_t need_bytes = ((size_t)OFF_GATES + (size_t)NBLK * (size_t)GB_STRIDE) * sizeof(float);
    if (ws_size >= need_bytes){
        hipLaunchKernelGGL(dgm_sg, dim3(NBLK), dim3(256), 0, stream,
            inputs, eps, w1, b1, uz, bz, ug, bg, urr, br, uh, wh, bh, wv, bv,
            Lm, WT, Uzgr, Wzgr, gates, fp1, val1, val2, t12);
    } else {
        hipLaunchKernelGGL(dgm_rc, dim3(NBLK), dim3(256), 0, stream,
            inputs, eps, w1, b1, uz, bz, ug, bg, urr, br, uh, wh, bh, wv, bv,
            Lm, WT, Uzgr, Wzgr, gates, fp1, val1, val2, t12);
    }
    hipLaunchKernelGGL(finalize_k, dim3(8), dim3(256), 0, stream,
        inputs, eps, Lm, fp1, val1, val2, t12, out);
}

// Round 11
// 1301.454 us; speedup vs baseline: 5.4047x; 1.0034x over previous
//
#include <hip/hip_runtime.h>
#include <math.h>

#define DIMN 20
#define DD 21
#define NN 2048
#define MCN 32
#define UNITS 128
#define SIGC 0.2f
#define MUC 0.05f
#define RC 0.05f
#define DELTAC 0.01f

#define TM 32
#define PTOT (NN + MCN*NN + NN)
#define NBLK (PTOT/TM)

// ws layout (floats)
#define OFF_L 0
#define OFF_WT 512
#define OFF_UZGR (OFF_WT + 4*16384)      // 66048 : packed [Uz|Ug|Ur] 21x384 (pad to 8192)
#define OFF_WZGR (OFF_UZGR + 8192)       // 74240 : packed [Wz|Wg|Wr] 128x384
#define OFF_FP1  (OFF_WZGR + 49152)      // 123392
#define OFF_VAL1 (OFF_FP1 + NN*DD)       // 166400
#define OFF_VAL2 (OFF_VAL1 + NN)         // 168448
#define OFF_T12  (OFF_VAL2 + NN)         // 170496
#define OFF_GATES (OFF_T12 + NN)         // 172544 : per-block stash

// per-block stash (floats), per-thread-linear layout; h recovered, not stashed
#define ST_S1 0
#define ST_Z1 4096
#define ST_G1 8192
#define ST_R1 12288
#define ST_Z2 16384
#define ST_G2 20480
#define ST_R2 24576
#define GB_STRIDE 28672     // total stash = (172544 + 2176*28672)*4 B = 250.3 MB

// LDS layouts (floats) -- no weight staging buffer anymore
// SG: S0 0 | S2 4096 | Db 8192 | xT 12288 | Vb 12960 | tot 13632 (54.5KB -> 2 blk/CU)
// RC: S0 0 | S1 4096 | S2 8192 | Db 12288 | xT 16384 | Vb 17056 | tot 17728 (70.9KB -> 2)
#define L_TOT_SG 13632
#define L_TOT_RC 17728

#define ELT44(...) _Pragma("unroll") for (int p = 0; p < 4; p++){ _Pragma("unroll") for (int jj = 0; jj < 4; jj++){ __VA_ARGS__; } }

__device__ __forceinline__ int offq(int row, int p0){
    return row*32 + ((p0 + 4*(row&7)) & 31);
}
__device__ __forceinline__ int offs(int row, int p){
    return row*32 + (((p & 28) + 4*(row&7)) & 31) + (p & 3);
}

// fast tanh: 1 - 2/(e^{2x}+1), clamp to +-9, ~6 VALU vs ~25 libm
__device__ __forceinline__ float ftanh(float x){
    float cx = fminf(9.f, fmaxf(-9.f, x));
    float e  = __expf(2.f*cx);
    return fmaf(-2.f, __builtin_amdgcn_rcpf(e + 1.f), 1.f);
}

#define FMA16(acc, s4, w4) \
  acc[0][0]=fmaf(s4.x,w4.x,acc[0][0]); acc[0][1]=fmaf(s4.x,w4.y,acc[0][1]); \
  acc[0][2]=fmaf(s4.x,w4.z,acc[0][2]); acc[0][3]=fmaf(s4.x,w4.w,acc[0][3]); \
  acc[1][0]=fmaf(s4.y,w4.x,acc[1][0]); acc[1][1]=fmaf(s4.y,w4.y,acc[1][1]); \
  acc[1][2]=fmaf(s4.y,w4.z,acc[1][2]); acc[1][3]=fmaf(s4.y,w4.w,acc[1][3]); \
  acc[2][0]=fmaf(s4.z,w4.x,acc[2][0]); acc[2][1]=fmaf(s4.z,w4.y,acc[2][1]); \
  acc[2][2]=fmaf(s4.z,w4.z,acc[2][2]); acc[2][3]=fmaf(s4.z,w4.w,acc[2][3]); \
  acc[3][0]=fmaf(s4.w,w4.x,acc[3][0]); acc[3][1]=fmaf(s4.w,w4.y,acc[3][1]); \
  acc[3][2]=fmaf(s4.w,w4.z,acc[3][2]); acc[3][3]=fmaf(s4.w,w4.w,acc[3][3]);

// direct-global matmul over 128-wide W rows; weights are L2-hot; NO barriers.
// lean unroll-4 keeps load transients ~32 regs (R2's failure was deep lookahead).
__device__ __forceinline__ void mm_d(const float* __restrict__ gW, int K,
    const float* __restrict__ vec, float acc[4][4], int jg, int p0)
{
    const float* wp = gW + 4*jg;
    #pragma unroll 4
    for (int k = 0; k < K; k++){
        float4 w4 = *(const float4*)(wp + k*UNITS);
        float4 s4 = *(const float4*)(vec + offq(k, p0));
        FMA16(acc, s4, w4)
    }
}
// 384-packed rows ([z|g|r]); one s4 feeds 48 FMAs; NO barriers.
__device__ __forceinline__ void mm3_d(const float* __restrict__ gW, int K,
    const float* __restrict__ vec, float a0[4][4], float a1[4][4], float a2[4][4],
    int jg, int p0)
{
    const float* wp = gW + 4*jg;
    #pragma unroll 2
    for (int k = 0; k < K; k++){
        const float* r = wp + k*384;
        float4 s4 = *(const float4*)(vec + offq(k, p0));
        float4 w0 = *(const float4*)(r);
        float4 w1v = *(const float4*)(r + 128);
        float4 w2 = *(const float4*)(r + 256);
        FMA16(a0, s4, w0) FMA16(a1, s4, w1v) FMA16(a2, s4, w2)
    }
}

__device__ __forceinline__ void write_own(float* buf, const float v[4][4], int j0, int p0){
    #pragma unroll
    for (int jj = 0; jj < 4; jj++){
        int j = j0 + jj;
        float4 q = make_float4(v[0][jj], v[1][jj], v[2][jj], v[3][jj]);
        *(float4*)(buf + offq(j, p0)) = q;
    }
}
__device__ __forceinline__ void read_own(const float* buf, float v[4][4], int j0, int p0){
    #pragma unroll
    for (int jj = 0; jj < 4; jj++){
        int j = j0 + jj;
        float4 q = *(const float4*)(buf + offq(j, p0));
        v[0][jj]=q.x; v[1][jj]=q.y; v[2][jj]=q.z; v[3][jj]=q.w;
    }
}
// per-thread-linear global stash (coalesced; only same thread reads back)
__device__ __forceinline__ void stash_w(float* buf, const float v[4][4], int t){
    #pragma unroll
    for (int jj = 0; jj < 4; jj++)
        *(float4*)(buf + (jj*256 + t)*4) = make_float4(v[0][jj], v[1][jj], v[2][jj], v[3][jj]);
}
__device__ __forceinline__ void stash_r(const float* buf, float v[4][4], int t){
    #pragma unroll
    for (int jj = 0; jj < 4; jj++){
        float4 q = *(const float4*)(buf + (jj*256 + t)*4);
        v[0][jj]=q.x; v[1][jj]=q.y; v[2][jj]=q.z; v[3][jj]=q.w;
    }
}

// out = tanh(bias + x@U + vec@W)  (h gate); all weights direct-global
__device__ __forceinline__ void gate_f(const float* __restrict__ U, const float* __restrict__ W,
    const float* __restrict__ bias, const float* __restrict__ xT, const float* __restrict__ Sin,
    float out[4][4], int jg, int p0, int j0)
{
    float acc[4][4];
    float4 b = *(const float4*)(bias + j0);
    #pragma unroll
    for (int p = 0; p < 4; p++){ acc[p][0]=b.x; acc[p][1]=b.y; acc[p][2]=b.z; acc[p][3]=b.w; }
    mm_d(U, DD, xT, acc, jg, p0);
    mm_d(W, UNITS, Sin, acc, jg, p0);
    #pragma unroll
    for (int p = 0; p < 4; p++)
        #pragma unroll
        for (int jj = 0; jj < 4; jj++) out[p][jj] = ftanh(acc[p][jj]);
}

// fused z,g,r gates; all weights direct-global; NO internal barriers
__device__ __forceinline__ void gate3_f(const float* __restrict__ Uzgr, const float* __restrict__ Wzgr,
    const float* __restrict__ bz, const float* __restrict__ bg, const float* __restrict__ br,
    const float* __restrict__ xT, const float* __restrict__ Sin,
    float zt[4][4], float gt[4][4], float rt[4][4],
    int jg, int p0, int j0)
{
    float4 b0 = *(const float4*)(bz + j0);
    float4 b1 = *(const float4*)(bg + j0);
    float4 b2 = *(const float4*)(br + j0);
    #pragma unroll
    for (int p = 0; p < 4; p++){
        zt[p][0]=b0.x; zt[p][1]=b0.y; zt[p][2]=b0.z; zt[p][3]=b0.w;
        gt[p][0]=b1.x; gt[p][1]=b1.y; gt[p][2]=b1.z; gt[p][3]=b1.w;
        rt[p][0]=b2.x; rt[p][1]=b2.y; rt[p][2]=b2.z; rt[p][3]=b2.w;
    }
    mm3_d(Uzgr, DD, xT, zt, gt, rt, jg, p0);
    mm3_d(Wzgr, UNITS, Sin, zt, gt, rt, jg, p0);
    ELT44(zt[p][jj]=ftanh(zt[p][jj]); gt[p][jj]=ftanh(gt[p][jj]); rt[p][jj]=ftanh(rt[p][jj]))
}

// closed-form Cholesky of DELTA*((1-RHO)I + RHO*J): equicorrelated structure.
__global__ void chol_kernel(float* __restrict__ Lout)
{
    if (threadIdx.x == 0 && blockIdx.x == 0) {
        const double beta = 0.01 * 0.5;          // off-diagonal
        const double diag = 0.01;                // alpha + beta
        double c[DIMN], d[DIMN];
        double S = 0.0;
        for (int j = 0; j < DIMN; j++){
            double dj = sqrt(diag - S);
            double cj = (beta - S) / dj;
            d[j] = dj; c[j] = cj;
            S += cj*cj;
        }
        for (int i = 0; i < DIMN; i++)
            for (int j = 0; j < DIMN; j++)
                Lout[i*DIMN + j] = (j < i) ? (float)c[j] : (j == i) ? (float)d[i] : 0.0f;
    }
}

__global__ void transpose_k(const float* __restrict__ wz, const float* __restrict__ wg,
                            const float* __restrict__ wr, const float* __restrict__ wh,
                            float* __restrict__ WT)
{
    int idx = blockIdx.x*256 + threadIdx.x;           // 0..65535
    int q = idx >> 14, r2 = idx & 16383, k = r2 >> 7, j = r2 & 127;
    const float* src = (q==0)? wz : (q==1)? wg : (q==2)? wr : wh;
    WT[(q<<14) + j*UNITS + k] = src[k*UNITS + j];
}

// pack [Uz|Ug|Ur] 21x384 and [Wz|Wg|Wr] 128x384
__global__ void pack_zgr(const float* __restrict__ uz, const float* __restrict__ ug,
                         const float* __restrict__ ur,
                         const float* __restrict__ wz, const float* __restrict__ wg,
                         const float* __restrict__ wr,
                         float* __restrict__ Uzgr, float* __restrict__ Wzgr)
{
    int idx = blockIdx.x*256 + threadIdx.x;
    if (idx < 128*384){
        int k = idx/384, c = idx - k*384, g = c >> 7, j = c & 127;
        const float* s = (g==0)? wz : (g==1)? wg : wr;
        Wzgr[idx] = s[k*UNITS + j];
        return;
    }
    int i2 = idx - 128*384;
    if (i2 < 21*384){
        int k = i2/384, c = i2 - k*384, g = c >> 7, j = c & 127;
        const float* s = (g==0)? uz : (g==1)? ug : ur;
        Uzgr[i2] = s[k*UNITS + j];
    }
}

#define DGM_PARAMS \
    const float* __restrict__ inputs, const float* __restrict__ eps, \
    const float* __restrict__ w1, const float* __restrict__ b1, \
    const float* __restrict__ uz, const float* __restrict__ bz, \
    const float* __restrict__ ug, const float* __restrict__ bg, \
    const float* __restrict__ ur, const float* __restrict__ br, \
    const float* __restrict__ uh, const float* __restrict__ wh, const float* __restrict__ bh, \
    const float* __restrict__ wv, const float* __restrict__ bv, \
    const float* __restrict__ Lm, const float* __restrict__ WT, \
    const float* __restrict__ Uzgr, const float* __restrict__ Wzgr, \
    float* __restrict__ gws, \
    float* __restrict__ fp1, float* __restrict__ val1, float* __restrict__ val2, \
    float* __restrict__ t12acc

#define DGM_ARGS inputs, eps, w1, b1, uz, bz, ug, bg, ur, br, uh, wh, bh, wv, bv, \
    Lm, WT, Uzgr, Wzgr, gws, fp1, val1, val2, t12acc

template<int SG>
__device__ __forceinline__ void dgm_body(float* lds, DGM_PARAMS)
{
    float* S0 = lds;
    float* S1 = SG ? lds : lds + 4096;                // RC only
    float* S2 = lds + (SG ? 4096 : 8192);
    float* Db = lds + (SG ? 8192 : 12288);
    float* xT = lds + (SG ? 12288 : 16384);
    float* Vb = lds + (SG ? 12960 : 17056);

    const int t  = threadIdx.x;
    const int jg = t & 31;
    const int pg = t >> 5;
    const int p0 = pg * 4;
    const int j0 = jg * 4;
    const int P0 = blockIdx.x * TM;
    const int type = (P0 < NN) ? 0 : (P0 < NN + MCN*NN) ? 1 : 2;
    int base_n = 0, mrow = 0;
    if (type == 1){ int q = P0 - NN; mrow = q >> 11; base_n = q & (NN-1); }

    float* gb = gws + (size_t)blockIdx.x * GB_STRIDE;

    // ---- build x tile (and violation V for type 1) ----
    {
        int p = t & 31, kq = t >> 5;
        for (int ki = 0; ki < 3; ki++){
            int k = kq + 8*ki;
            if (k > DIMN) break;
            float xv;
            if (type == 0){
                xv = inputs[(P0 + p)*DD + k];
            } else if (type == 2){
                xv = inputs[(NN + (P0 - NN - MCN*NN) + p)*DD + k];
            } else {
                int n = base_n + p;
                float x1v = inputs[n*DD + k];
                if (k == DIMN) xv = x1v;
                else {
                    const float* ep = eps + (size_t)(mrow*NN + n)*DIMN;
                    float a = x1v;
                    for (int d = 0; d < DIMN; d++) a = fmaf(ep[d], Lm[k*DIMN + d], a);
                    float viol = a * (SIGC * x1v);
                    Vb[offs(k, p)] = viol;
                    xv = x1v + viol;
                }
            }
            xT[offs(k, p)] = xv;
        }
    }
    __syncthreads();

    // ---- forward ----
    float s_own[4][4];
    {
        float acc[4][4];
        float4 b = *(const float4*)(b1 + j0);
        #pragma unroll
        for (int p = 0; p < 4; p++){ acc[p][0]=b.x; acc[p][1]=b.y; acc[p][2]=b.z; acc[p][3]=b.w; }
        mm_d(w1, DD, xT, acc, jg, p0);
        ELT44(s_own[p][jj] = ftanh(acc[p][jj]))
        write_own(S0, s_own, j0, p0);
        __syncthreads();
    }

    float zt[4][4], gt[4][4], rt[4][4], ht[4][4];

// GATES: gate3 (reads SIN cross-thread) -> sync (prior Db readers + SIN reads done)
// -> tt into Db -> sync -> gate_f reads Db
#define GATES(SIN, SMUL) \
    gate3_f(Uzgr, Wzgr, bz, bg, br, xT, SIN, zt, gt, rt, jg, p0, j0); \
    __syncthreads(); \
    { float tt[4][4]; ELT44(tt[p][jj] = SMUL[p][jj]*rt[p][jj]) write_own(Db, tt, j0, p0); } \
    __syncthreads(); \
    gate_f(uh, wh, bh, xT, Db, ht, jg, p0, j0);

#define FWD_LAYER(SIN) \
    GATES(SIN, s_own) \
    ELT44(s_own[p][jj] = (1.f - gt[p][jj])*ht[p][jj] + zt[p][jj]*s_own[p][jj])

    FWD_LAYER(S0)                      // layer 1
    if (SG){ if (type != 2){
        stash_w(gb + ST_S1, s_own, t);
        stash_w(gb + ST_Z1, zt, t); stash_w(gb + ST_G1, gt, t); stash_w(gb + ST_R1, rt, t);
    } }
    else   { write_own(S1, s_own, j0, p0); }
    __syncthreads();                   // layer-1 gate_f's Db readers done
    write_own(Db, s_own, j0, p0);      // Sin for layer 2
    __syncthreads();

    FWD_LAYER(Db)                      // layer 2
    if (SG && type != 2){
        stash_w(gb + ST_Z2, zt, t); stash_w(gb + ST_G2, gt, t); stash_w(gb + ST_R2, rt, t);
    }
    write_own(S2, s_own, j0, p0);      // s2 in LDS for backward
    __syncthreads();

    FWD_LAYER(S2)                      // layer 3 -- zt/gt/rt/ht stay live into backward

    // ---- value head ----
    {
        float4 wv4 = *(const float4*)(wv + j0);
        float vs[4];
        #pragma unroll
        for (int p = 0; p < 4; p++)
            vs[p] = s_own[p][0]*wv4.x + s_own[p][1]*wv4.y + s_own[p][2]*wv4.z + s_own[p][3]*wv4.w;
        __syncthreads();   // layer-3 gate_f's Db readers done
        *(float4*)(Db + jg*32 + p0) = make_float4(vs[0], vs[1], vs[2], vs[3]);
        __syncthreads();
        if (t < TM){
            float v = bv[0];
            for (int j2 = 0; j2 < 32; j2++) v += Db[j2*32 + t];
            if (type == 0) val1[P0 + t] = v;
            else if (type == 2) val2[P0 + t - NN - MCN*NN] = v;
        }
        __syncthreads();
    }
    if (type == 2) return;

    // ---- backward ----
    float ds[4][4];
    {
        float4 wv4 = *(const float4*)(wv + j0);
        #pragma unroll
        for (int p = 0; p < 4; p++){ ds[p][0]=wv4.x; ds[p][1]=wv4.y; ds[p][2]=wv4.z; ds[p][3]=wv4.w; }
    }
    float proj[4] = {0.f, 0.f, 0.f, 0.f};
    float dxp[3] = {0.f, 0.f, 0.f};
    const int pi = t >> 3, il = t & 7;

    const float* WTz = WT;
    const float* WTg = WT + 16384;
    const float* WTr = WT + 2*16384;
    const float* WTh = WT + 3*16384;

#define DX_DOT(UMAT) \
    { _Pragma("unroll") for (int ii = 0; ii < 3; ii++){ \
        int i = il + 8*ii; \
        if (i < DD){ \
            const float* Urow = UMAT + i*UNITS; \
            float a = 0.f; \
            for (int j2 = 0; j2 < UNITS; j2++) a = fmaf(Db[offs(j2, pi)], Urow[j2], a); \
            dxp[ii] += a; \
        } } }

// K=20 direct-global U pass; reads only own Vb/SEL; no barriers
#define PROJ_D(UMAT, SEL) \
    { float uv[4][4]; \
      ELT44(uv[p][jj] = 0.f) \
      mm_d(UMAT, DIMN, Vb, uv, jg, p0); \
      ELT44(proj[p] += uv[p][jj]*SEL[p][jj]) }

// Backward layer as 4 sequential delta passes (z -> g -> h -> r), barriers only
// around Db handoffs; all WT matmuls direct-global.
// MODE 0: sl=S2(LDS), gates live in regs (layer 3)
// MODE 1: recompute gates from SLP (RC fallback)
// MODE 2: sl=stash S1, z/g/r stash, h=(S2_lds - z*sl)/(1-g)   (SG layer 2)
// MODE 3: sl=SLP(LDS), z/g/r stash, h=(stash S1 - z*sl)/(1-g) (SG layer 1)
#define BWD_LAYER(SLP, MODE, GZ, GG, GR) \
    { \
    float dsn[4][4]; \
    if (MODE == 1){ \
        float slg[4][4]; read_own(SLP, slg, j0, p0); \
        GATES(SLP, slg) \
    } \
    { /* pass z */ \
        float sl[4][4], zv[4][4]; \
        if (MODE == 2){ stash_r(gb + ST_S1, sl, t); stash_r(gb + GZ, zv, t); } \
        else if (MODE == 3){ read_own(SLP, sl, j0, p0); stash_r(gb + GZ, zv, t); } \
        else if (MODE == 0){ read_own(S2, sl, j0, p0); ELT44(zv[p][jj] = zt[p][jj]) } \
        else { read_own(SLP, sl, j0, p0); ELT44(zv[p][jj] = zt[p][jj]) } \
        float dzp[4][4]; \
        ELT44(float d=ds[p][jj]; float zz=zv[p][jj]; \
            dzp[p][jj] = d*sl[p][jj]*(1.f - zz*zz); dsn[p][jj] = d*zz) \
        __syncthreads(); \
        write_own(Db, dzp, j0, p0); \
        __syncthreads(); \
        if (type == 1){ PROJ_D(uz, dzp) } else { DX_DOT(uz) } \
    } \
    mm_d(WTz, UNITS, Db, dsn, jg, p0); \
    float dhp[4][4]; \
    { /* pass g */ \
        float gv[4][4], hv[4][4]; \
        if (MODE == 2 || MODE == 3){ \
            float zv[4][4], sl[4][4], sn[4][4]; \
            stash_r(gb + GZ, zv, t); stash_r(gb + GG, gv, t); \
            if (MODE == 2){ stash_r(gb + ST_S1, sl, t); read_own(S2, sn, j0, p0); } \
            else { read_own(SLP, sl, j0, p0); stash_r(gb + ST_S1, sn, t); } \
            ELT44(hv[p][jj] = (sn[p][jj] - zv[p][jj]*sl[p][jj]) / (1.f - gv[p][jj])) \
        } else { ELT44(gv[p][jj] = gt[p][jj]; hv[p][jj] = ht[p][jj]) } \
        float dgp[4][4]; \
        ELT44(float d=ds[p][jj]; float gg=gv[p][jj]; float hh=hv[p][jj]; \
            dgp[p][jj] = -d*hh*(1.f - gg*gg); \
            dhp[p][jj] = d*(1.f - gg)*(1.f - hh*hh)) \
        __syncthreads(); \
        write_own(Db, dgp, j0, p0); \
        __syncthreads(); \
        if (type == 1){ PROJ_D(ug, dgp) } else { DX_DOT(ug) } \
    } \
    mm_d(WTg, UNITS, Db, dsn, jg, p0); \
    /* pass h */ \
    __syncthreads(); \
    write_own(Db, dhp, j0, p0); \
    __syncthreads(); \
    if (type == 1){ PROJ_D(uh, dhp) } else { DX_DOT(uh) } \
    float dsr[4][4]; \
    ELT44(dsr[p][jj] = 0.f) \
    mm_d(WTh, UNITS, Db, dsr, jg, p0); \
    { /* pass r */ \
        float rv[4][4], sl[4][4], drp[4][4]; \
        if (MODE == 2){ stash_r(gb + GR, rv, t); stash_r(gb + ST_S1, sl, t); } \
        else if (MODE == 3){ stash_r(gb + GR, rv, t); read_own(SLP, sl, j0, p0); } \
        else if (MODE == 0){ ELT44(rv[p][jj] = rt[p][jj]) read_own(S2, sl, j0, p0); } \
        else { ELT44(rv[p][jj] = rt[p][jj]) read_own(SLP, sl, j0, p0); } \
        ELT44(float dr=dsr[p][jj]; float rr=rv[p][jj]; \
            drp[p][jj] = dr*sl[p][jj]*(1.f - rr*rr); dsn[p][jj] += dr*rr) \
        __syncthreads(); \
        write_own(Db, drp, j0, p0); \
        __syncthreads(); \
        if (type == 1){ PROJ_D(ur, drp) } else { DX_DOT(ur) } \
    } \
    mm_d(WTr, UNITS, Db, dsn, jg, p0); \
    ELT44(ds[p][jj] = dsn[p][jj]) \
    }

    BWD_LAYER(S0, 0, ST_Z2, ST_G2, ST_R2)                  // layer 3: gates live
    BWD_LAYER(S1, (SG ? 2 : 1), ST_Z2, ST_G2, ST_R2)       // layer 2
    if (SG){ BWD_LAYER(S0, 3, ST_Z1, ST_G1, ST_R1) }       // layer 1 (stash)
    else   { BWD_LAYER(S0, 1, ST_Z1, ST_G1, ST_R1) }       // layer 1 (recompute)

    // first-layer backward + epilogue
    {
        float s0l[4][4];
        read_own(S0, s0l, j0, p0);
        float v0[4][4];
        ELT44(v0[p][jj] = ds[p][jj]*(1.f - s0l[p][jj]*s0l[p][jj]))

        if (type == 1){
            PROJ_D(w1, v0)
            __syncthreads();   // last mm_d's Db readers done
            *(float4*)(Db + jg*32 + p0) = make_float4(proj[0], proj[1], proj[2], proj[3]);
            __syncthreads();
            if (t < TM){
                float s = 0.f;
                for (int j2 = 0; j2 < 32; j2++) s += Db[j2*32 + t];
                atomicAdd(t12acc + base_n + t, s);
            }
        } else {
            __syncthreads();   // last mm_d's Db readers done
            write_own(Db, v0, j0, p0);
            __syncthreads();
            DX_DOT(w1)
            #pragma unroll
            for (int ii = 0; ii < 3; ii++){
                int i = il + 8*ii;
                if (i < DD) fp1[(P0 + pi)*DD + i] = dxp[ii];
            }
        }
    }
}

__global__ __launch_bounds__(256) __attribute__((amdgpu_waves_per_eu(2,2))) void dgm_sg(DGM_PARAMS){
    __shared__ float lds[L_TOT_SG];
    dgm_body<1>(lds, DGM_ARGS);
}
__global__ __launch_bounds__(256) __attribute__((amdgpu_waves_per_eu(2,2))) void dgm_rc(DGM_PARAMS){
    __shared__ float lds[L_TOT_RC];
    dgm_body<0>(lds, DGM_ARGS);
}

__global__ void finalize_k(const float* __restrict__ inputs, const float* __restrict__ eps,
    const float* __restrict__ Lm, const float* __restrict__ fp1, const float* __restrict__ val1,
    const float* __restrict__ val2, const float* __restrict__ t12acc, float* __restrict__ out)
{
    int n = blockIdx.x*256 + threadIdx.x;
    if (n >= NN) return;
    float fp[DD];
    #pragma unroll
    for (int k = 0; k < DD; k++) fp[k] = fp1[n*DD + k];
    float t11 = fp[DIMN];
    #pragma unroll
    for (int k = 0; k < DIMN; k++) t11 = fmaf(MUC*inputs[n*DD + k], fp[k], t11);
    float esum[DIMN];
    #pragma unroll
    for (int d = 0; d < DIMN; d++){
        float a = 0.f;
        for (int m = 0; m < MCN; m++) a += eps[(size_t)(m*NN + n)*DIMN + d];
        esum[d] = a;
    }
    float t12b = 0.f;
    #pragma unroll
    for (int k = 0; k < DIMN; k++){
        float loc = inputs[n*DD + k];
        float ssum = (float)MCN * loc;
        #pragma unroll
        for (int d = 0; d < DIMN; d++) ssum = fmaf(esum[d], Lm[k*DIMN + d], ssum);
        float vsum = ssum * (SIGC*loc);
        t12b = fmaf(fp[k], vsum, t12b);
    }
    float term12 = (t12acc[n] - t12b) * (1.0f/(DELTAC*(float)MCN));
    out[n] = t11 + 0.5f*term12 - RC*val1[n];

    float prod = 1.f;
    #pragma unroll
    for (int k = 0; k < DIMN; k++) prod *= inputs[(NN + n)*DD + k];
    float payoff = powf(prod, 1.0f/(float)DIMN);
    if (!(payoff > 0.f)) payoff = 0.f;
    out[NN + n] = val2[n] - payoff;
}

extern "C" void kernel_launch(void* const* d_in, const int* in_sizes, int n_in,
                              void* d_out, int out_size, void* d_ws, size_t ws_size,
                              hipStream_t stream)
{
    const float* inputs = (const float*)d_in[0];
    const float* eps    = (const float*)d_in[1];
    const float* w1     = (const float*)d_in[2];
    const float* b1     = (const float*)d_in[3];
    const float* uz     = (const float*)d_in[4];
    const float* wz     = (const float*)d_in[5];
    const float* bz     = (const float*)d_in[6];
    const float* ug     = (const float*)d_in[7];
    const float* wg     = (const float*)d_in[8];
    const float* bg     = (const float*)d_in[9];
    const float* urr    = (const float*)d_in[10];
    const float* wr     = (const float*)d_in[11];
    const float* br     = (const float*)d_in[12];
    const float* uh     = (const float*)d_in[13];
    const float* wh     = (const float*)d_in[14];
    const float* bh     = (const float*)d_in[15];
    const float* wv     = (const float*)d_in[16];
    const float* bv     = (const float*)d_in[17];

    float* ws    = (float*)d_ws;
    float* Lm    = ws + OFF_L;
    float* WT    = ws + OFF_WT;
    float* Uzgr  = ws + OFF_UZGR;
    float* Wzgr  = ws + OFF_WZGR;
    float* fp1   = ws + OFF_FP1;
    float* val1  = ws + OFF_VAL1;
    float* val2  = ws + OFF_VAL2;
    float* t12   = ws + OFF_T12;
    float* gates = ws + OFF_GATES;
    float* out   = (float*)d_out;

    hipMemsetAsync(t12, 0, NN*sizeof(float), stream);
    hipLaunchKernelGGL(chol_kernel, dim3(1), dim3(64), 0, stream, Lm);
    hipLaunchKernelGGL(transpose_k, dim3(256), dim3(256), 0, stream, wz, wg, wr, wh, WT);
    hipLaunchKernelGGL(pack_zgr, dim3(224), dim3(256), 0, stream, uz, ug, urr, wz, wg, wr, Uzgr, Wzgr);

    size_t need_bytes = ((size_t)OFF_GATES + (size_t)NBLK * (size_t)GB_STRIDE) * sizeof(float);
    if (ws_size >= need_bytes){
        hipLaunchKernelGGL(dgm_sg, dim3(NBLK), dim3(256), 0, stream,
            inputs, eps, w1, b1, uz, bz, ug, bg, urr, br, uh, wh, bh, wv, bv,
            Lm, WT, Uzgr, Wzgr, gates, fp1, val1, val2, t12);
    } else {
        hipLaunchKernelGGL(dgm_rc, dim3(NBLK), dim3(256), 0, stream,
            inputs, eps, w1, b1, uz, bz, ug, bg, urr, br, uh, wh, bh, wv, bv,
            Lm, WT, Uzgr, Wzgr, gates, fp1, val1, val2, t12);
    }
    hipLaunchKernelGGL(finalize_k, dim3(8), dim3(256), 0, stream,
        inputs, eps, Lm, fp1, val1, val2, t12, out);
}

// Round 12
// 1249.396 us; speedup vs baseline: 5.6299x; 1.0417x over previous
//
#include <hip/hip_runtime.h>
#include <math.h>

#define DIMN 20
#define DD 21
#define NN 2048
#define MCN 32
#define UNITS 128
#define SIGC 0.2f
#define MUC 0.05f
#define RC 0.05f
#define DELTAC 0.01f

#define TM 32
#define PTOT (NN + MCN*NN + NN)
#define NBLK (PTOT/TM)

// ws layout (floats)
#define OFF_L 0
#define OFF_WT 512
#define OFF_UZGR (OFF_WT + 4*16384)      // 66048 : packed [Uz|Ug|Ur] 21x384 (pad to 8192)
#define OFF_WZGR (OFF_UZGR + 8192)       // 74240 : packed [Wz|Wg|Wr] 128x384
#define OFF_FP1  (OFF_WZGR + 49152)      // 123392
#define OFF_VAL1 (OFF_FP1 + NN*DD)       // 166400
#define OFF_VAL2 (OFF_VAL1 + NN)         // 168448
#define OFF_T12  (OFF_VAL2 + NN)         // 170496
#define OFF_GATES (OFF_T12 + NN)         // 172544 : per-block stash

// per-block stash (floats), per-thread-linear layout; h recovered, not stashed
#define ST_S1 0
#define ST_Z1 4096
#define ST_G1 8192
#define ST_R1 12288
#define ST_Z2 16384
#define ST_G2 20480
#define ST_R2 24576
#define GB_STRIDE 28672     // total stash = (172544 + 2176*28672)*4 B = 250.3 MB

// LDS layouts (floats); Db2 added for merged z+g backward pass
// SG: S0 0 | S2 4096 | Db 8192 | Db2 12288 | xT 16384 | Vb 17056 | tot 17728 (70.9KB -> 2 blk/CU)
// RC: S0 0 | S1 4096 | S2 8192 | Db 12288 | Db2 16384 | xT 20480 | Vb 21152 | tot 21824 (87.3KB -> 1)
#define L_TOT_SG 17728
#define L_TOT_RC 21824

#define ELT44(...) _Pragma("unroll") for (int p = 0; p < 4; p++){ _Pragma("unroll") for (int jj = 0; jj < 4; jj++){ __VA_ARGS__; } }

__device__ __forceinline__ int offq(int row, int p0){
    return row*32 + ((p0 + 4*(row&7)) & 31);
}
__device__ __forceinline__ int offs(int row, int p){
    return row*32 + (((p & 28) + 4*(row&7)) & 31) + (p & 3);
}

// fast tanh: 1 - 2/(e^{2x}+1), clamp to +-9, ~6 VALU vs ~25 libm
__device__ __forceinline__ float ftanh(float x){
    float cx = fminf(9.f, fmaxf(-9.f, x));
    float e  = __expf(2.f*cx);
    return fmaf(-2.f, __builtin_amdgcn_rcpf(e + 1.f), 1.f);
}

#define FMA16(acc, s4, w4) \
  acc[0][0]=fmaf(s4.x,w4.x,acc[0][0]); acc[0][1]=fmaf(s4.x,w4.y,acc[0][1]); \
  acc[0][2]=fmaf(s4.x,w4.z,acc[0][2]); acc[0][3]=fmaf(s4.x,w4.w,acc[0][3]); \
  acc[1][0]=fmaf(s4.y,w4.x,acc[1][0]); acc[1][1]=fmaf(s4.y,w4.y,acc[1][1]); \
  acc[1][2]=fmaf(s4.y,w4.z,acc[1][2]); acc[1][3]=fmaf(s4.y,w4.w,acc[1][3]); \
  acc[2][0]=fmaf(s4.z,w4.x,acc[2][0]); acc[2][1]=fmaf(s4.z,w4.y,acc[2][1]); \
  acc[2][2]=fmaf(s4.z,w4.z,acc[2][2]); acc[2][3]=fmaf(s4.z,w4.w,acc[2][3]); \
  acc[3][0]=fmaf(s4.w,w4.x,acc[3][0]); acc[3][1]=fmaf(s4.w,w4.y,acc[3][1]); \
  acc[3][2]=fmaf(s4.w,w4.z,acc[3][2]); acc[3][3]=fmaf(s4.w,w4.w,acc[3][3]);

// direct-global matmul over 128-wide W rows; L2-hot weights; NO barriers.
// unroll 8: 8 w4 loads in flight to amortize ~200cyc L2 latency (R11 was 4).
__device__ __forceinline__ void mm_d(const float* __restrict__ gW, int K,
    const float* __restrict__ vec, float acc[4][4], int jg, int p0)
{
    const float* wp = gW + 4*jg;
    #pragma unroll 8
    for (int k = 0; k < K; k++){
        float4 w4 = *(const float4*)(wp + k*UNITS);
        float4 s4 = *(const float4*)(vec + offq(k, p0));
        FMA16(acc, s4, w4)
    }
}
// 384-packed rows ([z|g|r]); one s4 feeds 48 FMAs; NO barriers.
__device__ __forceinline__ void mm3_d(const float* __restrict__ gW, int K,
    const float* __restrict__ vec, float a0[4][4], float a1[4][4], float a2[4][4],
    int jg, int p0)
{
    const float* wp = gW + 4*jg;
    #pragma unroll 2
    for (int k = 0; k < K; k++){
        const float* r = wp + k*384;
        float4 s4 = *(const float4*)(vec + offq(k, p0));
        float4 w0 = *(const float4*)(r);
        float4 w1v = *(const float4*)(r + 128);
        float4 w2 = *(const float4*)(r + 256);
        FMA16(a0, s4, w0) FMA16(a1, s4, w1v) FMA16(a2, s4, w2)
    }
}

__device__ __forceinline__ void write_own(float* buf, const float v[4][4], int j0, int p0){
    #pragma unroll
    for (int jj = 0; jj < 4; jj++){
        int j = j0 + jj;
        float4 q = make_float4(v[0][jj], v[1][jj], v[2][jj], v[3][jj]);
        *(float4*)(buf + offq(j, p0)) = q;
    }
}
__device__ __forceinline__ void read_own(const float* buf, float v[4][4], int j0, int p0){
    #pragma unroll
    for (int jj = 0; jj < 4; jj++){
        int j = j0 + jj;
        float4 q = *(const float4*)(buf + offq(j, p0));
        v[0][jj]=q.x; v[1][jj]=q.y; v[2][jj]=q.z; v[3][jj]=q.w;
    }
}
// per-thread-linear global stash (coalesced; only same thread reads back)
__device__ __forceinline__ void stash_w(float* buf, const float v[4][4], int t){
    #pragma unroll
    for (int jj = 0; jj < 4; jj++)
        *(float4*)(buf + (jj*256 + t)*4) = make_float4(v[0][jj], v[1][jj], v[2][jj], v[3][jj]);
}
__device__ __forceinline__ void stash_r(const float* buf, float v[4][4], int t){
    #pragma unroll
    for (int jj = 0; jj < 4; jj++){
        float4 q = *(const float4*)(buf + (jj*256 + t)*4);
        v[0][jj]=q.x; v[1][jj]=q.y; v[2][jj]=q.z; v[3][jj]=q.w;
    }
}

// out = tanh(bias + x@U + vec@W)  (h gate); all weights direct-global
__device__ __forceinline__ void gate_f(const float* __restrict__ U, const float* __restrict__ W,
    const float* __restrict__ bias, const float* __restrict__ xT, const float* __restrict__ Sin,
    float out[4][4], int jg, int p0, int j0)
{
    float acc[4][4];
    float4 b = *(const float4*)(bias + j0);
    #pragma unroll
    for (int p = 0; p < 4; p++){ acc[p][0]=b.x; acc[p][1]=b.y; acc[p][2]=b.z; acc[p][3]=b.w; }
    mm_d(U, DD, xT, acc, jg, p0);
    mm_d(W, UNITS, Sin, acc, jg, p0);
    #pragma unroll
    for (int p = 0; p < 4; p++)
        #pragma unroll
        for (int jj = 0; jj < 4; jj++) out[p][jj] = ftanh(acc[p][jj]);
}

// fused z,g,r gates; all weights direct-global; NO internal barriers
__device__ __forceinline__ void gate3_f(const float* __restrict__ Uzgr, const float* __restrict__ Wzgr,
    const float* __restrict__ bz, const float* __restrict__ bg, const float* __restrict__ br,
    const float* __restrict__ xT, const float* __restrict__ Sin,
    float zt[4][4], float gt[4][4], float rt[4][4],
    int jg, int p0, int j0)
{
    float4 b0 = *(const float4*)(bz + j0);
    float4 b1 = *(const float4*)(bg + j0);
    float4 b2 = *(const float4*)(br + j0);
    #pragma unroll
    for (int p = 0; p < 4; p++){
        zt[p][0]=b0.x; zt[p][1]=b0.y; zt[p][2]=b0.z; zt[p][3]=b0.w;
        gt[p][0]=b1.x; gt[p][1]=b1.y; gt[p][2]=b1.z; gt[p][3]=b1.w;
        rt[p][0]=b2.x; rt[p][1]=b2.y; rt[p][2]=b2.z; rt[p][3]=b2.w;
    }
    mm3_d(Uzgr, DD, xT, zt, gt, rt, jg, p0);
    mm3_d(Wzgr, UNITS, Sin, zt, gt, rt, jg, p0);
    ELT44(zt[p][jj]=ftanh(zt[p][jj]); gt[p][jj]=ftanh(gt[p][jj]); rt[p][jj]=ftanh(rt[p][jj]))
}

// closed-form Cholesky of DELTA*((1-RHO)I + RHO*J): equicorrelated structure.
__global__ void chol_kernel(float* __restrict__ Lout)
{
    if (threadIdx.x == 0 && blockIdx.x == 0) {
        const double beta = 0.01 * 0.5;          // off-diagonal
        const double diag = 0.01;                // alpha + beta
        double c[DIMN], d[DIMN];
        double S = 0.0;
        for (int j = 0; j < DIMN; j++){
            double dj = sqrt(diag - S);
            double cj = (beta - S) / dj;
            d[j] = dj; c[j] = cj;
            S += cj*cj;
        }
        for (int i = 0; i < DIMN; i++)
            for (int j = 0; j < DIMN; j++)
                Lout[i*DIMN + j] = (j < i) ? (float)c[j] : (j == i) ? (float)d[i] : 0.0f;
    }
}

__global__ void transpose_k(const float* __restrict__ wz, const float* __restrict__ wg,
                            const float* __restrict__ wr, const float* __restrict__ wh,
                            float* __restrict__ WT)
{
    int idx = blockIdx.x*256 + threadIdx.x;           // 0..65535
    int q = idx >> 14, r2 = idx & 16383, k = r2 >> 7, j = r2 & 127;
    const float* src = (q==0)? wz : (q==1)? wg : (q==2)? wr : wh;
    WT[(q<<14) + j*UNITS + k] = src[k*UNITS + j];
}

// pack [Uz|Ug|Ur] 21x384 and [Wz|Wg|Wr] 128x384
__global__ void pack_zgr(const float* __restrict__ uz, const float* __restrict__ ug,
                         const float* __restrict__ ur,
                         const float* __restrict__ wz, const float* __restrict__ wg,
                         const float* __restrict__ wr,
                         float* __restrict__ Uzgr, float* __restrict__ Wzgr)
{
    int idx = blockIdx.x*256 + threadIdx.x;
    if (idx < 128*384){
        int k = idx/384, c = idx - k*384, g = c >> 7, j = c & 127;
        const float* s = (g==0)? wz : (g==1)? wg : wr;
        Wzgr[idx] = s[k*UNITS + j];
        return;
    }
    int i2 = idx - 128*384;
    if (i2 < 21*384){
        int k = i2/384, c = i2 - k*384, g = c >> 7, j = c & 127;
        const float* s = (g==0)? uz : (g==1)? ug : ur;
        Uzgr[i2] = s[k*UNITS + j];
    }
}

#define DGM_PARAMS \
    const float* __restrict__ inputs, const float* __restrict__ eps, \
    const float* __restrict__ w1, const float* __restrict__ b1, \
    const float* __restrict__ uz, const float* __restrict__ bz, \
    const float* __restrict__ ug, const float* __restrict__ bg, \
    const float* __restrict__ ur, const float* __restrict__ br, \
    const float* __restrict__ uh, const float* __restrict__ wh, const float* __restrict__ bh, \
    const float* __restrict__ wv, const float* __restrict__ bv, \
    const float* __restrict__ Lm, const float* __restrict__ WT, \
    const float* __restrict__ Uzgr, const float* __restrict__ Wzgr, \
    float* __restrict__ gws, \
    float* __restrict__ fp1, float* __restrict__ val1, float* __restrict__ val2, \
    float* __restrict__ t12acc

#define DGM_ARGS inputs, eps, w1, b1, uz, bz, ug, bg, ur, br, uh, wh, bh, wv, bv, \
    Lm, WT, Uzgr, Wzgr, gws, fp1, val1, val2, t12acc

template<int SG>
__device__ __forceinline__ void dgm_body(float* lds, DGM_PARAMS)
{
    float* S0  = lds;
    float* S1  = SG ? lds : lds + 4096;               // RC only
    float* S2  = lds + (SG ? 4096 : 8192);
    float* Db  = lds + (SG ? 8192 : 12288);
    float* Db2 = lds + (SG ? 12288 : 16384);
    float* xT  = lds + (SG ? 16384 : 20480);
    float* Vb  = lds + (SG ? 17056 : 21152);

    const int t  = threadIdx.x;
    const int jg = t & 31;
    const int pg = t >> 5;
    const int p0 = pg * 4;
    const int j0 = jg * 4;
    const int P0 = blockIdx.x * TM;
    const int type = (P0 < NN) ? 0 : (P0 < NN + MCN*NN) ? 1 : 2;
    int base_n = 0, mrow = 0;
    if (type == 1){ int q = P0 - NN; mrow = q >> 11; base_n = q & (NN-1); }

    float* gb = gws + (size_t)blockIdx.x * GB_STRIDE;

    // ---- build x tile (and violation V for type 1) ----
    {
        int p = t & 31, kq = t >> 5;
        for (int ki = 0; ki < 3; ki++){
            int k = kq + 8*ki;
            if (k > DIMN) break;
            float xv;
            if (type == 0){
                xv = inputs[(P0 + p)*DD + k];
            } else if (type == 2){
                xv = inputs[(NN + (P0 - NN - MCN*NN) + p)*DD + k];
            } else {
                int n = base_n + p;
                float x1v = inputs[n*DD + k];
                if (k == DIMN) xv = x1v;
                else {
                    const float* ep = eps + (size_t)(mrow*NN + n)*DIMN;
                    float a = x1v;
                    for (int d = 0; d < DIMN; d++) a = fmaf(ep[d], Lm[k*DIMN + d], a);
                    float viol = a * (SIGC * x1v);
                    Vb[offs(k, p)] = viol;
                    xv = x1v + viol;
                }
            }
            xT[offs(k, p)] = xv;
        }
    }
    __syncthreads();

    // ---- forward ----
    float s_own[4][4];
    {
        float acc[4][4];
        float4 b = *(const float4*)(b1 + j0);
        #pragma unroll
        for (int p = 0; p < 4; p++){ acc[p][0]=b.x; acc[p][1]=b.y; acc[p][2]=b.z; acc[p][3]=b.w; }
        mm_d(w1, DD, xT, acc, jg, p0);
        ELT44(s_own[p][jj] = ftanh(acc[p][jj]))
        write_own(S0, s_own, j0, p0);
        __syncthreads();
    }

    float zt[4][4], gt[4][4], rt[4][4], ht[4][4];

#define GATES(SIN, SMUL) \
    gate3_f(Uzgr, Wzgr, bz, bg, br, xT, SIN, zt, gt, rt, jg, p0, j0); \
    __syncthreads(); \
    { float tt[4][4]; ELT44(tt[p][jj] = SMUL[p][jj]*rt[p][jj]) write_own(Db, tt, j0, p0); } \
    __syncthreads(); \
    gate_f(uh, wh, bh, xT, Db, ht, jg, p0, j0);

#define FWD_LAYER(SIN) \
    GATES(SIN, s_own) \
    ELT44(s_own[p][jj] = (1.f - gt[p][jj])*ht[p][jj] + zt[p][jj]*s_own[p][jj])

    FWD_LAYER(S0)                      // layer 1
    if (SG){ if (type != 2){
        stash_w(gb + ST_S1, s_own, t);
        stash_w(gb + ST_Z1, zt, t); stash_w(gb + ST_G1, gt, t); stash_w(gb + ST_R1, rt, t);
    } }
    else   { write_own(S1, s_own, j0, p0); }
    __syncthreads();                   // layer-1 gate_f's Db readers done
    write_own(Db, s_own, j0, p0);      // Sin for layer 2
    __syncthreads();

    FWD_LAYER(Db)                      // layer 2
    if (SG && type != 2){
        stash_w(gb + ST_Z2, zt, t); stash_w(gb + ST_G2, gt, t); stash_w(gb + ST_R2, rt, t);
    }
    write_own(S2, s_own, j0, p0);      // s2 in LDS for backward
    __syncthreads();

    FWD_LAYER(S2)                      // layer 3 -- zt/gt/rt/ht stay live into backward

    // ---- value head ----
    {
        float4 wv4 = *(const float4*)(wv + j0);
        float vs[4];
        #pragma unroll
        for (int p = 0; p < 4; p++)
            vs[p] = s_own[p][0]*wv4.x + s_own[p][1]*wv4.y + s_own[p][2]*wv4.z + s_own[p][3]*wv4.w;
        __syncthreads();   // layer-3 gate_f's Db readers done
        *(float4*)(Db + jg*32 + p0) = make_float4(vs[0], vs[1], vs[2], vs[3]);
        __syncthreads();
        if (t < TM){
            float v = bv[0];
            for (int j2 = 0; j2 < 32; j2++) v += Db[j2*32 + t];
            if (type == 0) val1[P0 + t] = v;
            else if (type == 2) val2[P0 + t - NN - MCN*NN] = v;
        }
        __syncthreads();
    }
    if (type == 2) return;

    // ---- backward ----
    float ds[4][4];
    {
        float4 wv4 = *(const float4*)(wv + j0);
        #pragma unroll
        for (int p = 0; p < 4; p++){ ds[p][0]=wv4.x; ds[p][1]=wv4.y; ds[p][2]=wv4.z; ds[p][3]=wv4.w; }
    }
    float proj[4] = {0.f, 0.f, 0.f, 0.f};
    float dxp[3] = {0.f, 0.f, 0.f};
    const int pi = t >> 3, il = t & 7;

    const float* WTz = WT;
    const float* WTg = WT + 16384;
    const float* WTr = WT + 2*16384;
    const float* WTh = WT + 3*16384;

#define DX_DOT(UMAT, BUF) \
    { _Pragma("unroll") for (int ii = 0; ii < 3; ii++){ \
        int i = il + 8*ii; \
        if (i < DD){ \
            const float* Urow = UMAT + i*UNITS; \
            float a = 0.f; \
            for (int j2 = 0; j2 < UNITS; j2++) a = fmaf(BUF[offs(j2, pi)], Urow[j2], a); \
            dxp[ii] += a; \
        } } }

// K=20 direct-global U pass; reads only own Vb/SEL; no barriers
#define PROJ_D(UMAT, SEL) \
    { float uv[4][4]; \
      ELT44(uv[p][jj] = 0.f) \
      mm_d(UMAT, DIMN, Vb, uv, jg, p0); \
      ELT44(proj[p] += uv[p][jj]*SEL[p][jj]) }

// Backward layer: merged z+g pass (dzp->Db, dgp->Db2, one sync pair, two
// back-to-back matmuls -> cross-matmul load overlap), then h, then r.
// MODE 0: sl=S2(LDS), gates live in regs (layer 3)
// MODE 1: recompute gates from SLP (RC fallback)
// MODE 2: sl=stash S1, z/g/r stash, h=(S2_lds - z*sl)/(1-g)   (SG layer 2)
// MODE 3: sl=SLP(LDS), z/g/r stash, h=(stash S1 - z*sl)/(1-g) (SG layer 1)
#define BWD_LAYER(SLP, MODE, GZ, GG, GR) \
    { \
    float dsn[4][4], dhp[4][4]; \
    if (MODE == 1){ \
        float slg[4][4]; read_own(SLP, slg, j0, p0); \
        GATES(SLP, slg) \
    } \
    { /* merged z+g (+h prep): all deltas computable upfront */ \
        float sl[4][4], zv[4][4], gv[4][4], hv[4][4]; \
        if (MODE == 2){ stash_r(gb + ST_S1, sl, t); stash_r(gb + GZ, zv, t); stash_r(gb + GG, gv, t); } \
        else if (MODE == 3){ read_own(SLP, sl, j0, p0); stash_r(gb + GZ, zv, t); stash_r(gb + GG, gv, t); } \
        else if (MODE == 0){ read_own(S2, sl, j0, p0); ELT44(zv[p][jj]=zt[p][jj]; gv[p][jj]=gt[p][jj]; hv[p][jj]=ht[p][jj]) } \
        else { read_own(SLP, sl, j0, p0); ELT44(zv[p][jj]=zt[p][jj]; gv[p][jj]=gt[p][jj]; hv[p][jj]=ht[p][jj]) } \
        if (MODE == 2 || MODE == 3){ \
            float sn[4][4]; \
            if (MODE == 2){ read_own(S2, sn, j0, p0); } \
            else { stash_r(gb + ST_S1, sn, t); } \
            ELT44(hv[p][jj] = (sn[p][jj] - zv[p][jj]*sl[p][jj]) / (1.f - gv[p][jj])) \
        } \
        float dzp[4][4], dgp[4][4]; \
        ELT44(float d=ds[p][jj]; float zz=zv[p][jj]; \
            dzp[p][jj] = d*sl[p][jj]*(1.f - zz*zz); dsn[p][jj] = d*zz) \
        ELT44(float d=ds[p][jj]; float gg=gv[p][jj]; float hh=hv[p][jj]; \
            dgp[p][jj] = -d*hh*(1.f - gg*gg); \
            dhp[p][jj] = d*(1.f - gg)*(1.f - hh*hh)) \
        __syncthreads(); \
        write_own(Db,  dzp, j0, p0); \
        write_own(Db2, dgp, j0, p0); \
        __syncthreads(); \
        if (type == 1){ PROJ_D(uz, dzp) PROJ_D(ug, dgp) } \
        else { DX_DOT(uz, Db) DX_DOT(ug, Db2) } \
    } \
    mm_d(WTz, UNITS, Db,  dsn, jg, p0); \
    mm_d(WTg, UNITS, Db2, dsn, jg, p0); \
    /* h pass */ \
    __syncthreads(); \
    write_own(Db, dhp, j0, p0); \
    __syncthreads(); \
    if (type == 1){ PROJ_D(uh, dhp) } else { DX_DOT(uh, Db) } \
    float dsr[4][4]; \
    ELT44(dsr[p][jj] = 0.f) \
    mm_d(WTh, UNITS, Db, dsr, jg, p0); \
    { /* r pass */ \
        float rv[4][4], sl[4][4], drp[4][4]; \
        if (MODE == 2){ stash_r(gb + GR, rv, t); stash_r(gb + ST_S1, sl, t); } \
        else if (MODE == 3){ stash_r(gb + GR, rv, t); read_own(SLP, sl, j0, p0); } \
        else if (MODE == 0){ ELT44(rv[p][jj] = rt[p][jj]) read_own(S2, sl, j0, p0); } \
        else { ELT44(rv[p][jj] = rt[p][jj]) read_own(SLP, sl, j0, p0); } \
        ELT44(float dr=dsr[p][jj]; float rr=rv[p][jj]; \
            drp[p][jj] = dr*sl[p][jj]*(1.f - rr*rr); dsn[p][jj] += dr*rr) \
        __syncthreads(); \
        write_own(Db, drp, j0, p0); \
        __syncthreads(); \
        if (type == 1){ PROJ_D(ur, drp) } else { DX_DOT(ur, Db) } \
    } \
    mm_d(WTr, UNITS, Db, dsn, jg, p0); \
    ELT44(ds[p][jj] = dsn[p][jj]) \
    }

    BWD_LAYER(S0, 0, ST_Z2, ST_G2, ST_R2)                  // layer 3: gates live
    BWD_LAYER(S1, (SG ? 2 : 1), ST_Z2, ST_G2, ST_R2)       // layer 2
    if (SG){ BWD_LAYER(S0, 3, ST_Z1, ST_G1, ST_R1) }       // layer 1 (stash)
    else   { BWD_LAYER(S0, 1, ST_Z1, ST_G1, ST_R1) }       // layer 1 (recompute)

    // first-layer backward + epilogue
    {
        float s0l[4][4];
        read_own(S0, s0l, j0, p0);
        float v0[4][4];
        ELT44(v0[p][jj] = ds[p][jj]*(1.f - s0l[p][jj]*s0l[p][jj]))

        if (type == 1){
            PROJ_D(w1, v0)
            __syncthreads();   // last mm_d's Db readers done
            *(float4*)(Db + jg*32 + p0) = make_float4(proj[0], proj[1], proj[2], proj[3]);
            __syncthreads();
            if (t < TM){
                float s = 0.f;
                for (int j2 = 0; j2 < 32; j2++) s += Db[j2*32 + t];
                atomicAdd(t12acc + base_n + t, s);
            }
        } else {
            __syncthreads();   // last mm_d's Db readers done
            write_own(Db, v0, j0, p0);
            __syncthreads();
            DX_DOT(w1, Db)
            #pragma unroll
            for (int ii = 0; ii < 3; ii++){
                int i = il + 8*ii;
                if (i < DD) fp1[(P0 + pi)*DD + i] = dxp[ii];
            }
        }
    }
}

__global__ __launch_bounds__(256) __attribute__((amdgpu_waves_per_eu(2,2))) void dgm_sg(DGM_PARAMS){
    __shared__ float lds[L_TOT_SG];
    dgm_body<1>(lds, DGM_ARGS);
}
__global__ __launch_bounds__(256) __attribute__((amdgpu_waves_per_eu(2,2))) void dgm_rc(DGM_PARAMS){
    __shared__ float lds[L_TOT_RC];
    dgm_body<0>(lds, DGM_ARGS);
}

__global__ void finalize_k(const float* __restrict__ inputs, const float* __restrict__ eps,
    const float* __restrict__ Lm, const float* __restrict__ fp1, const float* __restrict__ val1,
    const float* __restrict__ val2, const float* __restrict__ t12acc, float* __restrict__ out)
{
    int n = blockIdx.x*256 + threadIdx.x;
    if (n >= NN) return;
    float fp[DD];
    #pragma unroll
    for (int k = 0; k < DD; k++) fp[k] = fp1[n*DD + k];
    float t11 = fp[DIMN];
    #pragma unroll
    for (int k = 0; k < DIMN; k++) t11 = fmaf(MUC*inputs[n*DD + k], fp[k], t11);
    float esum[DIMN];
    #pragma unroll
    for (int d = 0; d < DIMN; d++){
        float a = 0.f;
        for (int m = 0; m < MCN; m++) a += eps[(size_t)(m*NN + n)*DIMN + d];
        esum[d] = a;
    }
    float t12b = 0.f;
    #pragma unroll
    for (int k = 0; k < DIMN; k++){
        float loc = inputs[n*DD + k];
        float ssum = (float)MCN * loc;
        #pragma unroll
        for (int d = 0; d < DIMN; d++) ssum = fmaf(esum[d], Lm[k*DIMN + d], ssum);
        float vsum = ssum * (SIGC*loc);
        t12b = fmaf(fp[k], vsum, t12b);
    }
    float term12 = (t12acc[n] - t12b) * (1.0f/(DELTAC*(float)MCN));
    out[n] = t11 + 0.5f*term12 - RC*val1[n];

    float prod = 1.f;
    #pragma unroll
    for (int k = 0; k < DIMN; k++) prod *= inputs[(NN + n)*DD + k];
    float payoff = powf(prod, 1.0f/(float)DIMN);
    if (!(payoff > 0.f)) payoff = 0.f;
    out[NN + n] = val2[n] - payoff;
}

extern "C" void kernel_launch(void* const* d_in, const int* in_sizes, int n_in,
                              void* d_out, int out_size, void* d_ws, size_t ws_size,
                              hipStream_t stream)
{
    const float* inputs = (const float*)d_in[0];
    const float* eps    = (const float*)d_in[1];
    const float* w1     = (const float*)d_in[2];
    const float* b1     = (const float*)d_in[3];
    const float* uz     = (const float*)d_in[4];
    const float* wz     = (const float*)d_in[5];
    const float* bz     = (const float*)d_in[6];
    const float* ug     = (const float*)d_in[7];
    const float* wg     = (const float*)d_in[8];
    const float* bg     = (const float*)d_in[9];
    const float* urr    = (const float*)d_in[10];
    const float* wr     = (const float*)d_in[11];
    const float* br     = (const float*)d_in[12];
    const float* uh     = (const float*)d_in[13];
    const float* wh     = (const float*)d_in[14];
    const float* bh     = (const float*)d_in[15];
    const float* wv     = (const float*)d_in[16];
    const float* bv     = (const float*)d_in[17];

    float* ws    = (float*)d_ws;
    float* Lm    = ws + OFF_L;
    float* WT    = ws + OFF_WT;
    float* Uzgr  = ws + OFF_UZGR;
    float* Wzgr  = ws + OFF_WZGR;
    float* fp1   = ws + OFF_FP1;
    float* val1  = ws + OFF_VAL1;
    float* val2  = ws + OFF_VAL2;
    float* t12   = ws + OFF_T12;
    float* gates = ws + OFF_GATES;
    float* out   = (float*)d_out;

    hipMemsetAsync(t12, 0, NN*sizeof(float), stream);
    hipLaunchKernelGGL(chol_kernel, dim3(1), dim3(64), 0, stream, Lm);
    hipLaunchKernelGGL(transpose_k, dim3(256), dim3(256), 0, stream, wz, wg, wr, wh, WT);
    hipLaunchKernelGGL(pack_zgr, dim3(224), dim3(256), 0, stream, uz, ug, urr, wz, wg, wr, Uzgr, Wzgr);

    size_t need_bytes = ((size_t)OFF_GATES + (size_t)NBLK * (size_t)GB_STRIDE) * sizeof(float);
    if (ws_size >= need_bytes){
        hipLaunchKernelGGL(dgm_sg, dim3(NBLK), dim3(256), 0, stream,
            inputs, eps, w1, b1, uz, bz, ug, bg, urr, br, uh, wh, bh, wv, bv,
            Lm, WT, Uzgr, Wzgr, gates, fp1, val1, val2, t12);
    } else {
        hipLaunchKernelGGL(dgm_rc, dim3(NBLK), dim3(256), 0, stream,
            inputs, eps, w1, b1, uz, bz, ug, bg, urr, br, uh, wh, bh, wv, bv,
            Lm, WT, Uzgr, Wzgr, gates, fp1, val1, val2, t12);
    }
    hipLaunchKernelGGL(finalize_k, dim3(8), dim3(256), 0, stream,
        inputs, eps, Lm, fp1, val1, val2, t12, out);
}

// Round 13
// 1229.513 us; speedup vs baseline: 5.7209x; 1.0162x over previous
//
#include <hip/hip_runtime.h>
#include <math.h>

#define DIMN 20
#define DD 21
#define NN 2048
#define MCN 32
#define UNITS 128
#define SIGC 0.2f
#define MUC 0.05f
#define RC 0.05f
#define DELTAC 0.01f

#define TM 32
#define PTOT (NN + MCN*NN + NN)
#define NBLK (PTOT/TM)

// ws layout (floats)
#define OFF_L 0
#define OFF_WT 512
#define OFF_UZGR (OFF_WT + 4*16384)      // 66048 : packed [Uz|Ug|Ur] 21x384 (pad to 8192)
#define OFF_WZGR (OFF_UZGR + 8192)       // 74240 : packed [Wz|Wg|Wr] 128x384
#define OFF_FP1  (OFF_WZGR + 49152)      // 123392
#define OFF_VAL1 (OFF_FP1 + NN*DD)       // 166400
#define OFF_VAL2 (OFF_VAL1 + NN)         // 168448
#define OFF_T12  (OFF_VAL2 + NN)         // 170496
#define OFF_GATES (OFF_T12 + NN)         // 172544 : per-block stash

// per-block stash (floats), per-thread-linear layout; h recovered, not stashed
#define ST_S1 0
#define ST_Z1 4096
#define ST_G1 8192
#define ST_R1 12288
#define ST_Z2 16384
#define ST_G2 20480
#define ST_R2 24576
#define GB_STRIDE 28672     // total stash = (172544 + 2176*28672)*4 B = 250.3 MB

// LDS layouts (floats); Db2 for merged z+g backward pass
// SG: S0 0 | S2 4096 | Db 8192 | Db2 12288 | xT 16384 | Vb 17056 | tot 17728 (70.9KB -> 2 blk/CU)
// RC: S0 0 | S1 4096 | S2 8192 | Db 12288 | Db2 16384 | xT 20480 | Vb 21152 | tot 21824 (87.3KB -> 1)
#define L_TOT_SG 17728
#define L_TOT_RC 21824

#define ELT44(...) _Pragma("unroll") for (int p = 0; p < 4; p++){ _Pragma("unroll") for (int jj = 0; jj < 4; jj++){ __VA_ARGS__; } }

__device__ __forceinline__ int offq(int row, int p0){
    return row*32 + ((p0 + 4*(row&7)) & 31);
}
__device__ __forceinline__ int offs(int row, int p){
    return row*32 + (((p & 28) + 4*(row&7)) & 31) + (p & 3);
}

// fast tanh: 1 - 2/(e^{2x}+1), clamp to +-9, ~6 VALU vs ~25 libm
__device__ __forceinline__ float ftanh(float x){
    float cx = fminf(9.f, fmaxf(-9.f, x));
    float e  = __expf(2.f*cx);
    return fmaf(-2.f, __builtin_amdgcn_rcpf(e + 1.f), 1.f);
}

#define FMA16(acc, s4, w4) \
  acc[0][0]=fmaf(s4.x,w4.x,acc[0][0]); acc[0][1]=fmaf(s4.x,w4.y,acc[0][1]); \
  acc[0][2]=fmaf(s4.x,w4.z,acc[0][2]); acc[0][3]=fmaf(s4.x,w4.w,acc[0][3]); \
  acc[1][0]=fmaf(s4.y,w4.x,acc[1][0]); acc[1][1]=fmaf(s4.y,w4.y,acc[1][1]); \
  acc[1][2]=fmaf(s4.y,w4.z,acc[1][2]); acc[1][3]=fmaf(s4.y,w4.w,acc[1][3]); \
  acc[2][0]=fmaf(s4.z,w4.x,acc[2][0]); acc[2][1]=fmaf(s4.z,w4.y,acc[2][1]); \
  acc[2][2]=fmaf(s4.z,w4.z,acc[2][2]); acc[2][3]=fmaf(s4.z,w4.w,acc[2][3]); \
  acc[3][0]=fmaf(s4.w,w4.x,acc[3][0]); acc[3][1]=fmaf(s4.w,w4.y,acc[3][1]); \
  acc[3][2]=fmaf(s4.w,w4.z,acc[3][2]); acc[3][3]=fmaf(s4.w,w4.w,acc[3][3]);

// direct-global matmul over 128-wide W rows; L2-hot weights; NO barriers.
// unroll 8 + setprio(1): amortize ~200cyc L2 latency; pre-empt the other
// block's load-issuing waves while in the FMA cluster.
__device__ __forceinline__ void mm_d(const float* __restrict__ gW, int K,
    const float* __restrict__ vec, float acc[4][4], int jg, int p0)
{
    const float* wp = gW + 4*jg;
    __builtin_amdgcn_s_setprio(1);
    #pragma unroll 8
    for (int k = 0; k < K; k++){
        float4 w4 = *(const float4*)(wp + k*UNITS);
        float4 s4 = *(const float4*)(vec + offq(k, p0));
        FMA16(acc, s4, w4)
    }
    __builtin_amdgcn_s_setprio(0);
}
// fused pair: two independent weight+LDS streams in one loop -> 2x MLP
__device__ __forceinline__ void mm2_d(const float* __restrict__ gWa, const float* __restrict__ gWb,
    int K, const float* __restrict__ vecA, const float* __restrict__ vecB,
    float acc[4][4], int jg, int p0)
{
    const float* wpa = gWa + 4*jg;
    const float* wpb = gWb + 4*jg;
    __builtin_amdgcn_s_setprio(1);
    #pragma unroll 4
    for (int k = 0; k < K; k++){
        float4 wa = *(const float4*)(wpa + k*UNITS);
        float4 sa = *(const float4*)(vecA + offq(k, p0));
        float4 wb = *(const float4*)(wpb + k*UNITS);
        float4 sb = *(const float4*)(vecB + offq(k, p0));
        FMA16(acc, sa, wa)
        FMA16(acc, sb, wb)
    }
    __builtin_amdgcn_s_setprio(0);
}
// 384-packed rows ([z|g|r]); one s4 feeds 48 FMAs; NO barriers.
__device__ __forceinline__ void mm3_d(const float* __restrict__ gW, int K,
    const float* __restrict__ vec, float a0[4][4], float a1[4][4], float a2[4][4],
    int jg, int p0)
{
    const float* wp = gW + 4*jg;
    __builtin_amdgcn_s_setprio(1);
    #pragma unroll 4
    for (int k = 0; k < K; k++){
        const float* r = wp + k*384;
        float4 s4 = *(const float4*)(vec + offq(k, p0));
        float4 w0 = *(const float4*)(r);
        float4 w1v = *(const float4*)(r + 128);
        float4 w2 = *(const float4*)(r + 256);
        FMA16(a0, s4, w0) FMA16(a1, s4, w1v) FMA16(a2, s4, w2)
    }
    __builtin_amdgcn_s_setprio(0);
}

__device__ __forceinline__ void write_own(float* buf, const float v[4][4], int j0, int p0){
    #pragma unroll
    for (int jj = 0; jj < 4; jj++){
        int j = j0 + jj;
        float4 q = make_float4(v[0][jj], v[1][jj], v[2][jj], v[3][jj]);
        *(float4*)(buf + offq(j, p0)) = q;
    }
}
__device__ __forceinline__ void read_own(const float* buf, float v[4][4], int j0, int p0){
    #pragma unroll
    for (int jj = 0; jj < 4; jj++){
        int j = j0 + jj;
        float4 q = *(const float4*)(buf + offq(j, p0));
        v[0][jj]=q.x; v[1][jj]=q.y; v[2][jj]=q.z; v[3][jj]=q.w;
    }
}
// per-thread-linear global stash (coalesced; only same thread reads back)
__device__ __forceinline__ void stash_w(float* buf, const float v[4][4], int t){
    #pragma unroll
    for (int jj = 0; jj < 4; jj++)
        *(float4*)(buf + (jj*256 + t)*4) = make_float4(v[0][jj], v[1][jj], v[2][jj], v[3][jj]);
}
__device__ __forceinline__ void stash_r(const float* buf, float v[4][4], int t){
    #pragma unroll
    for (int jj = 0; jj < 4; jj++){
        float4 q = *(const float4*)(buf + (jj*256 + t)*4);
        v[0][jj]=q.x; v[1][jj]=q.y; v[2][jj]=q.z; v[3][jj]=q.w;
    }
}

// out = tanh(bias + x@U + vec@W)  (h gate); all weights direct-global
__device__ __forceinline__ void gate_f(const float* __restrict__ U, const float* __restrict__ W,
    const float* __restrict__ bias, const float* __restrict__ xT, const float* __restrict__ Sin,
    float out[4][4], int jg, int p0, int j0)
{
    float acc[4][4];
    float4 b = *(const float4*)(bias + j0);
    #pragma unroll
    for (int p = 0; p < 4; p++){ acc[p][0]=b.x; acc[p][1]=b.y; acc[p][2]=b.z; acc[p][3]=b.w; }
    mm_d(U, DD, xT, acc, jg, p0);
    mm_d(W, UNITS, Sin, acc, jg, p0);
    #pragma unroll
    for (int p = 0; p < 4; p++)
        #pragma unroll
        for (int jj = 0; jj < 4; jj++) out[p][jj] = ftanh(acc[p][jj]);
}

// fused z,g,r gates; all weights direct-global; NO internal barriers
__device__ __forceinline__ void gate3_f(const float* __restrict__ Uzgr, const float* __restrict__ Wzgr,
    const float* __restrict__ bz, const float* __restrict__ bg, const float* __restrict__ br,
    const float* __restrict__ xT, const float* __restrict__ Sin,
    float zt[4][4], float gt[4][4], float rt[4][4],
    int jg, int p0, int j0)
{
    float4 b0 = *(const float4*)(bz + j0);
    float4 b1 = *(const float4*)(bg + j0);
    float4 b2 = *(const float4*)(br + j0);
    #pragma unroll
    for (int p = 0; p < 4; p++){
        zt[p][0]=b0.x; zt[p][1]=b0.y; zt[p][2]=b0.z; zt[p][3]=b0.w;
        gt[p][0]=b1.x; gt[p][1]=b1.y; gt[p][2]=b1.z; gt[p][3]=b1.w;
        rt[p][0]=b2.x; rt[p][1]=b2.y; rt[p][2]=b2.z; rt[p][3]=b2.w;
    }
    mm3_d(Uzgr, DD, xT, zt, gt, rt, jg, p0);
    mm3_d(Wzgr, UNITS, Sin, zt, gt, rt, jg, p0);
    ELT44(zt[p][jj]=ftanh(zt[p][jj]); gt[p][jj]=ftanh(gt[p][jj]); rt[p][jj]=ftanh(rt[p][jj]))
}

// closed-form Cholesky of DELTA*((1-RHO)I + RHO*J): equicorrelated structure.
__global__ void chol_kernel(float* __restrict__ Lout)
{
    if (threadIdx.x == 0 && blockIdx.x == 0) {
        const double beta = 0.01 * 0.5;          // off-diagonal
        const double diag = 0.01;                // alpha + beta
        double c[DIMN], d[DIMN];
        double S = 0.0;
        for (int j = 0; j < DIMN; j++){
            double dj = sqrt(diag - S);
            double cj = (beta - S) / dj;
            d[j] = dj; c[j] = cj;
            S += cj*cj;
        }
        for (int i = 0; i < DIMN; i++)
            for (int j = 0; j < DIMN; j++)
                Lout[i*DIMN + j] = (j < i) ? (float)c[j] : (j == i) ? (float)d[i] : 0.0f;
    }
}

__global__ void transpose_k(const float* __restrict__ wz, const float* __restrict__ wg,
                            const float* __restrict__ wr, const float* __restrict__ wh,
                            float* __restrict__ WT)
{
    int idx = blockIdx.x*256 + threadIdx.x;           // 0..65535
    int q = idx >> 14, r2 = idx & 16383, k = r2 >> 7, j = r2 & 127;
    const float* src = (q==0)? wz : (q==1)? wg : (q==2)? wr : wh;
    WT[(q<<14) + j*UNITS + k] = src[k*UNITS + j];
}

// pack [Uz|Ug|Ur] 21x384 and [Wz|Wg|Wr] 128x384
__global__ void pack_zgr(const float* __restrict__ uz, const float* __restrict__ ug,
                         const float* __restrict__ ur,
                         const float* __restrict__ wz, const float* __restrict__ wg,
                         const float* __restrict__ wr,
                         float* __restrict__ Uzgr, float* __restrict__ Wzgr)
{
    int idx = blockIdx.x*256 + threadIdx.x;
    if (idx < 128*384){
        int k = idx/384, c = idx - k*384, g = c >> 7, j = c & 127;
        const float* s = (g==0)? wz : (g==1)? wg : wr;
        Wzgr[idx] = s[k*UNITS + j];
        return;
    }
    int i2 = idx - 128*384;
    if (i2 < 21*384){
        int k = i2/384, c = i2 - k*384, g = c >> 7, j = c & 127;
        const float* s = (g==0)? uz : (g==1)? ug : ur;
        Uzgr[i2] = s[k*UNITS + j];
    }
}

#define DGM_PARAMS \
    const float* __restrict__ inputs, const float* __restrict__ eps, \
    const float* __restrict__ w1, const float* __restrict__ b1, \
    const float* __restrict__ uz, const float* __restrict__ bz, \
    const float* __restrict__ ug, const float* __restrict__ bg, \
    const float* __restrict__ ur, const float* __restrict__ br, \
    const float* __restrict__ uh, const float* __restrict__ wh, const float* __restrict__ bh, \
    const float* __restrict__ wv, const float* __restrict__ bv, \
    const float* __restrict__ Lm, const float* __restrict__ WT, \
    const float* __restrict__ Uzgr, const float* __restrict__ Wzgr, \
    float* __restrict__ gws, \
    float* __restrict__ fp1, float* __restrict__ val1, float* __restrict__ val2, \
    float* __restrict__ t12acc

#define DGM_ARGS inputs, eps, w1, b1, uz, bz, ug, bg, ur, br, uh, wh, bh, wv, bv, \
    Lm, WT, Uzgr, Wzgr, gws, fp1, val1, val2, t12acc

template<int SG>
__device__ __forceinline__ void dgm_body(float* lds, DGM_PARAMS)
{
    float* S0  = lds;
    float* S1  = SG ? lds : lds + 4096;               // RC only
    float* S2  = lds + (SG ? 4096 : 8192);
    float* Db  = lds + (SG ? 8192 : 12288);
    float* Db2 = lds + (SG ? 12288 : 16384);
    float* xT  = lds + (SG ? 16384 : 20480);
    float* Vb  = lds + (SG ? 17056 : 21152);

    const int t  = threadIdx.x;
    const int jg = t & 31;
    const int pg = t >> 5;
    const int p0 = pg * 4;
    const int j0 = jg * 4;
    const int P0 = blockIdx.x * TM;
    const int type = (P0 < NN) ? 0 : (P0 < NN + MCN*NN) ? 1 : 2;
    int base_n = 0, mrow = 0;
    if (type == 1){ int q = P0 - NN; mrow = q >> 11; base_n = q & (NN-1); }

    float* gb = gws + (size_t)blockIdx.x * GB_STRIDE;

    // ---- build x tile (and violation V for type 1) ----
    {
        int p = t & 31, kq = t >> 5;
        for (int ki = 0; ki < 3; ki++){
            int k = kq + 8*ki;
            if (k > DIMN) break;
            float xv;
            if (type == 0){
                xv = inputs[(P0 + p)*DD + k];
            } else if (type == 2){
                xv = inputs[(NN + (P0 - NN - MCN*NN) + p)*DD + k];
            } else {
                int n = base_n + p;
                float x1v = inputs[n*DD + k];
                if (k == DIMN) xv = x1v;
                else {
                    const float* ep = eps + (size_t)(mrow*NN + n)*DIMN;
                    float a = x1v;
                    for (int d = 0; d < DIMN; d++) a = fmaf(ep[d], Lm[k*DIMN + d], a);
                    float viol = a * (SIGC * x1v);
                    Vb[offs(k, p)] = viol;
                    xv = x1v + viol;
                }
            }
            xT[offs(k, p)] = xv;
        }
    }
    __syncthreads();

    // ---- forward ----
    float s_own[4][4];
    {
        float acc[4][4];
        float4 b = *(const float4*)(b1 + j0);
        #pragma unroll
        for (int p = 0; p < 4; p++){ acc[p][0]=b.x; acc[p][1]=b.y; acc[p][2]=b.z; acc[p][3]=b.w; }
        mm_d(w1, DD, xT, acc, jg, p0);
        ELT44(s_own[p][jj] = ftanh(acc[p][jj]))
        write_own(S0, s_own, j0, p0);
        __syncthreads();
    }

    float zt[4][4], gt[4][4], rt[4][4], ht[4][4];

#define GATES(SIN, SMUL) \
    gate3_f(Uzgr, Wzgr, bz, bg, br, xT, SIN, zt, gt, rt, jg, p0, j0); \
    __syncthreads(); \
    { float tt[4][4]; ELT44(tt[p][jj] = SMUL[p][jj]*rt[p][jj]) write_own(Db, tt, j0, p0); } \
    __syncthreads(); \
    gate_f(uh, wh, bh, xT, Db, ht, jg, p0, j0);

#define FWD_LAYER(SIN) \
    GATES(SIN, s_own) \
    ELT44(s_own[p][jj] = (1.f - gt[p][jj])*ht[p][jj] + zt[p][jj]*s_own[p][jj])

    FWD_LAYER(S0)                      // layer 1
    if (SG){ if (type != 2){
        stash_w(gb + ST_S1, s_own, t);
        stash_w(gb + ST_Z1, zt, t); stash_w(gb + ST_G1, gt, t); stash_w(gb + ST_R1, rt, t);
    } }
    else   { write_own(S1, s_own, j0, p0); }
    __syncthreads();                   // layer-1 gate_f's Db readers done
    write_own(Db, s_own, j0, p0);      // Sin for layer 2
    __syncthreads();

    FWD_LAYER(Db)                      // layer 2
    if (SG && type != 2){
        stash_w(gb + ST_Z2, zt, t); stash_w(gb + ST_G2, gt, t); stash_w(gb + ST_R2, rt, t);
    }
    write_own(S2, s_own, j0, p0);      // s2 in LDS for backward
    __syncthreads();

    FWD_LAYER(S2)                      // layer 3 -- zt/gt/rt/ht stay live into backward

    // ---- value head ----
    {
        float4 wv4 = *(const float4*)(wv + j0);
        float vs[4];
        #pragma unroll
        for (int p = 0; p < 4; p++)
            vs[p] = s_own[p][0]*wv4.x + s_own[p][1]*wv4.y + s_own[p][2]*wv4.z + s_own[p][3]*wv4.w;
        __syncthreads();   // layer-3 gate_f's Db readers done
        *(float4*)(Db + jg*32 + p0) = make_float4(vs[0], vs[1], vs[2], vs[3]);
        __syncthreads();
        if (t < TM){
            float v = bv[0];
            for (int j2 = 0; j2 < 32; j2++) v += Db[j2*32 + t];
            if (type == 0) val1[P0 + t] = v;
            else if (type == 2) val2[P0 + t - NN - MCN*NN] = v;
        }
        __syncthreads();
    }
    if (type == 2) return;

    // ---- backward ----
    float ds[4][4];
    {
        float4 wv4 = *(const float4*)(wv + j0);
        #pragma unroll
        for (int p = 0; p < 4; p++){ ds[p][0]=wv4.x; ds[p][1]=wv4.y; ds[p][2]=wv4.z; ds[p][3]=wv4.w; }
    }
    float proj[4] = {0.f, 0.f, 0.f, 0.f};
    float dxp[3] = {0.f, 0.f, 0.f};
    const int pi = t >> 3, il = t & 7;

    const float* WTz = WT;
    const float* WTg = WT + 16384;
    const float* WTr = WT + 2*16384;
    const float* WTh = WT + 3*16384;

#define DX_DOT(UMAT, BUF) \
    { _Pragma("unroll") for (int ii = 0; ii < 3; ii++){ \
        int i = il + 8*ii; \
        if (i < DD){ \
            const float* Urow = UMAT + i*UNITS; \
            float a = 0.f; \
            for (int j2 = 0; j2 < UNITS; j2++) a = fmaf(BUF[offs(j2, pi)], Urow[j2], a); \
            dxp[ii] += a; \
        } } }

// K=20 direct-global U pass; reads only own Vb/SEL; no barriers
#define PROJ_D(UMAT, SEL) \
    { float uv[4][4]; \
      ELT44(uv[p][jj] = 0.f) \
      mm_d(UMAT, DIMN, Vb, uv, jg, p0); \
      ELT44(proj[p] += uv[p][jj]*SEL[p][jj]) }

// Backward layer: merged z+g pass (dzp->Db, dgp->Db2, one sync pair, fused
// interleaved WTz/WTg matmul -> 2x MLP), then h, then r.
// MODE 0: sl=S2(LDS), gates live in regs (layer 3)
// MODE 1: recompute gates from SLP (RC fallback)
// MODE 2: sl=stash S1, z/g/r stash, h=(S2_lds - z*sl)/(1-g)   (SG layer 2)
// MODE 3: sl=SLP(LDS), z/g/r stash, h=(stash S1 - z*sl)/(1-g) (SG layer 1)
#define BWD_LAYER(SLP, MODE, GZ, GG, GR) \
    { \
    float dsn[4][4], dhp[4][4]; \
    if (MODE == 1){ \
        float slg[4][4]; read_own(SLP, slg, j0, p0); \
        GATES(SLP, slg) \
    } \
    { /* merged z+g (+h prep): all deltas computable upfront */ \
        float sl[4][4], zv[4][4], gv[4][4], hv[4][4]; \
        if (MODE == 2){ stash_r(gb + ST_S1, sl, t); stash_r(gb + GZ, zv, t); stash_r(gb + GG, gv, t); } \
        else if (MODE == 3){ read_own(SLP, sl, j0, p0); stash_r(gb + GZ, zv, t); stash_r(gb + GG, gv, t); } \
        else if (MODE == 0){ read_own(S2, sl, j0, p0); ELT44(zv[p][jj]=zt[p][jj]; gv[p][jj]=gt[p][jj]; hv[p][jj]=ht[p][jj]) } \
        else { read_own(SLP, sl, j0, p0); ELT44(zv[p][jj]=zt[p][jj]; gv[p][jj]=gt[p][jj]; hv[p][jj]=ht[p][jj]) } \
        if (MODE == 2 || MODE == 3){ \
            float sn[4][4]; \
            if (MODE == 2){ read_own(S2, sn, j0, p0); } \
            else { stash_r(gb + ST_S1, sn, t); } \
            ELT44(hv[p][jj] = (sn[p][jj] - zv[p][jj]*sl[p][jj]) / (1.f - gv[p][jj])) \
        } \
        float dzp[4][4], dgp[4][4]; \
        ELT44(float d=ds[p][jj]; float zz=zv[p][jj]; \
            dzp[p][jj] = d*sl[p][jj]*(1.f - zz*zz); dsn[p][jj] = d*zz) \
        ELT44(float d=ds[p][jj]; float gg=gv[p][jj]; float hh=hv[p][jj]; \
            dgp[p][jj] = -d*hh*(1.f - gg*gg); \
            dhp[p][jj] = d*(1.f - gg)*(1.f - hh*hh)) \
        __syncthreads(); \
        write_own(Db,  dzp, j0, p0); \
        write_own(Db2, dgp, j0, p0); \
        __syncthreads(); \
        if (type == 1){ PROJ_D(uz, dzp) PROJ_D(ug, dgp) } \
        else { DX_DOT(uz, Db) DX_DOT(ug, Db2) } \
    } \
    mm2_d(WTz, WTg, UNITS, Db, Db2, dsn, jg, p0); \
    /* h pass */ \
    __syncthreads(); \
    write_own(Db, dhp, j0, p0); \
    __syncthreads(); \
    if (type == 1){ PROJ_D(uh, dhp) } else { DX_DOT(uh, Db) } \
    float dsr[4][4]; \
    ELT44(dsr[p][jj] = 0.f) \
    mm_d(WTh, UNITS, Db, dsr, jg, p0); \
    { /* r pass */ \
        float rv[4][4], sl[4][4], drp[4][4]; \
        if (MODE == 2){ stash_r(gb + GR, rv, t); stash_r(gb + ST_S1, sl, t); } \
        else if (MODE == 3){ stash_r(gb + GR, rv, t); read_own(SLP, sl, j0, p0); } \
        else if (MODE == 0){ ELT44(rv[p][jj] = rt[p][jj]) read_own(S2, sl, j0, p0); } \
        else { ELT44(rv[p][jj] = rt[p][jj]) read_own(SLP, sl, j0, p0); } \
        ELT44(float dr=dsr[p][jj]; float rr=rv[p][jj]; \
            drp[p][jj] = dr*sl[p][jj]*(1.f - rr*rr); dsn[p][jj] += dr*rr) \
        __syncthreads(); \
        write_own(Db, drp, j0, p0); \
        __syncthreads(); \
        if (type == 1){ PROJ_D(ur, drp) } else { DX_DOT(ur, Db) } \
    } \
    mm_d(WTr, UNITS, Db, dsn, jg, p0); \
    ELT44(ds[p][jj] = dsn[p][jj]) \
    }

    BWD_LAYER(S0, 0, ST_Z2, ST_G2, ST_R2)                  // layer 3: gates live
    BWD_LAYER(S1, (SG ? 2 : 1), ST_Z2, ST_G2, ST_R2)       // layer 2
    if (SG){ BWD_LAYER(S0, 3, ST_Z1, ST_G1, ST_R1) }       // layer 1 (stash)
    else   { BWD_LAYER(S0, 1, ST_Z1, ST_G1, ST_R1) }       // layer 1 (recompute)

    // first-layer backward + epilogue
    {
        float s0l[4][4];
        read_own(S0, s0l, j0, p0);
        float v0[4][4];
        ELT44(v0[p][jj] = ds[p][jj]*(1.f - s0l[p][jj]*s0l[p][jj]))

        if (type == 1){
            PROJ_D(w1, v0)
            __syncthreads();   // last mm_d's Db readers done
            *(float4*)(Db + jg*32 + p0) = make_float4(proj[0], proj[1], proj[2], proj[3]);
            __syncthreads();
            if (t < TM){
                float s = 0.f;
                for (int j2 = 0; j2 < 32; j2++) s += Db[j2*32 + t];
                atomicAdd(t12acc + base_n + t, s);
            }
        } else {
            __syncthreads();   // last mm_d's Db readers done
            write_own(Db, v0, j0, p0);
            __syncthreads();
            DX_DOT(w1, Db)
            #pragma unroll
            for (int ii = 0; ii < 3; ii++){
                int i = il + 8*ii;
                if (i < DD) fp1[(P0 + pi)*DD + i] = dxp[ii];
            }
        }
    }
}

__global__ __launch_bounds__(256) __attribute__((amdgpu_waves_per_eu(2,2))) void dgm_sg(DGM_PARAMS){
    __shared__ float lds[L_TOT_SG];
    dgm_body<1>(lds, DGM_ARGS);
}
__global__ __launch_bounds__(256) __attribute__((amdgpu_waves_per_eu(2,2))) void dgm_rc(DGM_PARAMS){
    __shared__ float lds[L_TOT_RC];
    dgm_body<0>(lds, DGM_ARGS);
}

__global__ void finalize_k(const float* __restrict__ inputs, const float* __restrict__ eps,
    const float* __restrict__ Lm, const float* __restrict__ fp1, const float* __restrict__ val1,
    const float* __restrict__ val2, const float* __restrict__ t12acc, float* __restrict__ out)
{
    int n = blockIdx.x*256 + threadIdx.x;
    if (n >= NN) return;
    float fp[DD];
    #pragma unroll
    for (int k = 0; k < DD; k++) fp[k] = fp1[n*DD + k];
    float t11 = fp[DIMN];
    #pragma unroll
    for (int k = 0; k < DIMN; k++) t11 = fmaf(MUC*inputs[n*DD + k], fp[k], t11);
    float esum[DIMN];
    #pragma unroll
    for (int d = 0; d < DIMN; d++){
        float a = 0.f;
        for (int m = 0; m < MCN; m++) a += eps[(size_t)(m*NN + n)*DIMN + d];
        esum[d] = a;
    }
    float t12b = 0.f;
    #pragma unroll
    for (int k = 0; k < DIMN; k++){
        float loc = inputs[n*DD + k];
        float ssum = (float)MCN * loc;
        #pragma unroll
        for (int d = 0; d < DIMN; d++) ssum = fmaf(esum[d], Lm[k*DIMN + d], ssum);
        float vsum = ssum * (SIGC*loc);
        t12b = fmaf(fp[k], vsum, t12b);
    }
    float term12 = (t12acc[n] - t12b) * (1.0f/(DELTAC*(float)MCN));
    out[n] = t11 + 0.5f*term12 - RC*val1[n];

    float prod = 1.f;
    #pragma unroll
    for (int k = 0; k < DIMN; k++) prod *= inputs[(NN + n)*DD + k];
    float payoff = powf(prod, 1.0f/(float)DIMN);
    if (!(payoff > 0.f)) payoff = 0.f;
    out[NN + n] = val2[n] - payoff;
}

extern "C" void kernel_launch(void* const* d_in, const int* in_sizes, int n_in,
                              void* d_out, int out_size, void* d_ws, size_t ws_size,
                              hipStream_t stream)
{
    const float* inputs = (const float*)d_in[0];
    const float* eps    = (const float*)d_in[1];
    const float* w1     = (const float*)d_in[2];
    const float* b1     = (const float*)d_in[3];
    const float* uz     = (const float*)d_in[4];
    const float* wz     = (const float*)d_in[5];
    const float* bz     = (const float*)d_in[6];
    const float* ug     = (const float*)d_in[7];
    const float* wg     = (const float*)d_in[8];
    const float* bg     = (const float*)d_in[9];
    const float* urr    = (const float*)d_in[10];
    const float* wr     = (const float*)d_in[11];
    const float* br     = (const float*)d_in[12];
    const float* uh     = (const float*)d_in[13];
    const float* wh     = (const float*)d_in[14];
    const float* bh     = (const float*)d_in[15];
    const float* wv     = (const float*)d_in[16];
    const float* bv     = (const float*)d_in[17];

    float* ws    = (float*)d_ws;
    float* Lm    = ws + OFF_L;
    float* WT    = ws + OFF_WT;
    float* Uzgr  = ws + OFF_UZGR;
    float* Wzgr  = ws + OFF_WZGR;
    float* fp1   = ws + OFF_FP1;
    float* val1  = ws + OFF_VAL1;
    float* val2  = ws + OFF_VAL2;
    float* t12   = ws + OFF_T12;
    float* gates = ws + OFF_GATES;
    float* out   = (float*)d_out;

    hipMemsetAsync(t12, 0, NN*sizeof(float), stream);
    hipLaunchKernelGGL(chol_kernel, dim3(1), dim3(64), 0, stream, Lm);
    hipLaunchKernelGGL(transpose_k, dim3(256), dim3(256), 0, stream, wz, wg, wr, wh, WT);
    hipLaunchKernelGGL(pack_zgr, dim3(224), dim3(256), 0, stream, uz, ug, urr, wz, wg, wr, Uzgr, Wzgr);

    size_t need_bytes = ((size_t)OFF_GATES + (size_t)NBLK * (size_t)GB_STRIDE) * sizeof(float);
    if (ws_size >= need_bytes){
        hipLaunchKernelGGL(dgm_sg, dim3(NBLK), dim3(256), 0, stream,
            inputs, eps, w1, b1, uz, bz, ug, bg, urr, br, uh, wh, bh, wv, bv,
            Lm, WT, Uzgr, Wzgr, gates, fp1, val1, val2, t12);
    } else {
        hipLaunchKernelGGL(dgm_rc, dim3(NBLK), dim3(256), 0, stream,
            inputs, eps, w1, b1, uz, bz, ug, bg, urr, br, uh, wh, bh, wv, bv,
            Lm, WT, Uzgr, Wzgr, gates, fp1, val1, val2, t12);
    }
    hipLaunchKernelGGL(finalize_k, dim3(8), dim3(256), 0, stream,
        inputs, eps, Lm, fp1, val1, val2, t12, out);
}

// Round 14
// 1208.603 us; speedup vs baseline: 5.8199x; 1.0173x over previous
//
#include <hip/hip_runtime.h>
#include <math.h>

#define DIMN 20
#define DD 21
#define NN 2048
#define MCN 32
#define UNITS 128
#define SIGC 0.2f
#define MUC 0.05f
#define RC 0.05f
#define DELTAC 0.01f

#define TM 32
#define PTOT (NN + MCN*NN + NN)
#define NBLK (PTOT/TM)

// ws layout (floats)
#define OFF_L 0
#define OFF_WT 512
#define OFF_UZGR (OFF_WT + 4*16384)      // 66048 : packed [Uz|Ug|Ur] 21x384 (pad to 8192)
#define OFF_WZGR (OFF_UZGR + 8192)       // 74240 : packed [Wz|Wg|Wr] 128x384
#define OFF_FP1  (OFF_WZGR + 49152)      // 123392
#define OFF_VAL1 (OFF_FP1 + NN*DD)       // 166400
#define OFF_VAL2 (OFF_VAL1 + NN)         // 168448
#define OFF_T12  (OFF_VAL2 + NN)         // 170496
#define OFF_GATES (OFF_T12 + NN)         // 172544 : per-block stash

// per-block stash (floats), per-thread-linear layout; h recovered, not stashed
#define ST_S1 0
#define ST_Z1 4096
#define ST_G1 8192
#define ST_R1 12288
#define ST_Z2 16384
#define ST_G2 20480
#define ST_R2 24576
#define GB_STRIDE 28672     // total stash = (172544 + 2176*28672)*4 B = 250.3 MB

// LDS layouts (floats)
// SG: S0 0 | S2 4096 | Db 8192 | Db2 12288 | xT 16384 | Vb 17056 | tot 17728 (70.9KB -> 2 blk/CU)
//     backward: S0 doubles as Db3 (dhp); s0 recomputed from xT into S2 for layer 1.
// RC: S0 0 | S1 4096 | S2 8192 | Db 12288 | Db2 16384 | Db3 20480 | xT 24576 | Vb 25248
//     tot 25920 (103.7KB -> 1 blk/CU, fallback only)
#define L_TOT_SG 17728
#define L_TOT_RC 25920

#define ELT44(...) _Pragma("unroll") for (int p = 0; p < 4; p++){ _Pragma("unroll") for (int jj = 0; jj < 4; jj++){ __VA_ARGS__; } }

__device__ __forceinline__ int offq(int row, int p0){
    return row*32 + ((p0 + 4*(row&7)) & 31);
}
__device__ __forceinline__ int offs(int row, int p){
    return row*32 + (((p & 28) + 4*(row&7)) & 31) + (p & 3);
}

// fast tanh: 1 - 2/(e^{2x}+1), clamp to +-9, ~6 VALU vs ~25 libm
__device__ __forceinline__ float ftanh(float x){
    float cx = fminf(9.f, fmaxf(-9.f, x));
    float e  = __expf(2.f*cx);
    return fmaf(-2.f, __builtin_amdgcn_rcpf(e + 1.f), 1.f);
}

#define FMA16(acc, s4, w4) \
  acc[0][0]=fmaf(s4.x,w4.x,acc[0][0]); acc[0][1]=fmaf(s4.x,w4.y,acc[0][1]); \
  acc[0][2]=fmaf(s4.x,w4.z,acc[0][2]); acc[0][3]=fmaf(s4.x,w4.w,acc[0][3]); \
  acc[1][0]=fmaf(s4.y,w4.x,acc[1][0]); acc[1][1]=fmaf(s4.y,w4.y,acc[1][1]); \
  acc[1][2]=fmaf(s4.y,w4.z,acc[1][2]); acc[1][3]=fmaf(s4.y,w4.w,acc[1][3]); \
  acc[2][0]=fmaf(s4.z,w4.x,acc[2][0]); acc[2][1]=fmaf(s4.z,w4.y,acc[2][1]); \
  acc[2][2]=fmaf(s4.z,w4.z,acc[2][2]); acc[2][3]=fmaf(s4.z,w4.w,acc[2][3]); \
  acc[3][0]=fmaf(s4.w,w4.x,acc[3][0]); acc[3][1]=fmaf(s4.w,w4.y,acc[3][1]); \
  acc[3][2]=fmaf(s4.w,w4.z,acc[3][2]); acc[3][3]=fmaf(s4.w,w4.w,acc[3][3]);

// direct-global matmul over 128-wide W rows; L2-hot weights; NO barriers.
__device__ __forceinline__ void mm_d(const float* __restrict__ gW, int K,
    const float* __restrict__ vec, float acc[4][4], int jg, int p0)
{
    const float* wp = gW + 4*jg;
    __builtin_amdgcn_s_setprio(1);
    #pragma unroll 8
    for (int k = 0; k < K; k++){
        float4 w4 = *(const float4*)(wp + k*UNITS);
        float4 s4 = *(const float4*)(vec + offq(k, p0));
        FMA16(acc, s4, w4)
    }
    __builtin_amdgcn_s_setprio(0);
}
// fused triple: z+g streams accumulate into accAB, h stream into accC.
// 3 independent weight+LDS streams in one loop -> 3x MLP, one serial section.
__device__ __forceinline__ void mm3w_d(const float* __restrict__ gWa, const float* __restrict__ gWb,
    const float* __restrict__ gWc, int K,
    const float* __restrict__ vecA, const float* __restrict__ vecB, const float* __restrict__ vecC,
    float accAB[4][4], float accC[4][4], int jg, int p0)
{
    const float* wpa = gWa + 4*jg;
    const float* wpb = gWb + 4*jg;
    const float* wpc = gWc + 4*jg;
    __builtin_amdgcn_s_setprio(1);
    #pragma unroll 2
    for (int k = 0; k < K; k++){
        float4 wa = *(const float4*)(wpa + k*UNITS);
        float4 sa = *(const float4*)(vecA + offq(k, p0));
        float4 wb = *(const float4*)(wpb + k*UNITS);
        float4 sb = *(const float4*)(vecB + offq(k, p0));
        float4 wc = *(const float4*)(wpc + k*UNITS);
        float4 sc = *(const float4*)(vecC + offq(k, p0));
        FMA16(accAB, sa, wa)
        FMA16(accAB, sb, wb)
        FMA16(accC,  sc, wc)
    }
    __builtin_amdgcn_s_setprio(0);
}
// 384-packed rows ([z|g|r]); one s4 feeds 48 FMAs; NO barriers.
__device__ __forceinline__ void mm3_d(const float* __restrict__ gW, int K,
    const float* __restrict__ vec, float a0[4][4], float a1[4][4], float a2[4][4],
    int jg, int p0)
{
    const float* wp = gW + 4*jg;
    __builtin_amdgcn_s_setprio(1);
    #pragma unroll 4
    for (int k = 0; k < K; k++){
        const float* r = wp + k*384;
        float4 s4 = *(const float4*)(vec + offq(k, p0));
        float4 w0 = *(const float4*)(r);
        float4 w1v = *(const float4*)(r + 128);
        float4 w2 = *(const float4*)(r + 256);
        FMA16(a0, s4, w0) FMA16(a1, s4, w1v) FMA16(a2, s4, w2)
    }
    __builtin_amdgcn_s_setprio(0);
}

__device__ __forceinline__ void write_own(float* buf, const float v[4][4], int j0, int p0){
    #pragma unroll
    for (int jj = 0; jj < 4; jj++){
        int j = j0 + jj;
        float4 q = make_float4(v[0][jj], v[1][jj], v[2][jj], v[3][jj]);
        *(float4*)(buf + offq(j, p0)) = q;
    }
}
__device__ __forceinline__ void read_own(const float* buf, float v[4][4], int j0, int p0){
    #pragma unroll
    for (int jj = 0; jj < 4; jj++){
        int j = j0 + jj;
        float4 q = *(const float4*)(buf + offq(j, p0));
        v[0][jj]=q.x; v[1][jj]=q.y; v[2][jj]=q.z; v[3][jj]=q.w;
    }
}
// per-thread-linear global stash (coalesced; only same thread reads back)
__device__ __forceinline__ void stash_w(float* buf, const float v[4][4], int t){
    #pragma unroll
    for (int jj = 0; jj < 4; jj++)
        *(float4*)(buf + (jj*256 + t)*4) = make_float4(v[0][jj], v[1][jj], v[2][jj], v[3][jj]);
}
__device__ __forceinline__ void stash_r(const float* buf, float v[4][4], int t){
    #pragma unroll
    for (int jj = 0; jj < 4; jj++){
        float4 q = *(const float4*)(buf + (jj*256 + t)*4);
        v[0][jj]=q.x; v[1][jj]=q.y; v[2][jj]=q.z; v[3][jj]=q.w;
    }
}

// out = tanh(bias + x@U + vec@W)  (h gate); all weights direct-global
__device__ __forceinline__ void gate_f(const float* __restrict__ U, const float* __restrict__ W,
    const float* __restrict__ bias, const float* __restrict__ xT, const float* __restrict__ Sin,
    float out[4][4], int jg, int p0, int j0)
{
    float acc[4][4];
    float4 b = *(const float4*)(bias + j0);
    #pragma unroll
    for (int p = 0; p < 4; p++){ acc[p][0]=b.x; acc[p][1]=b.y; acc[p][2]=b.z; acc[p][3]=b.w; }
    mm_d(U, DD, xT, acc, jg, p0);
    mm_d(W, UNITS, Sin, acc, jg, p0);
    #pragma unroll
    for (int p = 0; p < 4; p++)
        #pragma unroll
        for (int jj = 0; jj < 4; jj++) out[p][jj] = ftanh(acc[p][jj]);
}

// fused z,g,r gates; all weights direct-global; NO internal barriers
__device__ __forceinline__ void gate3_f(const float* __restrict__ Uzgr, const float* __restrict__ Wzgr,
    const float* __restrict__ bz, const float* __restrict__ bg, const float* __restrict__ br,
    const float* __restrict__ xT, const float* __restrict__ Sin,
    float zt[4][4], float gt[4][4], float rt[4][4],
    int jg, int p0, int j0)
{
    float4 b0 = *(const float4*)(bz + j0);
    float4 b1 = *(const float4*)(bg + j0);
    float4 b2 = *(const float4*)(br + j0);
    #pragma unroll
    for (int p = 0; p < 4; p++){
        zt[p][0]=b0.x; zt[p][1]=b0.y; zt[p][2]=b0.z; zt[p][3]=b0.w;
        gt[p][0]=b1.x; gt[p][1]=b1.y; gt[p][2]=b1.z; gt[p][3]=b1.w;
        rt[p][0]=b2.x; rt[p][1]=b2.y; rt[p][2]=b2.z; rt[p][3]=b2.w;
    }
    mm3_d(Uzgr, DD, xT, zt, gt, rt, jg, p0);
    mm3_d(Wzgr, UNITS, Sin, zt, gt, rt, jg, p0);
    ELT44(zt[p][jj]=ftanh(zt[p][jj]); gt[p][jj]=ftanh(gt[p][jj]); rt[p][jj]=ftanh(rt[p][jj]))
}

// closed-form Cholesky of DELTA*((1-RHO)I + RHO*J): equicorrelated structure.
__global__ void chol_kernel(float* __restrict__ Lout)
{
    if (threadIdx.x == 0 && blockIdx.x == 0) {
        const double beta = 0.01 * 0.5;          // off-diagonal
        const double diag = 0.01;                // alpha + beta
        double c[DIMN], d[DIMN];
        double S = 0.0;
        for (int j = 0; j < DIMN; j++){
            double dj = sqrt(diag - S);
            double cj = (beta - S) / dj;
            d[j] = dj; c[j] = cj;
            S += cj*cj;
        }
        for (int i = 0; i < DIMN; i++)
            for (int j = 0; j < DIMN; j++)
                Lout[i*DIMN + j] = (j < i) ? (float)c[j] : (j == i) ? (float)d[i] : 0.0f;
    }
}

__global__ void transpose_k(const float* __restrict__ wz, const float* __restrict__ wg,
                            const float* __restrict__ wr, const float* __restrict__ wh,
                            float* __restrict__ WT)
{
    int idx = blockIdx.x*256 + threadIdx.x;           // 0..65535
    int q = idx >> 14, r2 = idx & 16383, k = r2 >> 7, j = r2 & 127;
    const float* src = (q==0)? wz : (q==1)? wg : (q==2)? wr : wh;
    WT[(q<<14) + j*UNITS + k] = src[k*UNITS + j];
}

// pack [Uz|Ug|Ur] 21x384 and [Wz|Wg|Wr] 128x384
__global__ void pack_zgr(const float* __restrict__ uz, const float* __restrict__ ug,
                         const float* __restrict__ ur,
                         const float* __restrict__ wz, const float* __restrict__ wg,
                         const float* __restrict__ wr,
                         float* __restrict__ Uzgr, float* __restrict__ Wzgr)
{
    int idx = blockIdx.x*256 + threadIdx.x;
    if (idx < 128*384){
        int k = idx/384, c = idx - k*384, g = c >> 7, j = c & 127;
        const float* s = (g==0)? wz : (g==1)? wg : wr;
        Wzgr[idx] = s[k*UNITS + j];
        return;
    }
    int i2 = idx - 128*384;
    if (i2 < 21*384){
        int k = i2/384, c = i2 - k*384, g = c >> 7, j = c & 127;
        const float* s = (g==0)? uz : (g==1)? ug : ur;
        Uzgr[i2] = s[k*UNITS + j];
    }
}

#define DGM_PARAMS \
    const float* __restrict__ inputs, const float* __restrict__ eps, \
    const float* __restrict__ w1, const float* __restrict__ b1, \
    const float* __restrict__ uz, const float* __restrict__ bz, \
    const float* __restrict__ ug, const float* __restrict__ bg, \
    const float* __restrict__ ur, const float* __restrict__ br, \
    const float* __restrict__ uh, const float* __restrict__ wh, const float* __restrict__ bh, \
    const float* __restrict__ wv, const float* __restrict__ bv, \
    const float* __restrict__ Lm, const float* __restrict__ WT, \
    const float* __restrict__ Uzgr, const float* __restrict__ Wzgr, \
    float* __restrict__ gws, \
    float* __restrict__ fp1, float* __restrict__ val1, float* __restrict__ val2, \
    float* __restrict__ t12acc

#define DGM_ARGS inputs, eps, w1, b1, uz, bz, ug, bg, ur, br, uh, wh, bh, wv, bv, \
    Lm, WT, Uzgr, Wzgr, gws, fp1, val1, val2, t12acc

template<int SG>
__device__ __forceinline__ void dgm_body(float* lds, DGM_PARAMS)
{
    float* S0  = lds;
    float* S1  = SG ? lds : lds + 4096;               // RC only
    float* S2  = lds + (SG ? 4096 : 8192);
    float* Db  = lds + (SG ? 8192 : 12288);
    float* Db2 = lds + (SG ? 12288 : 16384);
    float* Db3 = SG ? lds : lds + 20480;              // SG: aliases S0 (clobbered in bwd)
    float* xT  = lds + (SG ? 16384 : 24576);
    float* Vb  = lds + (SG ? 17056 : 25248);

    const int t  = threadIdx.x;
    const int jg = t & 31;
    const int pg = t >> 5;
    const int p0 = pg * 4;
    const int j0 = jg * 4;
    const int P0 = blockIdx.x * TM;
    const int type = (P0 < NN) ? 0 : (P0 < NN + MCN*NN) ? 1 : 2;
    int base_n = 0, mrow = 0;
    if (type == 1){ int q = P0 - NN; mrow = q >> 11; base_n = q & (NN-1); }

    float* gb = gws + (size_t)blockIdx.x * GB_STRIDE;

    // ---- build x tile (and violation V for type 1) ----
    {
        int p = t & 31, kq = t >> 5;
        for (int ki = 0; ki < 3; ki++){
            int k = kq + 8*ki;
            if (k > DIMN) break;
            float xv;
            if (type == 0){
                xv = inputs[(P0 + p)*DD + k];
            } else if (type == 2){
                xv = inputs[(NN + (P0 - NN - MCN*NN) + p)*DD + k];
            } else {
                int n = base_n + p;
                float x1v = inputs[n*DD + k];
                if (k == DIMN) xv = x1v;
                else {
                    const float* ep = eps + (size_t)(mrow*NN + n)*DIMN;
                    float a = x1v;
                    for (int d = 0; d < DIMN; d++) a = fmaf(ep[d], Lm[k*DIMN + d], a);
                    float viol = a * (SIGC * x1v);
                    Vb[offs(k, p)] = viol;
                    xv = x1v + viol;
                }
            }
            xT[offs(k, p)] = xv;
        }
    }
    __syncthreads();

    // ---- forward ----
    float s_own[4][4];
    {
        float acc[4][4];
        float4 b = *(const float4*)(b1 + j0);
        #pragma unroll
        for (int p = 0; p < 4; p++){ acc[p][0]=b.x; acc[p][1]=b.y; acc[p][2]=b.z; acc[p][3]=b.w; }
        mm_d(w1, DD, xT, acc, jg, p0);
        ELT44(s_own[p][jj] = ftanh(acc[p][jj]))
        write_own(S0, s_own, j0, p0);
        __syncthreads();
    }

    float zt[4][4], gt[4][4], rt[4][4], ht[4][4];

#define GATES(SIN, SMUL) \
    gate3_f(Uzgr, Wzgr, bz, bg, br, xT, SIN, zt, gt, rt, jg, p0, j0); \
    __syncthreads(); \
    { float tt[4][4]; ELT44(tt[p][jj] = SMUL[p][jj]*rt[p][jj]) write_own(Db, tt, j0, p0); } \
    __syncthreads(); \
    gate_f(uh, wh, bh, xT, Db, ht, jg, p0, j0);

#define FWD_LAYER(SIN) \
    GATES(SIN, s_own) \
    ELT44(s_own[p][jj] = (1.f - gt[p][jj])*ht[p][jj] + zt[p][jj]*s_own[p][jj])

    FWD_LAYER(S0)                      // layer 1
    if (SG){ if (type != 2){
        stash_w(gb + ST_S1, s_own, t);
        stash_w(gb + ST_Z1, zt, t); stash_w(gb + ST_G1, gt, t); stash_w(gb + ST_R1, rt, t);
    } }
    else   { write_own(S1, s_own, j0, p0); }
    __syncthreads();                   // layer-1 gate_f's Db readers done
    write_own(Db, s_own, j0, p0);      // Sin for layer 2
    __syncthreads();

    FWD_LAYER(Db)                      // layer 2
    if (SG && type != 2){
        stash_w(gb + ST_Z2, zt, t); stash_w(gb + ST_G2, gt, t); stash_w(gb + ST_R2, rt, t);
    }
    write_own(S2, s_own, j0, p0);      // s2 in LDS for backward
    __syncthreads();

    FWD_LAYER(S2)                      // layer 3 -- zt/gt/rt/ht stay live into backward

    // ---- value head ----
    {
        float4 wv4 = *(const float4*)(wv + j0);
        float vs[4];
        #pragma unroll
        for (int p = 0; p < 4; p++)
            vs[p] = s_own[p][0]*wv4.x + s_own[p][1]*wv4.y + s_own[p][2]*wv4.z + s_own[p][3]*wv4.w;
        __syncthreads();   // layer-3 gate_f's Db readers done
        *(float4*)(Db + jg*32 + p0) = make_float4(vs[0], vs[1], vs[2], vs[3]);
        __syncthreads();
        if (t < TM){
            float v = bv[0];
            for (int j2 = 0; j2 < 32; j2++) v += Db[j2*32 + t];
            if (type == 0) val1[P0 + t] = v;
            else if (type == 2) val2[P0 + t - NN - MCN*NN] = v;
        }
        __syncthreads();
    }
    if (type == 2) return;

    // ---- backward ----
    float ds[4][4];
    {
        float4 wv4 = *(const float4*)(wv + j0);
        #pragma unroll
        for (int p = 0; p < 4; p++){ ds[p][0]=wv4.x; ds[p][1]=wv4.y; ds[p][2]=wv4.z; ds[p][3]=wv4.w; }
    }
    float proj[4] = {0.f, 0.f, 0.f, 0.f};
    float dxp[3] = {0.f, 0.f, 0.f};
    const int pi = t >> 3, il = t & 7;

    const float* WTz = WT;
    const float* WTg = WT + 16384;
    const float* WTr = WT + 2*16384;
    const float* WTh = WT + 3*16384;

#define DX_DOT(UMAT, BUF) \
    { _Pragma("unroll") for (int ii = 0; ii < 3; ii++){ \
        int i = il + 8*ii; \
        if (i < DD){ \
            const float* Urow = UMAT + i*UNITS; \
            float a = 0.f; \
            for (int j2 = 0; j2 < UNITS; j2++) a = fmaf(BUF[offs(j2, pi)], Urow[j2], a); \
            dxp[ii] += a; \
        } } }

// K=20 direct-global U pass; reads only own Vb/SEL; no barriers
#define PROJ_D(UMAT, SEL) \
    { float uv[4][4]; \
      ELT44(uv[p][jj] = 0.f) \
      mm_d(UMAT, DIMN, Vb, uv, jg, p0); \
      ELT44(proj[p] += uv[p][jj]*SEL[p][jj]) }

// Backward layer: fused z+g+h pass (dzp->Db, dgp->Db2, dhp->Db3, one sync
// pair, 3-stream fused WTz/WTg/WTh matmul: dsn<-z,g; dsr<-h), then r pass.
// MODE 0: sl=S2(LDS), gates live in regs (layer 3)
// MODE 1: recompute gates from SLP (RC fallback)
// MODE 2: sl=stash S1, z/g/r stash, h=(S2_lds - z*sl)/(1-g)   (SG layer 2)
// MODE 3: sl=SLP(LDS, recomputed s0 in S2), z/g/r stash, h=(stash S1 - z*sl)/(1-g)
#define BWD_LAYER(SLP, MODE, GZ, GG, GR) \
    { \
    float dsn[4][4], dsr[4][4]; \
    if (MODE == 1){ \
        float slg[4][4]; read_own(SLP, slg, j0, p0); \
        GATES(SLP, slg) \
    } \
    { /* fused z+g+h pass */ \
        float sl[4][4], zv[4][4], gv[4][4], hv[4][4]; \
        if (MODE == 2){ stash_r(gb + ST_S1, sl, t); stash_r(gb + GZ, zv, t); stash_r(gb + GG, gv, t); } \
        else if (MODE == 3){ read_own(SLP, sl, j0, p0); stash_r(gb + GZ, zv, t); stash_r(gb + GG, gv, t); } \
        else if (MODE == 0){ read_own(S2, sl, j0, p0); ELT44(zv[p][jj]=zt[p][jj]; gv[p][jj]=gt[p][jj]; hv[p][jj]=ht[p][jj]) } \
        else { read_own(SLP, sl, j0, p0); ELT44(zv[p][jj]=zt[p][jj]; gv[p][jj]=gt[p][jj]; hv[p][jj]=ht[p][jj]) } \
        if (MODE == 2 || MODE == 3){ \
            float sn[4][4]; \
            if (MODE == 2){ read_own(S2, sn, j0, p0); } \
            else { stash_r(gb + ST_S1, sn, t); } \
            ELT44(hv[p][jj] = (sn[p][jj] - zv[p][jj]*sl[p][jj]) / (1.f - gv[p][jj])) \
        } \
        float dzp[4][4], dgp[4][4], dhp[4][4]; \
        ELT44(float d=ds[p][jj]; float zz=zv[p][jj]; \
            dzp[p][jj] = d*sl[p][jj]*(1.f - zz*zz); dsn[p][jj] = d*zz) \
        ELT44(float d=ds[p][jj]; float gg=gv[p][jj]; float hh=hv[p][jj]; \
            dgp[p][jj] = -d*hh*(1.f - gg*gg); \
            dhp[p][jj] = d*(1.f - gg)*(1.f - hh*hh)) \
        __syncthreads(); \
        write_own(Db,  dzp, j0, p0); \
        write_own(Db2, dgp, j0, p0); \
        write_own(Db3, dhp, j0, p0); \
        __syncthreads(); \
        if (type == 1){ PROJ_D(uz, dzp) PROJ_D(ug, dgp) PROJ_D(uh, dhp) } \
        else { DX_DOT(uz, Db) DX_DOT(ug, Db2) DX_DOT(uh, Db3) } \
        ELT44(dsr[p][jj] = 0.f) \
        mm3w_d(WTz, WTg, WTh, UNITS, Db, Db2, Db3, dsn, dsr, jg, p0); \
    } \
    { /* r pass */ \
        float rv[4][4], sl2[4][4], drp[4][4]; \
        if (MODE == 2){ stash_r(gb + GR, rv, t); stash_r(gb + ST_S1, sl2, t); } \
        else if (MODE == 3){ stash_r(gb + GR, rv, t); read_own(SLP, sl2, j0, p0); } \
        else if (MODE == 0){ ELT44(rv[p][jj] = rt[p][jj]) read_own(S2, sl2, j0, p0); } \
        else { ELT44(rv[p][jj] = rt[p][jj]) read_own(SLP, sl2, j0, p0); } \
        ELT44(float dr=dsr[p][jj]; float rr=rv[p][jj]; \
            drp[p][jj] = dr*sl2[p][jj]*(1.f - rr*rr); dsn[p][jj] += dr*rr) \
        __syncthreads(); \
        write_own(Db, drp, j0, p0); \
        __syncthreads(); \
        if (type == 1){ PROJ_D(ur, drp) } else { DX_DOT(ur, Db) } \
    } \
    mm_d(WTr, UNITS, Db, dsn, jg, p0); \
    ELT44(ds[p][jj] = dsn[p][jj]) \
    }

    BWD_LAYER(S2, 0, ST_Z2, ST_G2, ST_R2)                  // layer 3: gates live
    BWD_LAYER(S1, (SG ? 2 : 1), ST_Z2, ST_G2, ST_R2)       // layer 2
    if (SG){
        // recompute s0 = ftanh(b1 + x@w1) into S2 (dead after layer-2 backward);
        // bit-identical to the forward value (same ops, same order).
        float acc[4][4];
        float4 b = *(const float4*)(b1 + j0);
        #pragma unroll
        for (int p = 0; p < 4; p++){ acc[p][0]=b.x; acc[p][1]=b.y; acc[p][2]=b.z; acc[p][3]=b.w; }
        mm_d(w1, DD, xT, acc, jg, p0);
        float s0r[4][4];
        ELT44(s0r[p][jj] = ftanh(acc[p][jj]))
        __syncthreads();
        write_own(S2, s0r, j0, p0);
        __syncthreads();
        BWD_LAYER(S2, 3, ST_Z1, ST_G1, ST_R1)              // layer 1 (stash; sl from S2)
    } else {
        BWD_LAYER(S0, 1, ST_Z1, ST_G1, ST_R1)              // layer 1 (recompute)
    }

    // first-layer backward + epilogue
    {
        float s0l[4][4];
        read_own((SG ? S2 : S0), s0l, j0, p0);
        float v0[4][4];
        ELT44(v0[p][jj] = ds[p][jj]*(1.f - s0l[p][jj]*s0l[p][jj]))

        if (type == 1){
            PROJ_D(w1, v0)
            __syncthreads();   // last mm_d's Db readers done
            *(float4*)(Db + jg*32 + p0) = make_float4(proj[0], proj[1], proj[2], proj[3]);
            __syncthreads();
            if (t < TM){
                float s = 0.f;
                for (int j2 = 0; j2 < 32; j2++) s += Db[j2*32 + t];
                atomicAdd(t12acc + base_n + t, s);
            }
        } else {
            __syncthreads();   // last mm_d's Db readers done
            write_own(Db, v0, j0, p0);
            __syncthreads();
            DX_DOT(w1, Db)
            #pragma unroll
            for (int ii = 0; ii < 3; ii++){
                int i = il + 8*ii;
                if (i < DD) fp1[(P0 + pi)*DD + i] = dxp[ii];
            }
        }
    }
}

__global__ __launch_bounds__(256) __attribute__((amdgpu_waves_per_eu(2,2))) void dgm_sg(DGM_PARAMS){
    __shared__ float lds[L_TOT_SG];
    dgm_body<1>(lds, DGM_ARGS);
}
__global__ __launch_bounds__(256) __attribute__((amdgpu_waves_per_eu(2,2))) void dgm_rc(DGM_PARAMS){
    __shared__ float lds[L_TOT_RC];
    dgm_body<0>(lds, DGM_ARGS);
}

__global__ void finalize_k(const float* __restrict__ inputs, const float* __restrict__ eps,
    const float* __restrict__ Lm, const float* __restrict__ fp1, const float* __restrict__ val1,
    const float* __restrict__ val2, const float* __restrict__ t12acc, float* __restrict__ out)
{
    int n = blockIdx.x*256 + threadIdx.x;
    if (n >= NN) return;
    float fp[DD];
    #pragma unroll
    for (int k = 0; k < DD; k++) fp[k] = fp1[n*DD + k];
    float t11 = fp[DIMN];
    #pragma unroll
    for (int k = 0; k < DIMN; k++) t11 = fmaf(MUC*inputs[n*DD + k], fp[k], t11);
    float esum[DIMN];
    #pragma unroll
    for (int d = 0; d < DIMN; d++){
        float a = 0.f;
        for (int m = 0; m < MCN; m++) a += eps[(size_t)(m*NN + n)*DIMN + d];
        esum[d] = a;
    }
    float t12b = 0.f;
    #pragma unroll
    for (int k = 0; k < DIMN; k++){
        float loc = inputs[n*DD + k];
        float ssum = (float)MCN * loc;
        #pragma unroll
        for (int d = 0; d < DIMN; d++) ssum = fmaf(esum[d], Lm[k*DIMN + d], ssum);
        float vsum = ssum * (SIGC*loc);
        t12b = fmaf(fp[k], vsum, t12b);
    }
    float term12 = (t12acc[n] - t12b) * (1.0f/(DELTAC*(float)MCN));
    out[n] = t11 + 0.5f*term12 - RC*val1[n];

    float prod = 1.f;
    #pragma unroll
    for (int k = 0; k < DIMN; k++) prod *= inputs[(NN + n)*DD + k];
    float payoff = powf(prod, 1.0f/(float)DIMN);
    if (!(payoff > 0.f)) payoff = 0.f;
    out[NN + n] = val2[n] - payoff;
}

extern "C" void kernel_launch(void* const* d_in, const int* in_sizes, int n_in,
                              void* d_out, int out_size, void* d_ws, size_t ws_size,
                              hipStream_t stream)
{
    const float* inputs = (const float*)d_in[0];
    const float* eps    = (const float*)d_in[1];
    const float* w1     = (const float*)d_in[2];
    const float* b1     = (const float*)d_in[3];
    const float* uz     = (const float*)d_in[4];
    const float* wz     = (const float*)d_in[5];
    const float* bz     = (const float*)d_in[6];
    const float* ug     = (const float*)d_in[7];
    const float* wg     = (const float*)d_in[8];
    const float* bg     = (const float*)d_in[9];
    const float* urr    = (const float*)d_in[10];
    const float* wr     = (const float*)d_in[11];
    const float* br     = (const float*)d_in[12];
    const float* uh     = (const float*)d_in[13];
    const float* wh     = (const float*)d_in[14];
    const float* bh     = (const float*)d_in[15];
    const float* wv     = (const float*)d_in[16];
    const float* bv     = (const float*)d_in[17];

    float* ws    = (float*)d_ws;
    float* Lm    = ws + OFF_L;
    float* WT    = ws + OFF_WT;
    float* Uzgr  = ws + OFF_UZGR;
    float* Wzgr  = ws + OFF_WZGR;
    float* fp1   = ws + OFF_FP1;
    float* val1  = ws + OFF_VAL1;
    float* val2  = ws + OFF_VAL2;
    float* t12   = ws + OFF_T12;
    float* gates = ws + OFF_GATES;
    float* out   = (float*)d_out;

    hipMemsetAsync(t12, 0, NN*sizeof(float), stream);
    hipLaunchKernelGGL(chol_kernel, dim3(1), dim3(64), 0, stream, Lm);
    hipLaunchKernelGGL(transpose_k, dim3(256), dim3(256), 0, stream, wz, wg, wr, wh, WT);
    hipLaunchKernelGGL(pack_zgr, dim3(224), dim3(256), 0, stream, uz, ug, urr, wz, wg, wr, Uzgr, Wzgr);

    size_t need_bytes = ((size_t)OFF_GATES + (size_t)NBLK * (size_t)GB_STRIDE) * sizeof(float);
    if (ws_size >= need_bytes){
        hipLaunchKernelGGL(dgm_sg, dim3(NBLK), dim3(256), 0, stream,
            inputs, eps, w1, b1, uz, bz, ug, bg, urr, br, uh, wh, bh, wv, bv,
            Lm, WT, Uzgr, Wzgr, gates, fp1, val1, val2, t12);
    } else {
        hipLaunchKernelGGL(dgm_rc, dim3(NBLK), dim3(256), 0, stream,
            inputs, eps, w1, b1, uz, bz, ug, bg, urr, br, uh, wh, bh, wv, bv,
            Lm, WT, Uzgr, Wzgr, gates, fp1, val1, val2, t12);
    }
    hipLaunchKernelGGL(finalize_k, dim3(8), dim3(256), 0, stream,
        inputs, eps, Lm, fp1, val1, val2, t12, out);
}